// Round 2
// baseline (561.288 us; speedup 1.0000x reference)
//
#include <hip/hip_runtime.h>
#include <math.h>

#define NEG_SLOPE 0.2f

constexpr int F_IN  = 128;
constexpr int HC1   = 256;  // H*HID
constexpr int HC2   = 160;  // H*CLS
constexpr int NHEAD = 4;
constexpr int NBANK = 16;   // per-XCD histogram banks (8 XCDs measured; 16 for safety)

typedef _Float16 h8v __attribute__((ext_vector_type(8)));
typedef _Float16 h4v __attribute__((ext_vector_type(4)));
typedef float f4v __attribute__((ext_vector_type(4)));

// f32 += f16(lo/hi of packed) * f32 — single VOP3P instruction
#define FMIX_LO(acc, pk, wt) \
    asm("v_fma_mix_f32 %0, %1, %2, %0 op_sel:[0,0,0] op_sel_hi:[1,0,0]" \
        : "+v"(acc) : "v"(pk), "v"(wt))
#define FMIX_HI(acc, pk, wt) \
    asm("v_fma_mix_f32 %0, %1, %2, %0 op_sel:[1,0,0] op_sel_hi:[1,0,0]" \
        : "+v"(acc) : "v"(pk), "v"(wt))

__device__ __forceinline__ int edge_val(const void* p, int m64, long long i) {
    if (m64) return (int)((const long long*)p)[i];
    return ((const int*)p)[i];
}

// ---------------- dispatch 2: edge dtype detect (+ zero stats) ----------------
__global__ void detect_kernel(const unsigned int* __restrict__ ei_words, int* __restrict__ mode,
                              float* __restrict__ stats) {
    stats[threadIdx.x] = 0.f;  // 256 threads zero 256 floats (sum|sumsq)
    __shared__ unsigned int red[256];
    unsigned int v = 0;
    for (int i = 1 + 2 * (int)threadIdx.x; i < 4096; i += 512) v |= ei_words[i];
    red[threadIdx.x] = v;
    __syncthreads();
    for (int off = 128; off > 0; off >>= 1) {
        if (threadIdx.x < off) red[threadIdx.x] |= red[threadIdx.x + off];
        __syncthreads();
    }
    if (threadIdx.x == 0) *mode = (red[0] == 0u) ? 1 : 0;
}

// ---------------- dispatch 3 (fused): count | colstats | convert_w ----------------
// count: per-XCD private histograms. Inline-asm global_atomic_add with sc0 ONLY
// (return-old, no sc1) -> RMW executes in the issuing XCD's local L2. Atomicity
// holds because only blocks on XCD k ever touch bank k.
__global__ __launch_bounds__(256) void fused_pre_kernel(
    const void* __restrict__ ei, const int* __restrict__ mode, int E,
    int* __restrict__ counts_x, int* __restrict__ pos, const float* __restrict__ x,
    float* __restrict__ stats, int N, const float* __restrict__ W1,
    const float* __restrict__ aS1, const float* __restrict__ aD1, _Float16* __restrict__ B1x,
    const float* __restrict__ W2, const float* __restrict__ aS2, const float* __restrict__ aD2,
    _Float16* __restrict__ B2x, int nbCnt, int nbStats) {
    int b = blockIdx.x;
    if (b < nbCnt) {
        // ---- count: pos[e] = (xcd | rank-within-xcd-bank) ----
        int e = b * 256 + (int)threadIdx.x;
        if (e < E) {
            int xcd;
            asm volatile("s_getreg_b32 %0, hwreg(HW_REG_XCC_ID)" : "=s"(xcd));
            int d = edge_val(ei, *mode, (long long)E + e);
            int* ap = &counts_x[(size_t)xcd * N + d];
            int one = 1, r;
            asm volatile(
                "global_atomic_add %0, %1, %2, off sc0\n\t"
                "s_waitcnt vmcnt(0)"
                : "=v"(r)
                : "v"(ap), "v"(one)
                : "memory");
            pos[e] = (xcd << 27) | r;
        }
    } else if (b < nbCnt + nbStats) {
        // ---- colstats: float4 loads, 32 iters/thread, LDS-reduce 8 row groups ----
        int t = (int)threadIdx.x;
        int c = t & 31;   // handles cols 4c..4c+3
        int g = t >> 5;   // row subgroup 0..7
        int r0 = (b - nbCnt) * 256;
        int rend = min(r0 + 256, N);
        f4v s = {0.f, 0.f, 0.f, 0.f}, q = {0.f, 0.f, 0.f, 0.f};
        for (int r = r0 + g; r < rend; r += 8) {
            f4v v = *(const f4v*)&x[(long)r * F_IN + 4 * c];
            s += v;
            q += v * v;
        }
        __shared__ f4v sh4[256];
        sh4[t] = s;
        __syncthreads();
        if (t < 32) {
            f4v a = sh4[t];
            for (int g2 = 1; g2 < 8; g2++) a += sh4[g2 * 32 + t];
            atomicAdd(&stats[4 * t + 0], a[0]);
            atomicAdd(&stats[4 * t + 1], a[1]);
            atomicAdd(&stats[4 * t + 2], a[2]);
            atomicAdd(&stats[4 * t + 3], a[3]);
        }
        __syncthreads();
        sh4[t] = q;
        __syncthreads();
        if (t < 32) {
            f4v a = sh4[t];
            for (int g2 = 1; g2 < 8; g2++) a += sh4[g2 * 32 + t];
            atomicAdd(&stats[128 + 4 * t + 0], a[0]);
            atomicAdd(&stats[128 + 4 * t + 1], a[1]);
            atomicAdd(&stats[128 + 4 * t + 2], a[2]);
            atomicAdd(&stats[128 + 4 * t + 3], a[3]);
        }
    } else {
        // ---- convert weights -> fp16 transposed + att columns ----
        constexpr int T1 = (HC1 + 16) * F_IN;
        constexpr int T2 = (HC2 + 16) * HC1;
        int idx = (b - nbCnt - nbStats) * 256 + (int)threadIdx.x;
        if (idx < T1) {
            int n = idx / F_IN, k = idx - n * F_IN;
            float v = 0.f;
            if (n < HC1) {
                v = W1[k * HC1 + n];
            } else {
                int n2 = n - HC1;
                if (n2 < 8) {
                    int hd = n2 & 3;
                    const float* a = (n2 < 4) ? aS1 : aD1;
                    for (int c = 0; c < 64; c++) v += W1[k * HC1 + hd * 64 + c] * a[hd * 64 + c];
                }
            }
            B1x[n * F_IN + k] = (_Float16)v;
        } else if (idx < T1 + T2) {
            int i2 = idx - T1;
            int n = i2 / HC1, k = i2 - n * HC1;
            float v = 0.f;
            if (n < HC2) {
                v = W2[k * HC2 + n];
            } else {
                int n2 = n - HC2;
                if (n2 < 8) {
                    int hd = n2 & 3;
                    const float* a = (n2 < 4) ? aS2 : aD2;
                    for (int c = 0; c < 40; c++) v += W2[k * HC2 + hd * 40 + c] * a[hd * 40 + c];
                }
            }
            B2x[n * HC1 + k] = (_Float16)v;
        }
    }
}

// ---------------- dispatch 4 (fused): standardize | scan_block ----------------
__global__ __launch_bounds__(256) void fused_mid_kernel(
    const float* __restrict__ x, const float* __restrict__ stats, _Float16* __restrict__ xs,
    int total4, float invN, float invN1, int* __restrict__ counts_x, int* __restrict__ offsets,
    int* __restrict__ blocksum, int N, int nbStd) {
    int b = blockIdx.x;
    if (b < nbStd) {
        int i = b * 256 + (int)threadIdx.x;
        if (i >= total4) return;
        int c = (i * 4) & (F_IN - 1);
        float4 s4 = *(const float4*)&stats[c];
        float4 q4 = *(const float4*)&stats[128 + c];
        float4 v = ((const float4*)x)[i];
        h4v o;
        o[0] = (_Float16)((v.x - s4.x * invN) / sqrtf((q4.x - s4.x * s4.x * invN) * invN1));
        o[1] = (_Float16)((v.y - s4.y * invN) / sqrtf((q4.y - s4.y * s4.y * invN) * invN1));
        o[2] = (_Float16)((v.z - s4.z * invN) / sqrtf((q4.z - s4.z * s4.z * invN) * invN1));
        o[3] = (_Float16)((v.w - s4.w * invN) / sqrtf((q4.w - s4.w * s4.w * invN) * invN1));
        ((h4v*)xs)[i] = o;
    } else {
        // scan_block: per-node sum of the NBANK histograms (+1 self loop), with
        // in-place conversion of counts_x[k][i] to per-bank exclusive prefix.
        int t = threadIdx.x;
        int i = (b - nbStd) * 256 + t;
        int v = 0;
        if (i < N) {
            int run = 0;
#pragma unroll
            for (int k = 0; k < NBANK; k++) {
                int* p = &counts_x[(size_t)k * N + i];
                int cv = *p;
                *p = run;
                run += cv;
            }
            v = run + 1;
        }
        int lane = t & 63, w = t >> 6;
        int xv = v;
#pragma unroll
        for (int d = 1; d < 64; d <<= 1) {
            int y = __shfl_up(xv, d);
            if (lane >= d) xv += y;
        }
        __shared__ int wsum[4];
        if (lane == 63) wsum[w] = xv;
        __syncthreads();
        int base = 0;
        for (int k = 0; k < w; k++) base += wsum[k];
        int incl = xv + base;
        if (i < N) offsets[i + 1] = incl;
        if (t == 255) blocksum[b - nbStd] = incl;
    }
}

// ---------------- dispatch 5: scan_add ----------------
__global__ void scan_add_kernel(const int* __restrict__ blocksum, int* __restrict__ offsets, int N,
                                int nb) {
    int t = threadIdx.x;
    int v = (t < nb) ? blocksum[t] : 0;
    int lane = t & 63, w = t >> 6;
    int x = v;
#pragma unroll
    for (int d = 1; d < 64; d <<= 1) {
        int y = __shfl_up(x, d);
        if (lane >= d) x += y;
    }
    __shared__ int wsum[4];
    __shared__ int excl[256];
    if (lane == 63) wsum[w] = x;
    __syncthreads();
    int base = 0;
    for (int k = 0; k < w; k++) base += wsum[k];
    excl[t] = x + base - v;
    __syncthreads();
    int myb = excl[blockIdx.x];
    int i = blockIdx.x * 256 + t;
    if (i < N) offsets[i + 1] += myb;
    if (i == 0) offsets[0] = 0;
}

// ---------------- MFMA f16 GEMM body (row-major C + fused att scores) ----------------
// PADC: remap C columns into padded [row][8 slices][32 halfwords] layout (20 used)
template <int Nc, int K, bool PADC>
__device__ __forceinline__ void gemm_att_body(int blk, const _Float16* __restrict__ A,
                                              const _Float16* __restrict__ Btx,
                                              _Float16* __restrict__ C_, float* __restrict__ as_,
                                              float* __restrict__ ad_, int M) {
    constexpr int NT = Nc / 16;
    constexpr int NTT = NT + 1;
    constexpr int KT = K / 32;
    int w = threadIdx.x >> 6;
    int l = threadIdx.x & 63;
    int quad = l >> 4, lan = l & 15;
    int row = blk * 64 + w * 16 + lan;
    int arow = min(row, M - 1);
    f4v acc[NTT] = {};
    const _Float16* Aptr = A + (long)arow * K + quad * 8;
#pragma unroll
    for (int k0 = 0; k0 < KT; k0++) {
        h8v af = *(const h8v*)(Aptr + k0 * 32);
#pragma unroll
        for (int ct = 0; ct < NTT; ct++) {
            const _Float16* Bptr = Btx + (long)(ct * 16 + lan) * K + k0 * 32 + quad * 8;
            h8v bf = *(const h8v*)Bptr;
            acc[ct] = __builtin_amdgcn_mfma_f32_16x16x32_f16(af, bf, acc[ct], 0, 0, 0);
        }
    }
    int orow = blk * 64 + w * 16 + quad * 4;
#pragma unroll
    for (int r = 0; r < 4; r++) {
        int gr = orow + r;
        if (gr < M) {
            if (!PADC) {
                _Float16* out = C_ + (long)gr * Nc + lan;
#pragma unroll
                for (int ct = 0; ct < NT; ct++) out[ct * 16] = (_Float16)acc[ct][r];
            } else {
#pragma unroll
                for (int ct = 0; ct < NT; ct++) {
                    int c = ct * 16 + lan;
                    int sl = c / 20;
                    C_[(long)gr * 256 + sl * 32 + (c - sl * 20)] = (_Float16)acc[ct][r];
                }
            }
            float av = acc[NT][r];
            if (lan < 4)
                as_[gr * 4 + lan] = av;
            else if (lan < 8)
                ad_[gr * 4 + lan - 4] = av;
        }
    }
}

// ---------------- dispatch 6 (fused): fill_csr | gemm1 ----------------
__global__ __launch_bounds__(256) void fused_fill_g1_kernel(
    const void* __restrict__ ei, const int* __restrict__ mode, int E, int N,
    const int* __restrict__ offsets, const int* __restrict__ pos,
    const int* __restrict__ counts_x, int* __restrict__ csr, int nbFill,
    const _Float16* __restrict__ A, const _Float16* __restrict__ B1x, _Float16* __restrict__ C_,
    float* __restrict__ as_, float* __restrict__ ad_) {
    int b = blockIdx.x;
    if (b < nbFill) {
        int e = b * 256 + (int)threadIdx.x;
        if (e < E) {
            int m = *mode;
            int s = edge_val(ei, m, e);
            int d = edge_val(ei, m, (long long)E + e);
            int pr = pos[e];
            int base = counts_x[(size_t)(pr >> 27) * N + d];
            csr[offsets[d] + 1 + base + (pr & 0x07FFFFFF)] = s;
        } else if (e < E + N) {
            int n = e - E;
            csr[offsets[n]] = n;
        }
    } else {
        gemm_att_body<HC1, F_IN, false>(b - nbFill, A, B1x, C_, as_, ad_, N);
    }
}

// ---------------- dispatch 8: gemm2 (padded C for sliced aggregate) ----------------
__global__ __launch_bounds__(256) void gemm2_kernel(const _Float16* __restrict__ A,
                                                    const _Float16* __restrict__ B2x,
                                                    _Float16* __restrict__ C_,
                                                    float* __restrict__ as_,
                                                    float* __restrict__ ad_, int M) {
    gemm_att_body<HC2, HC1, true>(blockIdx.x, A, B2x, C_, as_, ad_, M);
}

// ---------------- channel-sliced aggregate with XCD affinity ----------------
// Block b handles slice b%8 (consecutive blocks round-robin across XCDs, so
// XCD k only touches slice k's 64B column of each row -> per-XCD L2 footprint
// = N*64B = 3.2MB, L2-resident -> src-row reuse becomes L2 hits).
// Wave layout: l = e8*8 + c8 -> 8 edges in parallel x 8 channel-chunks (4 ch each).
// hb rows are HCP=256 halfwords (512B); slice s occupies bytes [s*64, s*64+CS*2).
template <int HC, bool RELU, typename OutT>
__global__ __launch_bounds__(256) void aggregate_slice_kernel(
    const _Float16* __restrict__ hb, const float* __restrict__ a_src,
    const float* __restrict__ a_dst, const int* __restrict__ offsets,
    const int* __restrict__ csr_src, const float* __restrict__ bias, OutT* __restrict__ out,
    int Ntot) {
    constexpr int CS = HC / 8;    // channels per slice (32 or 20)
    constexpr int CPL = CS / 4;   // active int2 lanes per edge (8 or 5)
    constexpr bool FULL = (CPL == 8);
    int slice = blockIdx.x & 7;
    int ng = blockIdx.x >> 3;
    int w = threadIdx.x >> 6, l = threadIdx.x & 63;
    int node = ng * 4 + w;
    if (node >= Ntot) return;  // wave-uniform exit
    int hd = slice >> 1;       // 2 slices per head in both layers
    int e8 = l >> 3, c8 = l & 7;

    __shared__ __align__(16) int sidx_sh[4][64];
    __shared__ float ew_sh[4][64];

    int start = offsets[node], deg = offsets[node + 1] - start;
    float adv = a_dst[node * 4 + hd];
    const char* hbl = (const char*)hb + (size_t)slice * 64 + 8 * c8;
    const bool act = FULL || (c8 < CPL);

    float a0 = 0.f, a1 = 0.f, a2 = 0.f, a3 = 0.f, ds = 0.f;

    for (int base = 0; base < deg; base += 64) {
        int cnt = min(64, deg - base);
        if (l < cnt) {
            int s = csr_src[start + base + l];
            sidx_sh[w][l] = s * 512;  // byte offset of row (HCP=256 halfwords)
            float e = a_src[s * 4 + hd] + adv;
            e = fmaxf(e, NEG_SLOPE * e);
            float wv = __expf(e);
            ew_sh[w][l] = wv;
            ds += wv;
        }
        int gmax = (cnt + 7) >> 3;
        int g = 0;
        for (; g + 2 <= gmax; g += 2) {
            int j0 = (g << 3) + e8;       // always < cnt here
            int j1 = j0 + 8;
            int j1c = min(j1, cnt - 1);
            int o0 = sidx_sh[w][j0];
            int o1 = sidx_sh[w][j1c];
            float w0 = ew_sh[w][j0];
            float w1 = (j1 < cnt) ? ew_sh[w][j1c] : 0.f;
            if (act) {
                int2 p0 = *(const int2*)(hbl + o0);
                int2 p1 = *(const int2*)(hbl + o1);
                FMIX_LO(a0, p0.x, w0); FMIX_HI(a1, p0.x, w0);
                FMIX_LO(a2, p0.y, w0); FMIX_HI(a3, p0.y, w0);
                FMIX_LO(a0, p1.x, w1); FMIX_HI(a1, p1.x, w1);
                FMIX_LO(a2, p1.y, w1); FMIX_HI(a3, p1.y, w1);
            }
        }
        if (g < gmax) {
            int j = (g << 3) + e8;
            int jc = min(j, cnt - 1);
            int o0 = sidx_sh[w][jc];
            float w0 = (j < cnt) ? ew_sh[w][jc] : 0.f;
            if (act) {
                int2 p0 = *(const int2*)(hbl + o0);
                FMIX_LO(a0, p0.x, w0); FMIX_HI(a1, p0.x, w0);
                FMIX_LO(a2, p0.y, w0); FMIX_HI(a3, p0.y, w0);
            }
        }
    }

    // reduce channel partials across the 8 edge-groups (xor bits 3..5 keep c8)
#pragma unroll
    for (int off = 8; off < 64; off <<= 1) {
        a0 += __shfl_xor(a0, off);
        a1 += __shfl_xor(a1, off);
        a2 += __shfl_xor(a2, off);
        a3 += __shfl_xor(a3, off);
    }
    // denominator over whole wave
#pragma unroll
    for (int off = 1; off < 64; off <<= 1) ds += __shfl_xor(ds, off);

    if (e8 == 0 && act) {
        float inv = 1.0f / ds;
        float4 bv = *(const float4*)&bias[slice * CS + 4 * c8];
        float r0 = a0 * inv + bv.x;
        float r1 = a1 * inv + bv.y;
        float r2 = a2 * inv + bv.z;
        float r3 = a3 * inv + bv.w;
        if (RELU) {
            r0 = fmaxf(r0, 0.f);
            r1 = fmaxf(r1, 0.f);
            r2 = fmaxf(r2, 0.f);
            r3 = fmaxf(r3, 0.f);
        }
        OutT* op = out + (long)node * HC + slice * CS + 4 * c8;
        if (sizeof(OutT) == 2) {
            h4v hv;
            hv[0] = (_Float16)r0;
            hv[1] = (_Float16)r1;
            hv[2] = (_Float16)r2;
            hv[3] = (_Float16)r3;
            *(h4v*)op = hv;
        } else {
            *(float4*)op = make_float4(r0, r1, r2, r3);
        }
    }
}

// ---------------- launch ----------------
extern "C" void kernel_launch(void* const* d_in, const int* in_sizes, int n_in, void* d_out,
                              int out_size, void* d_ws, size_t ws_size, hipStream_t stream) {
    const float* x = (const float*)d_in[0];
    const void* ei = d_in[1];
    const float* W1 = (const float*)d_in[2];
    const float* attS1 = (const float*)d_in[3];
    const float* attD1 = (const float*)d_in[4];
    const float* b1 = (const float*)d_in[5];
    const float* W2 = (const float*)d_in[6];
    const float* attS2 = (const float*)d_in[7];
    const float* attD2 = (const float*)d_in[8];
    const float* b2 = (const float*)d_in[9];
    float* out = (float*)d_out;

    int N = in_sizes[0] / F_IN;  // 50000
    int E = in_sizes[1] / 2;     // 800000
    int nb = (N + 255) / 256;    // 196
    int nwS = 8 * ((N + 3) / 4); // sliced aggregate grid (slice = blockIdx%8)

    _Float16* xs_h = (_Float16*)d_ws;             // N*128
    _Float16* hb1 = xs_h + (size_t)N * F_IN;      // N*256 row-major; reused as padded hb2p
    _Float16* o1h = hb1 + (size_t)N * HC1;        // N*256 row-major (counts_x overlays early)
    _Float16* posb = o1h + (size_t)N * HC1;       // old hb2 slot: pos[] overlay (E ints fit)
    _Float16* B1x = posb + (size_t)N * HC2;       // 272*128
    _Float16* B2x = B1x + (HC1 + 16) * F_IN;      // 176*256
    float* as1 = (float*)(B2x + (HC2 + 16) * HC1);
    float* ad1 = as1 + (size_t)N * NHEAD;
    float* as2 = ad1 + (size_t)N * NHEAD;
    float* ad2 = as2 + (size_t)N * NHEAD;
    float* stats = ad2 + (size_t)N * NHEAD;       // 256 (zeroed in detect_kernel)
    int* offsets = (int*)(stats + 256) + N;       // N+1 (pad 4)
    int* csr = offsets + (N + 4);                 // E+N
    int* blocksum = csr + (E + N);                // 256
    int* mode = blocksum + 256;                   // 1
    int* pos = (int*)posb;     // E ints
    int* counts_x = (int*)o1h; // NBANK*N ints; dead before aggregate1 writes o1h

    int nbCnt = (E + 255) / 256;                         // 3125
    constexpr int TCV = (HC1 + 16) * F_IN + (HC2 + 16) * HC1;
    int nbConv = (TCV + 255) / 256;                      // 143
    int total4 = N * F_IN / 4;
    int nbStd = (total4 + 255) / 256;                    // 6250
    int nbFill = (E + N + 255) / 256;                    // 3321
    int nbG1 = (N + 63) / 64;                            // 782

    // 1. zero per-XCD histograms (stats is zeroed inside detect_kernel)
    hipMemsetAsync(counts_x, 0, (size_t)NBANK * N * sizeof(int), stream);
    // 2. detect edge dtype + zero stats
    detect_kernel<<<1, 256, 0, stream>>>((const unsigned int*)ei, mode, stats);
    // 3. fused: count | colstats | convert_w
    fused_pre_kernel<<<nbCnt + nb + nbConv, 256, 0, stream>>>(
        ei, mode, E, counts_x, pos, x, stats, N, W1, attS1, attD1, B1x, W2, attS2, attD2, B2x,
        nbCnt, nb);
    // 4. fused: standardize | scan_block (bank prefix + node scan)
    fused_mid_kernel<<<nbStd + nb, 256, 0, stream>>>(x, stats, xs_h, total4, 1.0f / (float)N,
                                                     1.0f / (float)(N - 1), counts_x, offsets,
                                                     blocksum, N, nbStd);
    // 5. scan_add
    scan_add_kernel<<<nb, 256, 0, stream>>>(blocksum, offsets, N, nb);
    // 6. fused: fill_csr | gemm1(+att)
    fused_fill_g1_kernel<<<nbFill + nbG1, 256, 0, stream>>>(ei, mode, E, N, offsets, pos,
                                                            counts_x, csr, nbFill, xs_h, B1x,
                                                            hb1, as1, ad1);
    // 7. aggregate layer 1 (channel-sliced)
    aggregate_slice_kernel<HC1, true, _Float16>
        <<<nwS, 256, 0, stream>>>(hb1, as1, ad1, offsets, csr, b1, o1h, N);
    // 8. gemm2(+att) -> padded layout into hb1 slot (dead after agg1)
    gemm2_kernel<<<nbG1, 256, 0, stream>>>(o1h, B2x, hb1, as2, ad2, N);
    // 9. aggregate layer 2 (channel-sliced, padded hb rows)
    aggregate_slice_kernel<HC2, false, float>
        <<<nwS, 256, 0, stream>>>(hb1, as2, ad2, offsets, csr, b2, out, N);
}

// Round 4
// 360.363 us; speedup vs baseline: 1.5576x; 1.5576x over previous
//
#include <hip/hip_runtime.h>
#include <math.h>

#define NEG_SLOPE 0.2f

constexpr int F_IN  = 128;
constexpr int HC1   = 256;  // H*HID
constexpr int HC2   = 160;  // H*CLS
constexpr int NHEAD = 4;
constexpr int NBANK = 16;   // per-XCD histogram banks (8 XCDs measured; 16 for safety)

typedef _Float16 h8v __attribute__((ext_vector_type(8)));
typedef _Float16 h4v __attribute__((ext_vector_type(4)));
typedef _Float16 h2v __attribute__((ext_vector_type(2)));
typedef float f4v __attribute__((ext_vector_type(4)));

// f32 += f16(lo/hi of packed) * f32 — single VOP3P instruction
#define FMIX_LO(acc, pk, wt) \
    asm("v_fma_mix_f32 %0, %1, %2, %0 op_sel:[0,0,0] op_sel_hi:[1,0,0]" \
        : "+v"(acc) : "v"(pk), "v"(wt))
#define FMIX_HI(acc, pk, wt) \
    asm("v_fma_mix_f32 %0, %1, %2, %0 op_sel:[1,0,0] op_sel_hi:[1,0,0]" \
        : "+v"(acc) : "v"(pk), "v"(wt))

__device__ __forceinline__ int edge_val(const void* p, int m64, long long i) {
    if (m64) return (int)((const long long*)p)[i];
    return ((const int*)p)[i];
}

// ---------------- dispatch 2: edge dtype detect (+ zero stats) ----------------
__global__ void detect_kernel(const unsigned int* __restrict__ ei_words, int* __restrict__ mode,
                              float* __restrict__ stats) {
    stats[threadIdx.x] = 0.f;  // 256 threads zero 256 floats (sum|sumsq)
    __shared__ unsigned int red[256];
    unsigned int v = 0;
    for (int i = 1 + 2 * (int)threadIdx.x; i < 4096; i += 512) v |= ei_words[i];
    red[threadIdx.x] = v;
    __syncthreads();
    for (int off = 128; off > 0; off >>= 1) {
        if (threadIdx.x < off) red[threadIdx.x] |= red[threadIdx.x + off];
        __syncthreads();
    }
    if (threadIdx.x == 0) *mode = (red[0] == 0u) ? 1 : 0;
}

// ---------------- dispatch 3 (fused): count | colstats | convert_w ----------------
__global__ __launch_bounds__(256) void fused_pre_kernel(
    const void* __restrict__ ei, const int* __restrict__ mode, int E,
    int* __restrict__ counts_x, int* __restrict__ pos, const float* __restrict__ x,
    float* __restrict__ stats, int N, const float* __restrict__ W1,
    const float* __restrict__ aS1, const float* __restrict__ aD1, _Float16* __restrict__ B1x,
    const float* __restrict__ W2, const float* __restrict__ aS2, const float* __restrict__ aD2,
    _Float16* __restrict__ B2x, int nbCnt, int nbStats) {
    int b = blockIdx.x;
    if (b < nbCnt) {
        // ---- count: pos[e] = (xcd | rank-within-xcd-bank) ----
        int e = b * 256 + (int)threadIdx.x;
        if (e < E) {
            int xcd;
            asm volatile("s_getreg_b32 %0, hwreg(HW_REG_XCC_ID)" : "=s"(xcd));
            int d = edge_val(ei, *mode, (long long)E + e);
            int* ap = &counts_x[(size_t)xcd * N + d];
            int one = 1, r;
            asm volatile(
                "global_atomic_add %0, %1, %2, off sc0\n\t"
                "s_waitcnt vmcnt(0)"
                : "=v"(r)
                : "v"(ap), "v"(one)
                : "memory");
            pos[e] = (xcd << 27) | r;
        }
    } else if (b < nbCnt + nbStats) {
        // ---- colstats: float4 loads, 32 iters/thread, LDS-reduce 8 row groups ----
        int t = (int)threadIdx.x;
        int c = t & 31;   // handles cols 4c..4c+3
        int g = t >> 5;   // row subgroup 0..7
        int r0 = (b - nbCnt) * 256;
        int rend = min(r0 + 256, N);
        f4v s = {0.f, 0.f, 0.f, 0.f}, q = {0.f, 0.f, 0.f, 0.f};
        for (int r = r0 + g; r < rend; r += 8) {
            f4v v = *(const f4v*)&x[(long)r * F_IN + 4 * c];
            s += v;
            q += v * v;
        }
        __shared__ f4v sh4[256];
        sh4[t] = s;
        __syncthreads();
        if (t < 32) {
            f4v a = sh4[t];
            for (int g2 = 1; g2 < 8; g2++) a += sh4[g2 * 32 + t];
            atomicAdd(&stats[4 * t + 0], a[0]);
            atomicAdd(&stats[4 * t + 1], a[1]);
            atomicAdd(&stats[4 * t + 2], a[2]);
            atomicAdd(&stats[4 * t + 3], a[3]);
        }
        __syncthreads();
        sh4[t] = q;
        __syncthreads();
        if (t < 32) {
            f4v a = sh4[t];
            for (int g2 = 1; g2 < 8; g2++) a += sh4[g2 * 32 + t];
            atomicAdd(&stats[128 + 4 * t + 0], a[0]);
            atomicAdd(&stats[128 + 4 * t + 1], a[1]);
            atomicAdd(&stats[128 + 4 * t + 2], a[2]);
            atomicAdd(&stats[128 + 4 * t + 3], a[3]);
        }
    } else {
        // ---- convert weights -> fp16 transposed + att columns ----
        constexpr int T1 = (HC1 + 16) * F_IN;
        constexpr int T2 = (HC2 + 16) * HC1;
        int idx = (b - nbCnt - nbStats) * 256 + (int)threadIdx.x;
        if (idx < T1) {
            int n = idx / F_IN, k = idx - n * F_IN;
            float v = 0.f;
            if (n < HC1) {
                v = W1[k * HC1 + n];
            } else {
                int n2 = n - HC1;
                if (n2 < 8) {
                    int hd = n2 & 3;
                    const float* a = (n2 < 4) ? aS1 : aD1;
                    for (int c = 0; c < 64; c++) v += W1[k * HC1 + hd * 64 + c] * a[hd * 64 + c];
                }
            }
            B1x[n * F_IN + k] = (_Float16)v;
        } else if (idx < T1 + T2) {
            int i2 = idx - T1;
            int n = i2 / HC1, k = i2 - n * HC1;
            float v = 0.f;
            if (n < HC2) {
                v = W2[k * HC2 + n];
            } else {
                int n2 = n - HC2;
                if (n2 < 8) {
                    int hd = n2 & 3;
                    const float* a = (n2 < 4) ? aS2 : aD2;
                    for (int c = 0; c < 40; c++) v += W2[k * HC2 + hd * 40 + c] * a[hd * 40 + c];
                }
            }
            B2x[n * HC1 + k] = (_Float16)v;
        }
    }
}

// ---------------- dispatch 4 (fused): standardize | scan_block ----------------
__global__ __launch_bounds__(256) void fused_mid_kernel(
    const float* __restrict__ x, const float* __restrict__ stats, _Float16* __restrict__ xs,
    int total4, float invN, float invN1, int* __restrict__ counts_x, int* __restrict__ offsets,
    int* __restrict__ blocksum, int N, int nbStd) {
    int b = blockIdx.x;
    if (b < nbStd) {
        int i = b * 256 + (int)threadIdx.x;
        if (i >= total4) return;
        int c = (i * 4) & (F_IN - 1);
        float4 s4 = *(const float4*)&stats[c];
        float4 q4 = *(const float4*)&stats[128 + c];
        float4 v = ((const float4*)x)[i];
        h4v o;
        o[0] = (_Float16)((v.x - s4.x * invN) / sqrtf((q4.x - s4.x * s4.x * invN) * invN1));
        o[1] = (_Float16)((v.y - s4.y * invN) / sqrtf((q4.y - s4.y * s4.y * invN) * invN1));
        o[2] = (_Float16)((v.z - s4.z * invN) / sqrtf((q4.z - s4.z * s4.z * invN) * invN1));
        o[3] = (_Float16)((v.w - s4.w * invN) / sqrtf((q4.w - s4.w * s4.w * invN) * invN1));
        ((h4v*)xs)[i] = o;
    } else {
        // scan_block: per-node sum of the NBANK histograms (+1 self loop), with
        // in-place conversion of counts_x[k][i] to per-bank exclusive prefix.
        int t = threadIdx.x;
        int i = (b - nbStd) * 256 + t;
        int v = 0;
        if (i < N) {
            int run = 0;
#pragma unroll
            for (int k = 0; k < NBANK; k++) {
                int* p = &counts_x[(size_t)k * N + i];
                int cv = *p;
                *p = run;
                run += cv;
            }
            v = run + 1;
        }
        int lane = t & 63, w = t >> 6;
        int xv = v;
#pragma unroll
        for (int d = 1; d < 64; d <<= 1) {
            int y = __shfl_up(xv, d);
            if (lane >= d) xv += y;
        }
        __shared__ int wsum[4];
        if (lane == 63) wsum[w] = xv;
        __syncthreads();
        int base = 0;
        for (int k = 0; k < w; k++) base += wsum[k];
        int incl = xv + base;
        if (i < N) offsets[i + 1] = incl;
        if (t == 255) blocksum[b - nbStd] = incl;
    }
}

// ---------------- dispatch 5: scan_add ----------------
__global__ void scan_add_kernel(const int* __restrict__ blocksum, int* __restrict__ offsets, int N,
                                int nb) {
    int t = threadIdx.x;
    int v = (t < nb) ? blocksum[t] : 0;
    int lane = t & 63, w = t >> 6;
    int x = v;
#pragma unroll
    for (int d = 1; d < 64; d <<= 1) {
        int y = __shfl_up(x, d);
        if (lane >= d) x += y;
    }
    __shared__ int wsum[4];
    __shared__ int excl[256];
    if (lane == 63) wsum[w] = x;
    __syncthreads();
    int base = 0;
    for (int k = 0; k < w; k++) base += wsum[k];
    excl[t] = x + base - v;
    __syncthreads();
    int myb = excl[blockIdx.x];
    int i = blockIdx.x * 256 + t;
    if (i < N) offsets[i + 1] += myb;
    if (i == 0) offsets[0] = 0;
}

// ---------------- MFMA f16 GEMM body (row-major C + fused att scores) ----------------
template <int Nc, int K>
__device__ __forceinline__ void gemm_att_body(int blk, const _Float16* __restrict__ A,
                                              const _Float16* __restrict__ Btx,
                                              _Float16* __restrict__ C_, float* __restrict__ as_,
                                              float* __restrict__ ad_, int M) {
    constexpr int NT = Nc / 16;
    constexpr int NTT = NT + 1;
    constexpr int KT = K / 32;
    int w = threadIdx.x >> 6;
    int l = threadIdx.x & 63;
    int quad = l >> 4, lan = l & 15;
    int row = blk * 64 + w * 16 + lan;
    int arow = min(row, M - 1);
    f4v acc[NTT] = {};
    const _Float16* Aptr = A + (long)arow * K + quad * 8;
#pragma unroll
    for (int k0 = 0; k0 < KT; k0++) {
        h8v af = *(const h8v*)(Aptr + k0 * 32);
#pragma unroll
        for (int ct = 0; ct < NTT; ct++) {
            const _Float16* Bptr = Btx + (long)(ct * 16 + lan) * K + k0 * 32 + quad * 8;
            h8v bf = *(const h8v*)Bptr;
            acc[ct] = __builtin_amdgcn_mfma_f32_16x16x32_f16(af, bf, acc[ct], 0, 0, 0);
        }
    }
    int orow = blk * 64 + w * 16 + quad * 4;
#pragma unroll
    for (int r = 0; r < 4; r++) {
        int gr = orow + r;
        if (gr < M) {
            _Float16* out = C_ + (long)gr * Nc + lan;
#pragma unroll
            for (int ct = 0; ct < NT; ct++) out[ct * 16] = (_Float16)acc[ct][r];
            float av = acc[NTT - 1][r];
            if (lan < 4)
                as_[gr * 4 + lan] = av;
            else if (lan < 8)
                ad_[gr * 4 + lan - 4] = av;
        }
    }
}

// ---------------- att1 mini-GEMM: as1/ad1 = xs @ (W1·att) (8 cols) ----------------
__device__ __forceinline__ void att1_body(int blk, const _Float16* __restrict__ A,
                                          const _Float16* __restrict__ Batt,
                                          float* __restrict__ as_, float* __restrict__ ad_,
                                          int M) {
    int w = threadIdx.x >> 6;
    int l = threadIdx.x & 63;
    int quad = l >> 4, lan = l & 15;
    int row = blk * 64 + w * 16 + lan;
    int arow = min(row, M - 1);
    f4v acc = {0.f, 0.f, 0.f, 0.f};
    const _Float16* Aptr = A + (long)arow * F_IN + quad * 8;
#pragma unroll
    for (int k0 = 0; k0 < F_IN / 32; k0++) {
        h8v af = *(const h8v*)(Aptr + k0 * 32);
        h8v bf = *(const h8v*)(Batt + (long)lan * F_IN + k0 * 32 + quad * 8);
        acc = __builtin_amdgcn_mfma_f32_16x16x32_f16(af, bf, acc, 0, 0, 0);
    }
    int orow = blk * 64 + w * 16 + quad * 4;
#pragma unroll
    for (int r = 0; r < 4; r++) {
        int gr = orow + r;
        if (gr < M) {
            float av = acc[r];
            if (lan < 4)
                as_[gr * 4 + lan] = av;
            else if (lan < 8)
                ad_[gr * 4 + lan - 4] = av;
        }
    }
}

// ---------------- dispatch 6 (fused): fill_csr | att1 ----------------
__global__ __launch_bounds__(256) void fused_fill_att1_kernel(
    const void* __restrict__ ei, const int* __restrict__ mode, int E, int N,
    const int* __restrict__ offsets, const int* __restrict__ pos,
    const int* __restrict__ counts_x, int* __restrict__ csr, int nbFill,
    const _Float16* __restrict__ xs, const _Float16* __restrict__ B1x,
    float* __restrict__ as_, float* __restrict__ ad_) {
    int b = blockIdx.x;
    if (b < nbFill) {
        int e = b * 256 + (int)threadIdx.x;
        if (e < E) {
            int m = *mode;
            int s = edge_val(ei, m, e);
            int d = edge_val(ei, m, (long long)E + e);
            int pr = pos[e];
            int base = counts_x[(size_t)(pr >> 27) * N + d];
            csr[offsets[d] + 1 + base + (pr & 0x07FFFFFF)] = s;
        } else if (e < E + N) {
            int n = e - E;
            csr[offsets[n]] = n;
        }
    } else {
        att1_body(b - nbFill, xs, B1x + (size_t)HC1 * F_IN, as_, ad_, N);
    }
}

// ---------------- dispatch 7: per-head layer-1 aggregate in xs-space ----------------
// For each head h: aggx[h][n][:] = (Sigma_e w_e^h * xs[src]) / (Sigma_e w_e^h).
// Lane owns 2 channels (4B of xs row), keeps 8 accumulators (4 heads x 2 ch).
// Gather = 256B/edge (half of hb1-space); FMIX work = 2x (8/lane/edge).
// Heads 0,1 -> aggx_lo (scratch in d_out), heads 2,3 -> aggx_hi (workspace).
__global__ __launch_bounds__(256) void aggregate_x4_kernel(
    const _Float16* __restrict__ xs, const float* __restrict__ a_src,
    const float* __restrict__ a_dst, const int* __restrict__ offsets,
    const int* __restrict__ csr_src, _Float16* __restrict__ aggx_lo,
    _Float16* __restrict__ aggx_hi, int Ntot) {
    int w = threadIdx.x >> 6, l = threadIdx.x & 63;
    int node = blockIdx.x * 4 + w;
    if (node >= Ntot) return;  // wave-uniform exit

    __shared__ __align__(16) int sidx_sh[4][64];     // byte offsets into xs (row = 256B)
    __shared__ __align__(16) float ew_sh[4][64][4];  // per-edge per-head exp weights

    int start = offsets[node], deg = offsets[node + 1] - start;
    float4 adv = ((const float4*)a_dst)[node];
    const char* hbl = (const char*)xs + 4 * l;  // this lane's 2-channel slice

    float ds0 = 0.f, ds1 = 0.f, ds2 = 0.f, ds3 = 0.f;
    float a00 = 0.f, a01 = 0.f, a10 = 0.f, a11 = 0.f;
    float a20 = 0.f, a21 = 0.f, a30 = 0.f, a31 = 0.f;

    for (int base = 0; base < deg; base += 64) {
        int cnt = min(64, deg - base);
        if (l < cnt) {
            int s = csr_src[start + base + l];
            sidx_sh[w][l] = s * (F_IN * 2);
            float4 av = ((const float4*)a_src)[s];
            float e0 = av.x + adv.x, e1 = av.y + adv.y, e2 = av.z + adv.z, e3 = av.w + adv.w;
            e0 = fmaxf(e0, NEG_SLOPE * e0);
            e1 = fmaxf(e1, NEG_SLOPE * e1);
            e2 = fmaxf(e2, NEG_SLOPE * e2);
            e3 = fmaxf(e3, NEG_SLOPE * e3);
            float w0 = __expf(e0), w1 = __expf(e1), w2 = __expf(e2), w3 = __expf(e3);
            *(float4*)ew_sh[w][l] = make_float4(w0, w1, w2, w3);
            ds0 += w0;
            ds1 += w1;
            ds2 += w2;
            ds3 += w3;
        }
        int j = 0;
        for (; j + 3 < cnt; j += 4) {
            int4 o4 = *(const int4*)&sidx_sh[w][j];
            float4 wa = *(const float4*)ew_sh[w][j + 0];
            float4 wb = *(const float4*)ew_sh[w][j + 1];
            float4 wc = *(const float4*)ew_sh[w][j + 2];
            float4 wd = *(const float4*)ew_sh[w][j + 3];
            int p0 = *(const int*)(hbl + o4.x);
            int p1 = *(const int*)(hbl + o4.y);
            int p2 = *(const int*)(hbl + o4.z);
            int p3 = *(const int*)(hbl + o4.w);
            FMIX_LO(a00, p0, wa.x); FMIX_HI(a01, p0, wa.x);
            FMIX_LO(a10, p0, wa.y); FMIX_HI(a11, p0, wa.y);
            FMIX_LO(a20, p0, wa.z); FMIX_HI(a21, p0, wa.z);
            FMIX_LO(a30, p0, wa.w); FMIX_HI(a31, p0, wa.w);
            FMIX_LO(a00, p1, wb.x); FMIX_HI(a01, p1, wb.x);
            FMIX_LO(a10, p1, wb.y); FMIX_HI(a11, p1, wb.y);
            FMIX_LO(a20, p1, wb.z); FMIX_HI(a21, p1, wb.z);
            FMIX_LO(a30, p1, wb.w); FMIX_HI(a31, p1, wb.w);
            FMIX_LO(a00, p2, wc.x); FMIX_HI(a01, p2, wc.x);
            FMIX_LO(a10, p2, wc.y); FMIX_HI(a11, p2, wc.y);
            FMIX_LO(a20, p2, wc.z); FMIX_HI(a21, p2, wc.z);
            FMIX_LO(a30, p2, wc.w); FMIX_HI(a31, p2, wc.w);
            FMIX_LO(a00, p3, wd.x); FMIX_HI(a01, p3, wd.x);
            FMIX_LO(a10, p3, wd.y); FMIX_HI(a11, p3, wd.y);
            FMIX_LO(a20, p3, wd.z); FMIX_HI(a21, p3, wd.z);
            FMIX_LO(a30, p3, wd.w); FMIX_HI(a31, p3, wd.w);
        }
        for (; j < cnt; j++) {
            int off = sidx_sh[w][j];
            float4 wa = *(const float4*)ew_sh[w][j];
            int p0 = *(const int*)(hbl + off);
            FMIX_LO(a00, p0, wa.x); FMIX_HI(a01, p0, wa.x);
            FMIX_LO(a10, p0, wa.y); FMIX_HI(a11, p0, wa.y);
            FMIX_LO(a20, p0, wa.z); FMIX_HI(a21, p0, wa.z);
            FMIX_LO(a30, p0, wa.w); FMIX_HI(a31, p0, wa.w);
        }
    }

#pragma unroll
    for (int off = 1; off < 64; off <<= 1) {
        ds0 += __shfl_xor(ds0, off);
        ds1 += __shfl_xor(ds1, off);
        ds2 += __shfl_xor(ds2, off);
        ds3 += __shfl_xor(ds3, off);
    }

    float i0 = 1.0f / ds0, i1 = 1.0f / ds1, i2 = 1.0f / ds2, i3 = 1.0f / ds3;
    h2v hv;
    hv[0] = (_Float16)(a00 * i0);
    hv[1] = (_Float16)(a01 * i0);
    *(h2v*)(aggx_lo + (size_t)node * F_IN + 2 * l) = hv;
    hv[0] = (_Float16)(a10 * i1);
    hv[1] = (_Float16)(a11 * i1);
    *(h2v*)(aggx_lo + ((size_t)Ntot + node) * F_IN + 2 * l) = hv;
    hv[0] = (_Float16)(a20 * i2);
    hv[1] = (_Float16)(a21 * i2);
    *(h2v*)(aggx_hi + (size_t)node * F_IN + 2 * l) = hv;
    hv[0] = (_Float16)(a30 * i3);
    hv[1] = (_Float16)(a31 * i3);
    *(h2v*)(aggx_hi + ((size_t)Ntot + node) * F_IN + 2 * l) = hv;
}

// ---------------- dispatch 8: gemm1b = relu(aggx[h] @ W1[:,h] + b1) -> o1 ----------------
__global__ __launch_bounds__(256) void gemm1b_kernel(const _Float16* __restrict__ Alo,
                                                     const _Float16* __restrict__ Ahi,
                                                     const _Float16* __restrict__ Btx,
                                                     const float* __restrict__ bias,
                                                     _Float16* __restrict__ C_, int M) {
    constexpr int NT = HC1 / 16;   // 16 col tiles; head = ct>>2
    constexpr int KT = F_IN / 32;  // 4
    int w = threadIdx.x >> 6;
    int l = threadIdx.x & 63;
    int quad = l >> 4, lan = l & 15;
    int row = blockIdx.x * 64 + w * 16 + lan;
    int arow = min(row, M - 1);
    f4v acc[NT] = {};
    const _Float16* Ah0 = Alo + (size_t)arow * F_IN + quad * 8;
    const _Float16* Ah1 = Alo + ((size_t)M + arow) * F_IN + quad * 8;
    const _Float16* Ah2 = Ahi + (size_t)arow * F_IN + quad * 8;
    const _Float16* Ah3 = Ahi + ((size_t)M + arow) * F_IN + quad * 8;
#pragma unroll
    for (int k0 = 0; k0 < KT; k0++) {
        h8v af0 = *(const h8v*)(Ah0 + k0 * 32);
        h8v af1 = *(const h8v*)(Ah1 + k0 * 32);
        h8v af2 = *(const h8v*)(Ah2 + k0 * 32);
        h8v af3 = *(const h8v*)(Ah3 + k0 * 32);
#pragma unroll
        for (int ct = 0; ct < NT; ct++) {
            const _Float16* Bptr = Btx + (long)(ct * 16 + lan) * F_IN + k0 * 32 + quad * 8;
            h8v bf = *(const h8v*)Bptr;
            h8v af = (ct < 4) ? af0 : (ct < 8) ? af1 : (ct < 12) ? af2 : af3;
            acc[ct] = __builtin_amdgcn_mfma_f32_16x16x32_f16(af, bf, acc[ct], 0, 0, 0);
        }
    }
    int orow = blockIdx.x * 64 + w * 16 + quad * 4;
#pragma unroll
    for (int r = 0; r < 4; r++) {
        int gr = orow + r;
        if (gr < M) {
            _Float16* out = C_ + (long)gr * HC1 + lan;
#pragma unroll
            for (int ct = 0; ct < NT; ct++) {
                float v = acc[ct][r] + bias[ct * 16 + lan];
                out[ct * 16] = (_Float16)fmaxf(v, 0.f);
            }
        }
    }
}

// ---------------- dispatch 9: gemm2(+att2) ----------------
__global__ __launch_bounds__(256) void gemm2_kernel(const _Float16* __restrict__ A,
                                                    const _Float16* __restrict__ B2x,
                                                    _Float16* __restrict__ C_,
                                                    float* __restrict__ as_,
                                                    float* __restrict__ ad_, int M) {
    gemm_att_body<HC2, HC1>(blockIdx.x, A, B2x, C_, as_, ad_, M);
}

// ---------------- layer-2 aggregate (R1 row-major structure, x8 unroll) ----------------
template <int HC, bool RELU, typename OutT>
__global__ __launch_bounds__(256) void aggregate_kernel(
    const _Float16* __restrict__ hb, const float* __restrict__ a_src,
    const float* __restrict__ a_dst, const int* __restrict__ offsets,
    const int* __restrict__ csr_src, const float* __restrict__ bias, OutT* __restrict__ out,
    int Ntot) {
    constexpr int ACT = HC / 4;       // active gather lanes (64 or 40)
    constexpr int CHPH = HC / NHEAD;  // channels per head
    constexpr bool FULL = (ACT == 64);
    int w = threadIdx.x >> 6, l = threadIdx.x & 63;
    int node = blockIdx.x * 4 + w;
    if (node >= Ntot) return;  // wave-uniform exit

    __shared__ __align__(16) int sidx_sh[4][64];     // byte offsets into hb
    __shared__ __align__(16) float ew_sh[4][64][4];  // per-edge per-head exp weights

    int start = offsets[node], end = offsets[node + 1];
    int deg = end - start;
    float4 adv = ((const float4*)a_dst)[node];
    const int hd = min((4 * l) / CHPH, 3);
    const char* hbl = (const char*)hb + 8 * l;  // this lane's 4-channel slice

    float ds0 = 0.f, ds1 = 0.f, ds2 = 0.f, ds3 = 0.f;
    float a0 = 0.f, a1 = 0.f, a2 = 0.f, a3 = 0.f;

    for (int base = 0; base < deg; base += 64) {
        int cnt = min(64, deg - base);
        if (l < cnt) {
            int s = csr_src[start + base + l];
            sidx_sh[w][l] = s * (HC * 2);
            float4 av = ((const float4*)a_src)[s];
            float e0 = av.x + adv.x, e1 = av.y + adv.y, e2 = av.z + adv.z, e3 = av.w + adv.w;
            e0 = fmaxf(e0, NEG_SLOPE * e0);
            e1 = fmaxf(e1, NEG_SLOPE * e1);
            e2 = fmaxf(e2, NEG_SLOPE * e2);
            e3 = fmaxf(e3, NEG_SLOPE * e3);
            float w0 = __expf(e0), w1 = __expf(e1), w2 = __expf(e2), w3 = __expf(e3);
            *(float4*)ew_sh[w][l] = make_float4(w0, w1, w2, w3);
            ds0 += w0;
            ds1 += w1;
            ds2 += w2;
            ds3 += w3;
        }
        int j = 0;
        for (; j + 7 < cnt; j += 8) {
            int4 oa = *(const int4*)&sidx_sh[w][j];
            int4 ob = *(const int4*)&sidx_sh[w][j + 4];
            float w0 = ew_sh[w][j + 0][hd], w1 = ew_sh[w][j + 1][hd];
            float w2 = ew_sh[w][j + 2][hd], w3 = ew_sh[w][j + 3][hd];
            float w4 = ew_sh[w][j + 4][hd], w5 = ew_sh[w][j + 5][hd];
            float w6 = ew_sh[w][j + 6][hd], w7 = ew_sh[w][j + 7][hd];
            if (FULL || l < ACT) {
                int2 p0 = *(const int2*)(hbl + oa.x);
                int2 p1 = *(const int2*)(hbl + oa.y);
                int2 p2 = *(const int2*)(hbl + oa.z);
                int2 p3 = *(const int2*)(hbl + oa.w);
                int2 p4 = *(const int2*)(hbl + ob.x);
                int2 p5 = *(const int2*)(hbl + ob.y);
                int2 p6 = *(const int2*)(hbl + ob.z);
                int2 p7 = *(const int2*)(hbl + ob.w);
                FMIX_LO(a0, p0.x, w0); FMIX_HI(a1, p0.x, w0);
                FMIX_LO(a2, p0.y, w0); FMIX_HI(a3, p0.y, w0);
                FMIX_LO(a0, p1.x, w1); FMIX_HI(a1, p1.x, w1);
                FMIX_LO(a2, p1.y, w1); FMIX_HI(a3, p1.y, w1);
                FMIX_LO(a0, p2.x, w2); FMIX_HI(a1, p2.x, w2);
                FMIX_LO(a2, p2.y, w2); FMIX_HI(a3, p2.y, w2);
                FMIX_LO(a0, p3.x, w3); FMIX_HI(a1, p3.x, w3);
                FMIX_LO(a2, p3.y, w3); FMIX_HI(a3, p3.y, w3);
                FMIX_LO(a0, p4.x, w4); FMIX_HI(a1, p4.x, w4);
                FMIX_LO(a2, p4.y, w4); FMIX_HI(a3, p4.y, w4);
                FMIX_LO(a0, p5.x, w5); FMIX_HI(a1, p5.x, w5);
                FMIX_LO(a2, p5.y, w5); FMIX_HI(a3, p5.y, w5);
                FMIX_LO(a0, p6.x, w6); FMIX_HI(a1, p6.x, w6);
                FMIX_LO(a2, p6.y, w6); FMIX_HI(a3, p6.y, w6);
                FMIX_LO(a0, p7.x, w7); FMIX_HI(a1, p7.x, w7);
                FMIX_LO(a2, p7.y, w7); FMIX_HI(a3, p7.y, w7);
            }
        }
        for (; j + 3 < cnt; j += 4) {
            int4 o4 = *(const int4*)&sidx_sh[w][j];
            float w0 = ew_sh[w][j + 0][hd], w1 = ew_sh[w][j + 1][hd];
            float w2 = ew_sh[w][j + 2][hd], w3 = ew_sh[w][j + 3][hd];
            if (FULL || l < ACT) {
                int2 p0 = *(const int2*)(hbl + o4.x);
                int2 p1 = *(const int2*)(hbl + o4.y);
                int2 p2 = *(const int2*)(hbl + o4.z);
                int2 p3 = *(const int2*)(hbl + o4.w);
                FMIX_LO(a0, p0.x, w0); FMIX_HI(a1, p0.x, w0);
                FMIX_LO(a2, p0.y, w0); FMIX_HI(a3, p0.y, w0);
                FMIX_LO(a0, p1.x, w1); FMIX_HI(a1, p1.x, w1);
                FMIX_LO(a2, p1.y, w1); FMIX_HI(a3, p1.y, w1);
                FMIX_LO(a0, p2.x, w2); FMIX_HI(a1, p2.x, w2);
                FMIX_LO(a2, p2.y, w2); FMIX_HI(a3, p2.y, w2);
                FMIX_LO(a0, p3.x, w3); FMIX_HI(a1, p3.x, w3);
                FMIX_LO(a2, p3.y, w3); FMIX_HI(a3, p3.y, w3);
            }
        }
        for (; j < cnt; j++) {
            int off = sidx_sh[w][j];
            float w0 = ew_sh[w][j][hd];
            if (FULL || l < ACT) {
                int2 p0 = *(const int2*)(hbl + off);
                FMIX_LO(a0, p0.x, w0); FMIX_HI(a1, p0.x, w0);
                FMIX_LO(a2, p0.y, w0); FMIX_HI(a3, p0.y, w0);
            }
        }
    }

#pragma unroll
    for (int off = 1; off < 64; off <<= 1) {
        ds0 += __shfl_xor(ds0, off);
        ds1 += __shfl_xor(ds1, off);
        ds2 += __shfl_xor(ds2, off);
        ds3 += __shfl_xor(ds3, off);
    }

    if (FULL || l < ACT) {
        float dsel = hd == 0 ? ds0 : hd == 1 ? ds1 : hd == 2 ? ds2 : ds3;
        float inv = 1.0f / dsel;
        float4 bv = ((const float4*)bias)[l];
        float r0 = a0 * inv + bv.x;
        float r1 = a1 * inv + bv.y;
        float r2 = a2 * inv + bv.z;
        float r3 = a3 * inv + bv.w;
        if (RELU) {
            r0 = fmaxf(r0, 0.f);
            r1 = fmaxf(r1, 0.f);
            r2 = fmaxf(r2, 0.f);
            r3 = fmaxf(r3, 0.f);
        }
        OutT* op = out + (long)node * HC + 4 * l;
        if (sizeof(OutT) == 2) {
            h4v hv;
            hv[0] = (_Float16)r0;
            hv[1] = (_Float16)r1;
            hv[2] = (_Float16)r2;
            hv[3] = (_Float16)r3;
            *(h4v*)op = hv;
        } else {
            *(float4*)op = make_float4(r0, r1, r2, r3);
        }
    }
}

// ---------------- launch ----------------
extern "C" void kernel_launch(void* const* d_in, const int* in_sizes, int n_in, void* d_out,
                              int out_size, void* d_ws, size_t ws_size, hipStream_t stream) {
    const float* x = (const float*)d_in[0];
    const void* ei = d_in[1];
    const float* W1 = (const float*)d_in[2];
    const float* attS1 = (const float*)d_in[3];
    const float* attD1 = (const float*)d_in[4];
    const float* b1 = (const float*)d_in[5];
    const float* W2 = (const float*)d_in[6];
    const float* attS2 = (const float*)d_in[7];
    const float* attD2 = (const float*)d_in[8];
    const float* b2 = (const float*)d_in[9];
    float* out = (float*)d_out;

    int N = in_sizes[0] / F_IN;  // 50000
    int E = in_sizes[1] / 2;     // 800000
    int nb = (N + 255) / 256;    // 196
    int nw = (N + 3) / 4;        // wave-per-node aggregate grid

    _Float16* xs_h = (_Float16*)d_ws;             // N*128
    _Float16* o1h = xs_h + (size_t)N * F_IN;      // N*256 (counts_x overlays early)
    _Float16* hb2 = o1h + (size_t)N * HC1;        // N*160 (pos[] overlays early)
    _Float16* aggx_hi = hb2 + (size_t)N * HC2;    // N*256 (heads 2,3 of aggx)
    _Float16* B1x = aggx_hi + (size_t)N * HC1;    // 272*128
    _Float16* B2x = B1x + (HC1 + 16) * F_IN;      // 176*256
    float* as1 = (float*)(B2x + (HC2 + 16) * HC1);
    float* ad1 = as1 + (size_t)N * NHEAD;
    float* as2 = ad1 + (size_t)N * NHEAD;
    float* ad2 = as2 + (size_t)N * NHEAD;
    float* stats = ad2 + (size_t)N * NHEAD;       // 256 (zeroed in detect_kernel)
    int* offsets = (int*)(stats + 256);           // N+1 (pad 4)
    int* csr = offsets + (N + 4);                 // E+N
    int* blocksum = csr + (E + N);                // 256
    int* mode = blocksum + 256;                   // 1
    int* pos = (int*)hb2;      // E ints; dead before gemm2 writes hb2
    int* counts_x = (int*)o1h; // NBANK*N ints; dead before gemm1b writes o1h
    _Float16* aggx_lo = (_Float16*)d_out;  // heads 0,1 (25.6MB <= 32MB out buffer;
                                           // fully overwritten by final aggregate)

    int nbCnt = (E + 255) / 256;                         // 3125
    constexpr int TCV = (HC1 + 16) * F_IN + (HC2 + 16) * HC1;
    int nbConv = (TCV + 255) / 256;                      // 143
    int total4 = N * F_IN / 4;
    int nbStd = (total4 + 255) / 256;                    // 6250
    int nbFill = (E + N + 255) / 256;                    // 3321
    int nbG1 = (N + 63) / 64;                            // 782

    // 1. zero per-XCD histograms (stats is zeroed inside detect_kernel)
    hipMemsetAsync(counts_x, 0, (size_t)NBANK * N * sizeof(int), stream);
    // 2. detect edge dtype + zero stats
    detect_kernel<<<1, 256, 0, stream>>>((const unsigned int*)ei, mode, stats);
    // 3. fused: count | colstats | convert_w
    fused_pre_kernel<<<nbCnt + nb + nbConv, 256, 0, stream>>>(
        ei, mode, E, counts_x, pos, x, stats, N, W1, attS1, attD1, B1x, W2, attS2, attD2, B2x,
        nbCnt, nb);
    // 4. fused: standardize | scan_block (bank prefix + node scan)
    fused_mid_kernel<<<nbStd + nb, 256, 0, stream>>>(x, stats, xs_h, total4, 1.0f / (float)N,
                                                     1.0f / (float)(N - 1), counts_x, offsets,
                                                     blocksum, N, nbStd);
    // 5. scan_add
    scan_add_kernel<<<nb, 256, 0, stream>>>(blocksum, offsets, N, nb);
    // 6. fused: fill_csr | att1 (as1/ad1 = xs @ B1x-att-cols)
    fused_fill_att1_kernel<<<nbFill + nbG1, 256, 0, stream>>>(ei, mode, E, N, offsets, pos,
                                                              counts_x, csr, nbFill, xs_h, B1x,
                                                              as1, ad1);
    // 7. per-head aggregate in xs-space
    aggregate_x4_kernel<<<nw, 256, 0, stream>>>(xs_h, as1, ad1, offsets, csr, aggx_lo, aggx_hi,
                                                N);
    // 8. gemm1b: o1[:, h*64:+64] = relu(aggx[h] @ W1[:, h*64:+64] + b1)
    gemm1b_kernel<<<nbG1, 256, 0, stream>>>(aggx_lo, aggx_hi, B1x, b1, o1h, N);
    // 9. gemm2(+att2)
    gemm2_kernel<<<nbG1, 256, 0, stream>>>(o1h, B2x, hb2, as2, ad2, N);
    // 10. aggregate layer 2
    aggregate_kernel<HC2, false, float>
        <<<nw, 256, 0, stream>>>(hb2, as2, ad2, offsets, csr, b2, out, N);
}

// Round 5
// 341.387 us; speedup vs baseline: 1.6441x; 1.0556x over previous
//
#include <hip/hip_runtime.h>
#include <math.h>

#define NEG_SLOPE 0.2f

constexpr int F_IN  = 128;
constexpr int HC1   = 256;  // H*HID
constexpr int HC2   = 160;  // H*CLS
constexpr int NHEAD = 4;
constexpr int EB    = 2048; // edges per level-1 block
constexpr int NPB   = 128;  // nodes per bucket
constexpr int BCAP  = 4096; // bucket capacity (avg 2046 @ E=800k; Poisson tail safe)

typedef _Float16 h8v __attribute__((ext_vector_type(8)));
typedef _Float16 h4v __attribute__((ext_vector_type(4)));
typedef _Float16 h2v __attribute__((ext_vector_type(2)));
typedef float f4v __attribute__((ext_vector_type(4)));

// f32 += f16(lo/hi of packed) * f32 — single VOP3P instruction
#define FMIX_LO(acc, pk, wt) \
    asm("v_fma_mix_f32 %0, %1, %2, %0 op_sel:[0,0,0] op_sel_hi:[1,0,0]" \
        : "+v"(acc) : "v"(pk), "v"(wt))
#define FMIX_HI(acc, pk, wt) \
    asm("v_fma_mix_f32 %0, %1, %2, %0 op_sel:[1,0,0] op_sel_hi:[1,0,0]" \
        : "+v"(acc) : "v"(pk), "v"(wt))

__device__ __forceinline__ int edge_val(const void* p, int m64, long long i) {
    if (m64) return (int)((const long long*)p)[i];
    return ((const int*)p)[i];
}

// ---------------- dispatch 1: edge dtype detect (+ zero stats) ----------------
__global__ void detect_kernel(const unsigned int* __restrict__ ei_words, int* __restrict__ mode,
                              float* __restrict__ stats) {
    stats[threadIdx.x] = 0.f;  // 256 threads zero 256 floats (sum|sumsq)
    __shared__ unsigned int red[256];
    unsigned int v = 0;
    for (int i = 1 + 2 * (int)threadIdx.x; i < 4096; i += 512) v |= ei_words[i];
    red[threadIdx.x] = v;
    __syncthreads();
    for (int off = 128; off > 0; off >>= 1) {
        if (threadIdx.x < off) red[threadIdx.x] |= red[threadIdx.x + off];
        __syncthreads();
    }
    if (threadIdx.x == 0) *mode = (red[0] == 0u) ? 1 : 0;
}

// ---------------- dispatch 2 (fused): bucket-hist | colstats | convert_w ----------------
// hist: LDS histogram of dst>>7 per 2048-edge block (non-returning ds_add), written
// bucket-major hist[bucket][blk]. NO far atomics anywhere in the new CSR build.
__global__ __launch_bounds__(256) void fused_pre_kernel(
    const void* __restrict__ ei, const int* __restrict__ mode, int E, int nbuck, int nblk1,
    int* __restrict__ hist, const float* __restrict__ x, float* __restrict__ stats, int N,
    const float* __restrict__ W1, const float* __restrict__ aS1, const float* __restrict__ aD1,
    _Float16* __restrict__ B1x, const float* __restrict__ W2, const float* __restrict__ aS2,
    const float* __restrict__ aD2, _Float16* __restrict__ B2x, int nbStats) {
    int b = blockIdx.x;
    if (b < nblk1) {
        // ---- level-1 histogram ----
        __shared__ int lh[512];
        for (int i = threadIdx.x; i < nbuck; i += 256) lh[i] = 0;
        __syncthreads();
        int m = *mode;
        long long e0 = (long long)b * EB;
#pragma unroll
        for (int k = 0; k < EB / 256; k++) {
            long long e = e0 + (int)threadIdx.x + k * 256;
            if (e < E) {
                int d = edge_val(ei, m, (long long)E + e);
                atomicAdd(&lh[d >> 7], 1);
            }
        }
        __syncthreads();
        for (int i = threadIdx.x; i < nbuck; i += 256) hist[(size_t)i * nblk1 + b] = lh[i];
    } else if (b < nblk1 + nbStats) {
        // ---- colstats: float4 loads, 32 iters/thread, LDS-reduce 8 row groups ----
        int t = (int)threadIdx.x;
        int c = t & 31;   // handles cols 4c..4c+3
        int g = t >> 5;   // row subgroup 0..7
        int r0 = (b - nblk1) * 256;
        int rend = min(r0 + 256, N);
        f4v s = {0.f, 0.f, 0.f, 0.f}, q = {0.f, 0.f, 0.f, 0.f};
        for (int r = r0 + g; r < rend; r += 8) {
            f4v v = *(const f4v*)&x[(long)r * F_IN + 4 * c];
            s += v;
            q += v * v;
        }
        __shared__ f4v sh4[256];
        sh4[t] = s;
        __syncthreads();
        if (t < 32) {
            f4v a = sh4[t];
            for (int g2 = 1; g2 < 8; g2++) a += sh4[g2 * 32 + t];
            atomicAdd(&stats[4 * t + 0], a[0]);
            atomicAdd(&stats[4 * t + 1], a[1]);
            atomicAdd(&stats[4 * t + 2], a[2]);
            atomicAdd(&stats[4 * t + 3], a[3]);
        }
        __syncthreads();
        sh4[t] = q;
        __syncthreads();
        if (t < 32) {
            f4v a = sh4[t];
            for (int g2 = 1; g2 < 8; g2++) a += sh4[g2 * 32 + t];
            atomicAdd(&stats[128 + 4 * t + 0], a[0]);
            atomicAdd(&stats[128 + 4 * t + 1], a[1]);
            atomicAdd(&stats[128 + 4 * t + 2], a[2]);
            atomicAdd(&stats[128 + 4 * t + 3], a[3]);
        }
    } else {
        // ---- convert weights -> fp16 transposed + att columns ----
        constexpr int T1 = (HC1 + 16) * F_IN;
        constexpr int T2 = (HC2 + 16) * HC1;
        int idx = (b - nblk1 - nbStats) * 256 + (int)threadIdx.x;
        if (idx < T1) {
            int n = idx / F_IN, k = idx - n * F_IN;
            float v = 0.f;
            if (n < HC1) {
                v = W1[k * HC1 + n];
            } else {
                int n2 = n - HC1;
                if (n2 < 8) {
                    int hd = n2 & 3;
                    const float* a = (n2 < 4) ? aS1 : aD1;
                    for (int c = 0; c < 64; c++) v += W1[k * HC1 + hd * 64 + c] * a[hd * 64 + c];
                }
            }
            B1x[n * F_IN + k] = (_Float16)v;
        } else if (idx < T1 + T2) {
            int i2 = idx - T1;
            int n = i2 / HC1, k = i2 - n * HC1;
            float v = 0.f;
            if (n < HC2) {
                v = W2[k * HC2 + n];
            } else {
                int n2 = n - HC2;
                if (n2 < 8) {
                    int hd = n2 & 3;
                    const float* a = (n2 < 4) ? aS2 : aD2;
                    for (int c = 0; c < 40; c++) v += W2[k * HC2 + hd * 40 + c] * a[hd * 40 + c];
                }
            }
            B2x[n * HC1 + k] = (_Float16)v;
        }
    }
}

// ---------------- dispatch 3 (fused): standardize | bucket col-scan ----------------
__global__ __launch_bounds__(256) void fused_mid_kernel(
    const float* __restrict__ x, const float* __restrict__ stats, _Float16* __restrict__ xs,
    int total4, float invN, float invN1, const int* __restrict__ hist,
    int* __restrict__ colBaseT, int* __restrict__ bucketTotal, int nbuck, int nblk1,
    int nbStd) {
    int b = blockIdx.x;
    if (b < nbStd) {
        int i = b * 256 + (int)threadIdx.x;
        if (i >= total4) return;
        int c = (i * 4) & (F_IN - 1);
        float4 s4 = *(const float4*)&stats[c];
        float4 q4 = *(const float4*)&stats[128 + c];
        float4 v = ((const float4*)x)[i];
        h4v o;
        o[0] = (_Float16)((v.x - s4.x * invN) / sqrtf((q4.x - s4.x * s4.x * invN) * invN1));
        o[1] = (_Float16)((v.y - s4.y * invN) / sqrtf((q4.y - s4.y * s4.y * invN) * invN1));
        o[2] = (_Float16)((v.z - s4.z * invN) / sqrtf((q4.z - s4.z * s4.z * invN) * invN1));
        o[3] = (_Float16)((v.w - s4.w * invN) / sqrtf((q4.w - s4.w * s4.w * invN) * invN1));
        ((h4v*)xs)[i] = o;
    } else {
        // col-scan: exclusive prefix over blocks of hist[bb][*]; write transposed
        // colBaseT[blk][bb] for coalesced level-1 scatter reads; total -> bucketTotal.
        int bb = b - nbStd;
        int t = (int)threadIdx.x;
        __shared__ int sh[512];
        __shared__ int wsum[4];
        for (int i = t; i < nblk1; i += 256) sh[i] = hist[(size_t)bb * nblk1 + i];
        __syncthreads();
        int carry = 0;
        for (int base = 0; base < nblk1; base += 256) {
            int idx = base + t;
            int v = (idx < nblk1) ? sh[idx] : 0;
            int lane = t & 63, w = t >> 6;
            int xv = v;
#pragma unroll
            for (int d = 1; d < 64; d <<= 1) {
                int y = __shfl_up(xv, d);
                if (lane >= d) xv += y;
            }
            if (lane == 63) wsum[w] = xv;
            __syncthreads();
            int wb = 0;
            for (int k = 0; k < w; k++) wb += wsum[k];
            int excl = xv - v + wb + carry;
            if (idx < nblk1) colBaseT[(size_t)idx * nbuck + bb] = excl;
            carry += wsum[0] + wsum[1] + wsum[2] + wsum[3];
            __syncthreads();
        }
        if (t == 0) bucketTotal[bb] = carry;
    }
}

// ---------------- dispatch 4: level-1 scatter into bucket regions ----------------
__global__ __launch_bounds__(256) void scatter1_kernel(const void* __restrict__ ei,
                                                       const int* __restrict__ mode, int E,
                                                       int nbuck,
                                                       const int* __restrict__ colBaseT,
                                                       int* __restrict__ bucketEdges) {
    __shared__ int cur[512];
    int b = blockIdx.x;
    for (int i = threadIdx.x; i < nbuck; i += 256)
        cur[i] = colBaseT[(size_t)b * nbuck + i];
    __syncthreads();
    int m = *mode;
    long long e0 = (long long)b * EB;
#pragma unroll
    for (int k = 0; k < EB / 256; k++) {
        long long e = e0 + (int)threadIdx.x + k * 256;
        if (e < E) {
            int s = edge_val(ei, m, e);
            int d = edge_val(ei, m, (long long)E + e);
            int bk = d >> 7;
            int r = atomicAdd(&cur[bk], 1);  // LDS returning atomic (fast)
            bucketEdges[(size_t)bk * BCAP + r] = s | ((d & (NPB - 1)) << 16);
        }
    }
}

// ---------------- dispatch 5: per-bucket node counts (exclusive node ownership) ----------------
__global__ __launch_bounds__(256) void bucket_count_kernel(const int* __restrict__ bucketEdges,
                                                           const int* __restrict__ bucketTotal,
                                                           int* __restrict__ counts, int N) {
    __shared__ int c[NPB];
    int b = blockIdx.x, t = threadIdx.x;
    if (t < NPB) c[t] = 0;
    __syncthreads();
    int cnt = bucketTotal[b];
    const int* be = bucketEdges + (size_t)b * BCAP;
    for (int i = t; i < cnt; i += 256) atomicAdd(&c[(be[i] >> 16) & (NPB - 1)], 1);
    __syncthreads();
    int node = b * NPB + t;
    if (t < NPB && node < N) counts[node] = c[t];  // non-atomic: bucket owns these nodes
}

// ---------------- dispatch 6: scan_block (counts+1 -> block-local inclusive) ----------------
__global__ __launch_bounds__(256) void scan_block_kernel(const int* __restrict__ counts,
                                                         int* __restrict__ offsets,
                                                         int* __restrict__ blocksum, int N) {
    int t = threadIdx.x;
    int i = blockIdx.x * 256 + t;
    int v = (i < N) ? counts[i] + 1 : 0;
    int lane = t & 63, w = t >> 6;
    int xv = v;
#pragma unroll
    for (int d = 1; d < 64; d <<= 1) {
        int y = __shfl_up(xv, d);
        if (lane >= d) xv += y;
    }
    __shared__ int wsum[4];
    if (lane == 63) wsum[w] = xv;
    __syncthreads();
    int base = 0;
    for (int k = 0; k < w; k++) base += wsum[k];
    int incl = xv + base;
    if (i < N) offsets[i + 1] = incl;
    if (t == 255) blocksum[blockIdx.x] = incl;
}

// ---------------- dispatch 7: scan_add ----------------
__global__ void scan_add_kernel(const int* __restrict__ blocksum, int* __restrict__ offsets, int N,
                                int nb) {
    int t = threadIdx.x;
    int v = (t < nb) ? blocksum[t] : 0;
    int lane = t & 63, w = t >> 6;
    int x = v;
#pragma unroll
    for (int d = 1; d < 64; d <<= 1) {
        int y = __shfl_up(x, d);
        if (lane >= d) x += y;
    }
    __shared__ int wsum[4];
    __shared__ int excl[256];
    if (lane == 63) wsum[w] = x;
    __syncthreads();
    int base = 0;
    for (int k = 0; k < w; k++) base += wsum[k];
    excl[t] = x + base - v;
    __syncthreads();
    int myb = excl[blockIdx.x];
    int i = blockIdx.x * 256 + t;
    if (i < N) offsets[i + 1] += myb;
    if (i == 0) offsets[0] = 0;
}

// ---------------- MFMA f16 GEMM body (row-major C + fused att scores) ----------------
template <int Nc, int K>
__device__ __forceinline__ void gemm_att_body(int blk, const _Float16* __restrict__ A,
                                              const _Float16* __restrict__ Btx,
                                              _Float16* __restrict__ C_, float* __restrict__ as_,
                                              float* __restrict__ ad_, int M) {
    constexpr int NT = Nc / 16;
    constexpr int NTT = NT + 1;
    constexpr int KT = K / 32;
    int w = threadIdx.x >> 6;
    int l = threadIdx.x & 63;
    int quad = l >> 4, lan = l & 15;
    int row = blk * 64 + w * 16 + lan;
    int arow = min(row, M - 1);
    f4v acc[NTT] = {};
    const _Float16* Aptr = A + (long)arow * K + quad * 8;
#pragma unroll
    for (int k0 = 0; k0 < KT; k0++) {
        h8v af = *(const h8v*)(Aptr + k0 * 32);
#pragma unroll
        for (int ct = 0; ct < NTT; ct++) {
            const _Float16* Bptr = Btx + (long)(ct * 16 + lan) * K + k0 * 32 + quad * 8;
            h8v bf = *(const h8v*)Bptr;
            acc[ct] = __builtin_amdgcn_mfma_f32_16x16x32_f16(af, bf, acc[ct], 0, 0, 0);
        }
    }
    int orow = blk * 64 + w * 16 + quad * 4;
#pragma unroll
    for (int r = 0; r < 4; r++) {
        int gr = orow + r;
        if (gr < M) {
            _Float16* out = C_ + (long)gr * Nc + lan;
#pragma unroll
            for (int ct = 0; ct < NT; ct++) out[ct * 16] = (_Float16)acc[ct][r];
            float av = acc[NTT - 1][r];
            if (lan < 4)
                as_[gr * 4 + lan] = av;
            else if (lan < 8)
                ad_[gr * 4 + lan - 4] = av;
        }
    }
}

// ---------------- att1 mini-GEMM: as1/ad1 = xs @ (W1·att) (8 cols) ----------------
__device__ __forceinline__ void att1_body(int blk, const _Float16* __restrict__ A,
                                          const _Float16* __restrict__ Batt,
                                          float* __restrict__ as_, float* __restrict__ ad_,
                                          int M) {
    int w = threadIdx.x >> 6;
    int l = threadIdx.x & 63;
    int quad = l >> 4, lan = l & 15;
    int row = blk * 64 + w * 16 + lan;
    int arow = min(row, M - 1);
    f4v acc = {0.f, 0.f, 0.f, 0.f};
    const _Float16* Aptr = A + (long)arow * F_IN + quad * 8;
#pragma unroll
    for (int k0 = 0; k0 < F_IN / 32; k0++) {
        h8v af = *(const h8v*)(Aptr + k0 * 32);
        h8v bf = *(const h8v*)(Batt + (long)lan * F_IN + k0 * 32 + quad * 8);
        acc = __builtin_amdgcn_mfma_f32_16x16x32_f16(af, bf, acc, 0, 0, 0);
    }
    int orow = blk * 64 + w * 16 + quad * 4;
#pragma unroll
    for (int r = 0; r < 4; r++) {
        int gr = orow + r;
        if (gr < M) {
            float av = acc[r];
            if (lan < 4)
                as_[gr * 4 + lan] = av;
            else if (lan < 8)
                ad_[gr * 4 + lan - 4] = av;
        }
    }
}

// ---------------- dispatch 8 (fused): csr-scatter | att1 ----------------
__global__ __launch_bounds__(256) void fused_csr_att1_kernel(
    const int* __restrict__ bucketEdges, const int* __restrict__ bucketTotal,
    const int* __restrict__ offsets, int* __restrict__ csr, int N, int nbuck,
    const _Float16* __restrict__ xs, const _Float16* __restrict__ B1x,
    float* __restrict__ as_, float* __restrict__ ad_) {
    int b = blockIdx.x;
    if (b < nbuck) {
        __shared__ int cur[NPB];
        int t = threadIdx.x;
        int node = b * NPB + t;
        if (t < NPB && node < N) {
            int off = offsets[node];
            csr[off] = node;  // self loop at slot 0
            cur[t] = off + 1;
        }
        __syncthreads();
        int cnt = bucketTotal[b];
        const int* be = bucketEdges + (size_t)b * BCAP;
        for (int i = t; i < cnt; i += 256) {
            int v = be[i];
            int pos = atomicAdd(&cur[(v >> 16) & (NPB - 1)], 1);  // LDS returning atomic
            csr[pos] = v & 0xFFFF;
        }
    } else {
        att1_body(b - nbuck, xs, B1x + (size_t)HC1 * F_IN, as_, ad_, N);
    }
}

// ---------------- dispatch 9: per-head layer-1 aggregate in xs-space ----------------
__global__ __launch_bounds__(256) void aggregate_x4_kernel(
    const _Float16* __restrict__ xs, const float* __restrict__ a_src,
    const float* __restrict__ a_dst, const int* __restrict__ offsets,
    const int* __restrict__ csr_src, _Float16* __restrict__ aggx_lo,
    _Float16* __restrict__ aggx_hi, int Ntot) {
    int w = threadIdx.x >> 6, l = threadIdx.x & 63;
    int node = blockIdx.x * 4 + w;
    if (node >= Ntot) return;  // wave-uniform exit

    __shared__ __align__(16) int sidx_sh[4][64];     // byte offsets into xs (row = 256B)
    __shared__ __align__(16) float ew_sh[4][64][4];  // per-edge per-head exp weights

    int start = offsets[node], deg = offsets[node + 1] - start;
    float4 adv = ((const float4*)a_dst)[node];
    const char* hbl = (const char*)xs + 4 * l;  // this lane's 2-channel slice

    float ds0 = 0.f, ds1 = 0.f, ds2 = 0.f, ds3 = 0.f;
    float a00 = 0.f, a01 = 0.f, a10 = 0.f, a11 = 0.f;
    float a20 = 0.f, a21 = 0.f, a30 = 0.f, a31 = 0.f;

    for (int base = 0; base < deg; base += 64) {
        int cnt = min(64, deg - base);
        if (l < cnt) {
            int s = csr_src[start + base + l];
            sidx_sh[w][l] = s * (F_IN * 2);
            float4 av = ((const float4*)a_src)[s];
            float e0 = av.x + adv.x, e1 = av.y + adv.y, e2 = av.z + adv.z, e3 = av.w + adv.w;
            e0 = fmaxf(e0, NEG_SLOPE * e0);
            e1 = fmaxf(e1, NEG_SLOPE * e1);
            e2 = fmaxf(e2, NEG_SLOPE * e2);
            e3 = fmaxf(e3, NEG_SLOPE * e3);
            float w0 = __expf(e0), w1 = __expf(e1), w2 = __expf(e2), w3 = __expf(e3);
            *(float4*)ew_sh[w][l] = make_float4(w0, w1, w2, w3);
            ds0 += w0;
            ds1 += w1;
            ds2 += w2;
            ds3 += w3;
        }
        int j = 0;
        for (; j + 3 < cnt; j += 4) {
            int4 o4 = *(const int4*)&sidx_sh[w][j];
            float4 wa = *(const float4*)ew_sh[w][j + 0];
            float4 wb = *(const float4*)ew_sh[w][j + 1];
            float4 wc = *(const float4*)ew_sh[w][j + 2];
            float4 wd = *(const float4*)ew_sh[w][j + 3];
            int p0 = *(const int*)(hbl + o4.x);
            int p1 = *(const int*)(hbl + o4.y);
            int p2 = *(const int*)(hbl + o4.z);
            int p3 = *(const int*)(hbl + o4.w);
            FMIX_LO(a00, p0, wa.x); FMIX_HI(a01, p0, wa.x);
            FMIX_LO(a10, p0, wa.y); FMIX_HI(a11, p0, wa.y);
            FMIX_LO(a20, p0, wa.z); FMIX_HI(a21, p0, wa.z);
            FMIX_LO(a30, p0, wa.w); FMIX_HI(a31, p0, wa.w);
            FMIX_LO(a00, p1, wb.x); FMIX_HI(a01, p1, wb.x);
            FMIX_LO(a10, p1, wb.y); FMIX_HI(a11, p1, wb.y);
            FMIX_LO(a20, p1, wb.z); FMIX_HI(a21, p1, wb.z);
            FMIX_LO(a30, p1, wb.w); FMIX_HI(a31, p1, wb.w);
            FMIX_LO(a00, p2, wc.x); FMIX_HI(a01, p2, wc.x);
            FMIX_LO(a10, p2, wc.y); FMIX_HI(a11, p2, wc.y);
            FMIX_LO(a20, p2, wc.z); FMIX_HI(a21, p2, wc.z);
            FMIX_LO(a30, p2, wc.w); FMIX_HI(a31, p2, wc.w);
            FMIX_LO(a00, p3, wd.x); FMIX_HI(a01, p3, wd.x);
            FMIX_LO(a10, p3, wd.y); FMIX_HI(a11, p3, wd.y);
            FMIX_LO(a20, p3, wd.z); FMIX_HI(a21, p3, wd.z);
            FMIX_LO(a30, p3, wd.w); FMIX_HI(a31, p3, wd.w);
        }
        for (; j < cnt; j++) {
            int off = sidx_sh[w][j];
            float4 wa = *(const float4*)ew_sh[w][j];
            int p0 = *(const int*)(hbl + off);
            FMIX_LO(a00, p0, wa.x); FMIX_HI(a01, p0, wa.x);
            FMIX_LO(a10, p0, wa.y); FMIX_HI(a11, p0, wa.y);
            FMIX_LO(a20, p0, wa.z); FMIX_HI(a21, p0, wa.z);
            FMIX_LO(a30, p0, wa.w); FMIX_HI(a31, p0, wa.w);
        }
    }

#pragma unroll
    for (int off = 1; off < 64; off <<= 1) {
        ds0 += __shfl_xor(ds0, off);
        ds1 += __shfl_xor(ds1, off);
        ds2 += __shfl_xor(ds2, off);
        ds3 += __shfl_xor(ds3, off);
    }

    float i0 = 1.0f / ds0, i1 = 1.0f / ds1, i2 = 1.0f / ds2, i3 = 1.0f / ds3;
    h2v hv;
    hv[0] = (_Float16)(a00 * i0);
    hv[1] = (_Float16)(a01 * i0);
    *(h2v*)(aggx_lo + (size_t)node * F_IN + 2 * l) = hv;
    hv[0] = (_Float16)(a10 * i1);
    hv[1] = (_Float16)(a11 * i1);
    *(h2v*)(aggx_lo + ((size_t)Ntot + node) * F_IN + 2 * l) = hv;
    hv[0] = (_Float16)(a20 * i2);
    hv[1] = (_Float16)(a21 * i2);
    *(h2v*)(aggx_hi + (size_t)node * F_IN + 2 * l) = hv;
    hv[0] = (_Float16)(a30 * i3);
    hv[1] = (_Float16)(a31 * i3);
    *(h2v*)(aggx_hi + ((size_t)Ntot + node) * F_IN + 2 * l) = hv;
}

// ---------------- dispatch 10: gemm1b = relu(aggx[h] @ W1[:,h] + b1) -> o1 ----------------
__global__ __launch_bounds__(256) void gemm1b_kernel(const _Float16* __restrict__ Alo,
                                                     const _Float16* __restrict__ Ahi,
                                                     const _Float16* __restrict__ Btx,
                                                     const float* __restrict__ bias,
                                                     _Float16* __restrict__ C_, int M) {
    constexpr int NT = HC1 / 16;   // 16 col tiles; head = ct>>2
    constexpr int KT = F_IN / 32;  // 4
    int w = threadIdx.x >> 6;
    int l = threadIdx.x & 63;
    int quad = l >> 4, lan = l & 15;
    int row = blockIdx.x * 64 + w * 16 + lan;
    int arow = min(row, M - 1);
    f4v acc[NT] = {};
    const _Float16* Ah0 = Alo + (size_t)arow * F_IN + quad * 8;
    const _Float16* Ah1 = Alo + ((size_t)M + arow) * F_IN + quad * 8;
    const _Float16* Ah2 = Ahi + (size_t)arow * F_IN + quad * 8;
    const _Float16* Ah3 = Ahi + ((size_t)M + arow) * F_IN + quad * 8;
#pragma unroll
    for (int k0 = 0; k0 < KT; k0++) {
        h8v af0 = *(const h8v*)(Ah0 + k0 * 32);
        h8v af1 = *(const h8v*)(Ah1 + k0 * 32);
        h8v af2 = *(const h8v*)(Ah2 + k0 * 32);
        h8v af3 = *(const h8v*)(Ah3 + k0 * 32);
#pragma unroll
        for (int ct = 0; ct < NT; ct++) {
            const _Float16* Bptr = Btx + (long)(ct * 16 + lan) * F_IN + k0 * 32 + quad * 8;
            h8v bf = *(const h8v*)Bptr;
            h8v af = (ct < 4) ? af0 : (ct < 8) ? af1 : (ct < 12) ? af2 : af3;
            acc[ct] = __builtin_amdgcn_mfma_f32_16x16x32_f16(af, bf, acc[ct], 0, 0, 0);
        }
    }
    int orow = blockIdx.x * 64 + w * 16 + quad * 4;
#pragma unroll
    for (int r = 0; r < 4; r++) {
        int gr = orow + r;
        if (gr < M) {
            _Float16* out = C_ + (long)gr * HC1 + lan;
#pragma unroll
            for (int ct = 0; ct < NT; ct++) {
                float v = acc[ct][r] + bias[ct * 16 + lan];
                out[ct * 16] = (_Float16)fmaxf(v, 0.f);
            }
        }
    }
}

// ---------------- dispatch 11: gemm2(+att2) ----------------
__global__ __launch_bounds__(256) void gemm2_kernel(const _Float16* __restrict__ A,
                                                    const _Float16* __restrict__ B2x,
                                                    _Float16* __restrict__ C_,
                                                    float* __restrict__ as_,
                                                    float* __restrict__ ad_, int M) {
    gemm_att_body<HC2, HC1>(blockIdx.x, A, B2x, C_, as_, ad_, M);
}

// ---------------- layer-2 aggregate (R1 row-major structure, x8 unroll) ----------------
template <int HC, bool RELU, typename OutT>
__global__ __launch_bounds__(256) void aggregate_kernel(
    const _Float16* __restrict__ hb, const float* __restrict__ a_src,
    const float* __restrict__ a_dst, const int* __restrict__ offsets,
    const int* __restrict__ csr_src, const float* __restrict__ bias, OutT* __restrict__ out,
    int Ntot) {
    constexpr int ACT = HC / 4;       // active gather lanes (64 or 40)
    constexpr int CHPH = HC / NHEAD;  // channels per head
    constexpr bool FULL = (ACT == 64);
    int w = threadIdx.x >> 6, l = threadIdx.x & 63;
    int node = blockIdx.x * 4 + w;
    if (node >= Ntot) return;  // wave-uniform exit

    __shared__ __align__(16) int sidx_sh[4][64];     // byte offsets into hb
    __shared__ __align__(16) float ew_sh[4][64][4];  // per-edge per-head exp weights

    int start = offsets[node], end = offsets[node + 1];
    int deg = end - start;
    float4 adv = ((const float4*)a_dst)[node];
    const int hd = min((4 * l) / CHPH, 3);
    const char* hbl = (const char*)hb + 8 * l;  // this lane's 4-channel slice

    float ds0 = 0.f, ds1 = 0.f, ds2 = 0.f, ds3 = 0.f;
    float a0 = 0.f, a1 = 0.f, a2 = 0.f, a3 = 0.f;

    for (int base = 0; base < deg; base += 64) {
        int cnt = min(64, deg - base);
        if (l < cnt) {
            int s = csr_src[start + base + l];
            sidx_sh[w][l] = s * (HC * 2);
            float4 av = ((const float4*)a_src)[s];
            float e0 = av.x + adv.x, e1 = av.y + adv.y, e2 = av.z + adv.z, e3 = av.w + adv.w;
            e0 = fmaxf(e0, NEG_SLOPE * e0);
            e1 = fmaxf(e1, NEG_SLOPE * e1);
            e2 = fmaxf(e2, NEG_SLOPE * e2);
            e3 = fmaxf(e3, NEG_SLOPE * e3);
            float w0 = __expf(e0), w1 = __expf(e1), w2 = __expf(e2), w3 = __expf(e3);
            *(float4*)ew_sh[w][l] = make_float4(w0, w1, w2, w3);
            ds0 += w0;
            ds1 += w1;
            ds2 += w2;
            ds3 += w3;
        }
        int j = 0;
        for (; j + 7 < cnt; j += 8) {
            int4 oa = *(const int4*)&sidx_sh[w][j];
            int4 ob = *(const int4*)&sidx_sh[w][j + 4];
            float w0 = ew_sh[w][j + 0][hd], w1 = ew_sh[w][j + 1][hd];
            float w2 = ew_sh[w][j + 2][hd], w3 = ew_sh[w][j + 3][hd];
            float w4 = ew_sh[w][j + 4][hd], w5 = ew_sh[w][j + 5][hd];
            float w6 = ew_sh[w][j + 6][hd], w7 = ew_sh[w][j + 7][hd];
            if (FULL || l < ACT) {
                int2 p0 = *(const int2*)(hbl + oa.x);
                int2 p1 = *(const int2*)(hbl + oa.y);
                int2 p2 = *(const int2*)(hbl + oa.z);
                int2 p3 = *(const int2*)(hbl + oa.w);
                int2 p4 = *(const int2*)(hbl + ob.x);
                int2 p5 = *(const int2*)(hbl + ob.y);
                int2 p6 = *(const int2*)(hbl + ob.z);
                int2 p7 = *(const int2*)(hbl + ob.w);
                FMIX_LO(a0, p0.x, w0); FMIX_HI(a1, p0.x, w0);
                FMIX_LO(a2, p0.y, w0); FMIX_HI(a3, p0.y, w0);
                FMIX_LO(a0, p1.x, w1); FMIX_HI(a1, p1.x, w1);
                FMIX_LO(a2, p1.y, w1); FMIX_HI(a3, p1.y, w1);
                FMIX_LO(a0, p2.x, w2); FMIX_HI(a1, p2.x, w2);
                FMIX_LO(a2, p2.y, w2); FMIX_HI(a3, p2.y, w2);
                FMIX_LO(a0, p3.x, w3); FMIX_HI(a1, p3.x, w3);
                FMIX_LO(a2, p3.y, w3); FMIX_HI(a3, p3.y, w3);
                FMIX_LO(a0, p4.x, w4); FMIX_HI(a1, p4.x, w4);
                FMIX_LO(a2, p4.y, w4); FMIX_HI(a3, p4.y, w4);
                FMIX_LO(a0, p5.x, w5); FMIX_HI(a1, p5.x, w5);
                FMIX_LO(a2, p5.y, w5); FMIX_HI(a3, p5.y, w5);
                FMIX_LO(a0, p6.x, w6); FMIX_HI(a1, p6.x, w6);
                FMIX_LO(a2, p6.y, w6); FMIX_HI(a3, p6.y, w6);
                FMIX_LO(a0, p7.x, w7); FMIX_HI(a1, p7.x, w7);
                FMIX_LO(a2, p7.y, w7); FMIX_HI(a3, p7.y, w7);
            }
        }
        for (; j + 3 < cnt; j += 4) {
            int4 o4 = *(const int4*)&sidx_sh[w][j];
            float w0 = ew_sh[w][j + 0][hd], w1 = ew_sh[w][j + 1][hd];
            float w2 = ew_sh[w][j + 2][hd], w3 = ew_sh[w][j + 3][hd];
            if (FULL || l < ACT) {
                int2 p0 = *(const int2*)(hbl + o4.x);
                int2 p1 = *(const int2*)(hbl + o4.y);
                int2 p2 = *(const int2*)(hbl + o4.z);
                int2 p3 = *(const int2*)(hbl + o4.w);
                FMIX_LO(a0, p0.x, w0); FMIX_HI(a1, p0.x, w0);
                FMIX_LO(a2, p0.y, w0); FMIX_HI(a3, p0.y, w0);
                FMIX_LO(a0, p1.x, w1); FMIX_HI(a1, p1.x, w1);
                FMIX_LO(a2, p1.y, w1); FMIX_HI(a3, p1.y, w1);
                FMIX_LO(a0, p2.x, w2); FMIX_HI(a1, p2.x, w2);
                FMIX_LO(a2, p2.y, w2); FMIX_HI(a3, p2.y, w2);
                FMIX_LO(a0, p3.x, w3); FMIX_HI(a1, p3.x, w3);
                FMIX_LO(a2, p3.y, w3); FMIX_HI(a3, p3.y, w3);
            }
        }
        for (; j < cnt; j++) {
            int off = sidx_sh[w][j];
            float w0 = ew_sh[w][j][hd];
            if (FULL || l < ACT) {
                int2 p0 = *(const int2*)(hbl + off);
                FMIX_LO(a0, p0.x, w0); FMIX_HI(a1, p0.x, w0);
                FMIX_LO(a2, p0.y, w0); FMIX_HI(a3, p0.y, w0);
            }
        }
    }

#pragma unroll
    for (int off = 1; off < 64; off <<= 1) {
        ds0 += __shfl_xor(ds0, off);
        ds1 += __shfl_xor(ds1, off);
        ds2 += __shfl_xor(ds2, off);
        ds3 += __shfl_xor(ds3, off);
    }

    if (FULL || l < ACT) {
        float dsel = hd == 0 ? ds0 : hd == 1 ? ds1 : hd == 2 ? ds2 : ds3;
        float inv = 1.0f / dsel;
        float4 bv = ((const float4*)bias)[l];
        float r0 = a0 * inv + bv.x;
        float r1 = a1 * inv + bv.y;
        float r2 = a2 * inv + bv.z;
        float r3 = a3 * inv + bv.w;
        if (RELU) {
            r0 = fmaxf(r0, 0.f);
            r1 = fmaxf(r1, 0.f);
            r2 = fmaxf(r2, 0.f);
            r3 = fmaxf(r3, 0.f);
        }
        OutT* op = out + (long)node * HC + 4 * l;
        if (sizeof(OutT) == 2) {
            h4v hv;
            hv[0] = (_Float16)r0;
            hv[1] = (_Float16)r1;
            hv[2] = (_Float16)r2;
            hv[3] = (_Float16)r3;
            *(h4v*)op = hv;
        } else {
            *(float4*)op = make_float4(r0, r1, r2, r3);
        }
    }
}

// ---------------- launch ----------------
extern "C" void kernel_launch(void* const* d_in, const int* in_sizes, int n_in, void* d_out,
                              int out_size, void* d_ws, size_t ws_size, hipStream_t stream) {
    const float* x = (const float*)d_in[0];
    const void* ei = d_in[1];
    const float* W1 = (const float*)d_in[2];
    const float* attS1 = (const float*)d_in[3];
    const float* attD1 = (const float*)d_in[4];
    const float* b1 = (const float*)d_in[5];
    const float* W2 = (const float*)d_in[6];
    const float* attS2 = (const float*)d_in[7];
    const float* attD2 = (const float*)d_in[8];
    const float* b2 = (const float*)d_in[9];
    float* out = (float*)d_out;

    int N = in_sizes[0] / F_IN;  // 50000
    int E = in_sizes[1] / 2;     // 800000
    int nb = (N + 255) / 256;    // 196
    int nw = (N + 3) / 4;        // wave-per-node aggregate grid
    int nblk1 = (E + EB - 1) / EB;   // 391 level-1 edge blocks
    int nbuck = (N + NPB - 1) / NPB; // 391 node buckets

    _Float16* xs_h = (_Float16*)d_ws;             // N*128
    _Float16* o1h = xs_h + (size_t)N * F_IN;      // N*256 (CSR-build scratch overlays early)
    _Float16* hb2 = o1h + (size_t)N * HC1;        // N*160
    _Float16* aggx_hi = hb2 + (size_t)N * HC2;    // N*256 (heads 2,3 of aggx)
    _Float16* B1x = aggx_hi + (size_t)N * HC1;    // 272*128
    _Float16* B2x = B1x + (HC1 + 16) * F_IN;      // 176*256
    float* as1 = (float*)(B2x + (HC2 + 16) * HC1);
    float* ad1 = as1 + (size_t)N * NHEAD;
    float* as2 = ad1 + (size_t)N * NHEAD;
    float* ad2 = as2 + (size_t)N * NHEAD;
    float* stats = ad2 + (size_t)N * NHEAD;       // 256 (zeroed in detect_kernel)
    int* offsets = (int*)(stats + 256);           // N+1 (pad 4)
    int* csr = offsets + (N + 4);                 // E+N
    int* blocksum = csr + (E + N);                // 256
    int* mode = blocksum + 256;                   // 1
    // CSR-build scratch in o1h slot (dead before gemm1b writes o1h): ~7.9MB < 25.6MB
    int* counts = (int*)o1h;                              // N
    int* bucketEdges = counts + N;                        // nbuck*BCAP
    int* hist = bucketEdges + (size_t)nbuck * BCAP;       // nbuck*nblk1 (bucket-major)
    int* colBaseT = hist + (size_t)nbuck * nblk1;         // nblk1*nbuck (block-major)
    int* bucketTotal = colBaseT + (size_t)nblk1 * nbuck;  // nbuck
    _Float16* aggx_lo = (_Float16*)d_out;  // heads 0,1 (25.6MB <= out buffer;
                                           // fully overwritten by final aggregate)

    constexpr int TCV = (HC1 + 16) * F_IN + (HC2 + 16) * HC1;
    int nbConv = (TCV + 255) / 256;                      // 143
    int total4 = N * F_IN / 4;
    int nbStd = (total4 + 255) / 256;                    // 6250
    int nbG1 = (N + 63) / 64;                            // 782

    // 1. detect edge dtype + zero stats
    detect_kernel<<<1, 256, 0, stream>>>((const unsigned int*)ei, mode, stats);
    // 2. fused: bucket-hist | colstats | convert_w  (no far atomics)
    fused_pre_kernel<<<nblk1 + nb + nbConv, 256, 0, stream>>>(
        ei, mode, E, nbuck, nblk1, hist, x, stats, N, W1, attS1, attD1, B1x, W2, attS2, attD2,
        B2x, nb);
    // 3. fused: standardize | bucket col-scan
    fused_mid_kernel<<<nbStd + nbuck, 256, 0, stream>>>(x, stats, xs_h, total4,
                                                        1.0f / (float)N, 1.0f / (float)(N - 1),
                                                        hist, colBaseT, bucketTotal, nbuck,
                                                        nblk1, nbStd);
    // 4. level-1 scatter into bucket regions
    scatter1_kernel<<<nblk1, 256, 0, stream>>>(ei, mode, E, nbuck, colBaseT, bucketEdges);
    // 5. per-bucket node counts
    bucket_count_kernel<<<nbuck, 256, 0, stream>>>(bucketEdges, bucketTotal, counts, N);
    // 6. scan offsets
    scan_block_kernel<<<nb, 256, 0, stream>>>(counts, offsets, blocksum, N);
    // 7. scan_add
    scan_add_kernel<<<nb, 256, 0, stream>>>(blocksum, offsets, N, nb);
    // 8. fused: csr scatter | att1
    fused_csr_att1_kernel<<<nbuck + nbG1, 256, 0, stream>>>(bucketEdges, bucketTotal, offsets,
                                                            csr, N, nbuck, xs_h, B1x, as1, ad1);
    // 9. per-head aggregate in xs-space
    aggregate_x4_kernel<<<nw, 256, 0, stream>>>(xs_h, as1, ad1, offsets, csr, aggx_lo, aggx_hi,
                                                N);
    // 10. gemm1b: o1[:, h*64:+64] = relu(aggx[h] @ W1[:, h*64:+64] + b1)
    gemm1b_kernel<<<nbG1, 256, 0, stream>>>(aggx_lo, aggx_hi, B1x, b1, o1h, N);
    // 11. gemm2(+att2)
    gemm2_kernel<<<nbG1, 256, 0, stream>>>(o1h, B2x, hb2, as2, ad2, N);
    // 12. aggregate layer 2
    aggregate_kernel<HC2, false, float>
        <<<nw, 256, 0, stream>>>(hb2, as2, ad2, offsets, csr, b2, out, N);
}

// Round 6
// 340.606 us; speedup vs baseline: 1.6479x; 1.0023x over previous
//
#include <hip/hip_runtime.h>
#include <math.h>

#define NEG_SLOPE 0.2f

constexpr int F_IN  = 128;
constexpr int HC1   = 256;  // H*HID
constexpr int HC2   = 160;  // H*CLS
constexpr int NHEAD = 4;
constexpr int EB    = 2048; // edges per level-1 block
constexpr int NPB   = 128;  // nodes per bucket
constexpr int BCAP  = 4096; // bucket capacity (avg 2046 @ E=800k; Poisson tail safe)

typedef _Float16 h8v __attribute__((ext_vector_type(8)));
typedef _Float16 h4v __attribute__((ext_vector_type(4)));
typedef _Float16 h2v __attribute__((ext_vector_type(2)));
typedef float f4v __attribute__((ext_vector_type(4)));

// f32 += f16(lo/hi of packed) * f32 — single VOP3P instruction
#define FMIX_LO(acc, pk, wt) \
    asm("v_fma_mix_f32 %0, %1, %2, %0 op_sel:[0,0,0] op_sel_hi:[1,0,0]" \
        : "+v"(acc) : "v"(pk), "v"(wt))
#define FMIX_HI(acc, pk, wt) \
    asm("v_fma_mix_f32 %0, %1, %2, %0 op_sel:[1,0,0] op_sel_hi:[1,0,0]" \
        : "+v"(acc) : "v"(pk), "v"(wt))

__device__ __forceinline__ int edge_val(const void* p, int m64, long long i) {
    if (m64) return (int)((const long long*)p)[i];
    return ((const int*)p)[i];
}

// ---------------- dispatch 1: edge dtype detect (+ zero stats) ----------------
__global__ void detect_kernel(const unsigned int* __restrict__ ei_words, int* __restrict__ mode,
                              float* __restrict__ stats) {
    stats[threadIdx.x] = 0.f;  // 256 threads zero 256 floats (sum|sumsq)
    __shared__ unsigned int red[256];
    unsigned int v = 0;
    for (int i = 1 + 2 * (int)threadIdx.x; i < 4096; i += 512) v |= ei_words[i];
    red[threadIdx.x] = v;
    __syncthreads();
    for (int off = 128; off > 0; off >>= 1) {
        if (threadIdx.x < off) red[threadIdx.x] |= red[threadIdx.x + off];
        __syncthreads();
    }
    if (threadIdx.x == 0) *mode = (red[0] == 0u) ? 1 : 0;
}

// ---------------- dispatch 2 (fused): bucket-hist | colstats | convert_w ----------------
__global__ __launch_bounds__(256) void fused_pre_kernel(
    const void* __restrict__ ei, const int* __restrict__ mode, int E, int nbuck, int nblk1,
    int* __restrict__ hist, const float* __restrict__ x, float* __restrict__ stats, int N,
    const float* __restrict__ W1, const float* __restrict__ aS1, const float* __restrict__ aD1,
    _Float16* __restrict__ B1x, const float* __restrict__ W2, const float* __restrict__ aS2,
    const float* __restrict__ aD2, _Float16* __restrict__ B2x, int nbStats) {
    int b = blockIdx.x;
    if (b < nblk1) {
        // ---- level-1 histogram ----
        __shared__ int lh[512];
        for (int i = threadIdx.x; i < nbuck; i += 256) lh[i] = 0;
        __syncthreads();
        int m = *mode;
        long long e0 = (long long)b * EB;
#pragma unroll
        for (int k = 0; k < EB / 256; k++) {
            long long e = e0 + (int)threadIdx.x + k * 256;
            if (e < E) {
                int d = edge_val(ei, m, (long long)E + e);
                atomicAdd(&lh[d >> 7], 1);
            }
        }
        __syncthreads();
        for (int i = threadIdx.x; i < nbuck; i += 256) hist[(size_t)i * nblk1 + b] = lh[i];
    } else if (b < nblk1 + nbStats) {
        // ---- colstats: float4 loads, 32 iters/thread, LDS-reduce 8 row groups ----
        int t = (int)threadIdx.x;
        int c = t & 31;   // handles cols 4c..4c+3
        int g = t >> 5;   // row subgroup 0..7
        int r0 = (b - nblk1) * 256;
        int rend = min(r0 + 256, N);
        f4v s = {0.f, 0.f, 0.f, 0.f}, q = {0.f, 0.f, 0.f, 0.f};
        for (int r = r0 + g; r < rend; r += 8) {
            f4v v = *(const f4v*)&x[(long)r * F_IN + 4 * c];
            s += v;
            q += v * v;
        }
        __shared__ f4v sh4[256];
        sh4[t] = s;
        __syncthreads();
        if (t < 32) {
            f4v a = sh4[t];
            for (int g2 = 1; g2 < 8; g2++) a += sh4[g2 * 32 + t];
            atomicAdd(&stats[4 * t + 0], a[0]);
            atomicAdd(&stats[4 * t + 1], a[1]);
            atomicAdd(&stats[4 * t + 2], a[2]);
            atomicAdd(&stats[4 * t + 3], a[3]);
        }
        __syncthreads();
        sh4[t] = q;
        __syncthreads();
        if (t < 32) {
            f4v a = sh4[t];
            for (int g2 = 1; g2 < 8; g2++) a += sh4[g2 * 32 + t];
            atomicAdd(&stats[128 + 4 * t + 0], a[0]);
            atomicAdd(&stats[128 + 4 * t + 1], a[1]);
            atomicAdd(&stats[128 + 4 * t + 2], a[2]);
            atomicAdd(&stats[128 + 4 * t + 3], a[3]);
        }
    } else {
        // ---- convert weights -> fp16 transposed + att columns ----
        constexpr int T1 = (HC1 + 16) * F_IN;
        constexpr int T2 = (HC2 + 16) * HC1;
        int idx = (b - nblk1 - nbStats) * 256 + (int)threadIdx.x;
        if (idx < T1) {
            int n = idx / F_IN, k = idx - n * F_IN;
            float v = 0.f;
            if (n < HC1) {
                v = W1[k * HC1 + n];
            } else {
                int n2 = n - HC1;
                if (n2 < 8) {
                    int hd = n2 & 3;
                    const float* a = (n2 < 4) ? aS1 : aD1;
                    for (int c = 0; c < 64; c++) v += W1[k * HC1 + hd * 64 + c] * a[hd * 64 + c];
                }
            }
            B1x[n * F_IN + k] = (_Float16)v;
        } else if (idx < T1 + T2) {
            int i2 = idx - T1;
            int n = i2 / HC1, k = i2 - n * HC1;
            float v = 0.f;
            if (n < HC2) {
                v = W2[k * HC2 + n];
            } else {
                int n2 = n - HC2;
                if (n2 < 8) {
                    int hd = n2 & 3;
                    const float* a = (n2 < 4) ? aS2 : aD2;
                    for (int c = 0; c < 40; c++) v += W2[k * HC2 + hd * 40 + c] * a[hd * 40 + c];
                }
            }
            B2x[n * HC1 + k] = (_Float16)v;
        }
    }
}

// ---------------- dispatch 3 (fused): standardize | bucket col-scan ----------------
__global__ __launch_bounds__(256) void fused_mid_kernel(
    const float* __restrict__ x, const float* __restrict__ stats, _Float16* __restrict__ xs,
    int total4, float invN, float invN1, const int* __restrict__ hist,
    int* __restrict__ colBaseT, int* __restrict__ bucketTotal, int nbuck, int nblk1,
    int nbStd) {
    int b = blockIdx.x;
    if (b < nbStd) {
        int i = b * 256 + (int)threadIdx.x;
        if (i >= total4) return;
        int c = (i * 4) & (F_IN - 1);
        float4 s4 = *(const float4*)&stats[c];
        float4 q4 = *(const float4*)&stats[128 + c];
        float4 v = ((const float4*)x)[i];
        h4v o;
        o[0] = (_Float16)((v.x - s4.x * invN) / sqrtf((q4.x - s4.x * s4.x * invN) * invN1));
        o[1] = (_Float16)((v.y - s4.y * invN) / sqrtf((q4.y - s4.y * s4.y * invN) * invN1));
        o[2] = (_Float16)((v.z - s4.z * invN) / sqrtf((q4.z - s4.z * s4.z * invN) * invN1));
        o[3] = (_Float16)((v.w - s4.w * invN) / sqrtf((q4.w - s4.w * s4.w * invN) * invN1));
        ((h4v*)xs)[i] = o;
    } else {
        // col-scan: exclusive prefix over blocks of hist[bb][*]; write transposed
        int bb = b - nbStd;
        int t = (int)threadIdx.x;
        __shared__ int sh[512];
        __shared__ int wsum[4];
        for (int i = t; i < nblk1; i += 256) sh[i] = hist[(size_t)bb * nblk1 + i];
        __syncthreads();
        int carry = 0;
        for (int base = 0; base < nblk1; base += 256) {
            int idx = base + t;
            int v = (idx < nblk1) ? sh[idx] : 0;
            int lane = t & 63, w = t >> 6;
            int xv = v;
#pragma unroll
            for (int d = 1; d < 64; d <<= 1) {
                int y = __shfl_up(xv, d);
                if (lane >= d) xv += y;
            }
            if (lane == 63) wsum[w] = xv;
            __syncthreads();
            int wb = 0;
            for (int k = 0; k < w; k++) wb += wsum[k];
            int excl = xv - v + wb + carry;
            if (idx < nblk1) colBaseT[(size_t)idx * nbuck + bb] = excl;
            carry += wsum[0] + wsum[1] + wsum[2] + wsum[3];
            __syncthreads();
        }
        if (t == 0) bucketTotal[bb] = carry;
    }
}

// ---------------- dispatch 4: level-1 scatter into bucket regions ----------------
__global__ __launch_bounds__(256) void scatter1_kernel(const void* __restrict__ ei,
                                                       const int* __restrict__ mode, int E,
                                                       int nbuck,
                                                       const int* __restrict__ colBaseT,
                                                       int* __restrict__ bucketEdges) {
    __shared__ int cur[512];
    int b = blockIdx.x;
    for (int i = threadIdx.x; i < nbuck; i += 256)
        cur[i] = colBaseT[(size_t)b * nbuck + i];
    __syncthreads();
    int m = *mode;
    long long e0 = (long long)b * EB;
#pragma unroll
    for (int k = 0; k < EB / 256; k++) {
        long long e = e0 + (int)threadIdx.x + k * 256;
        if (e < E) {
            int s = edge_val(ei, m, e);
            int d = edge_val(ei, m, (long long)E + e);
            int bk = d >> 7;
            int r = atomicAdd(&cur[bk], 1);  // LDS returning atomic (fast)
            bucketEdges[(size_t)bk * BCAP + r] = s | ((d & (NPB - 1)) << 16);
        }
    }
}

// ---------------- dispatch 5: per-bucket node counts ----------------
__global__ __launch_bounds__(256) void bucket_count_kernel(const int* __restrict__ bucketEdges,
                                                           const int* __restrict__ bucketTotal,
                                                           int* __restrict__ counts, int N) {
    __shared__ int c[NPB];
    int b = blockIdx.x, t = threadIdx.x;
    if (t < NPB) c[t] = 0;
    __syncthreads();
    int cnt = bucketTotal[b];
    const int* be = bucketEdges + (size_t)b * BCAP;
    for (int i = t; i < cnt; i += 256) atomicAdd(&c[(be[i] >> 16) & (NPB - 1)], 1);
    __syncthreads();
    int node = b * NPB + t;
    if (t < NPB && node < N) counts[node] = c[t];  // non-atomic: bucket owns these nodes
}

// ---------------- dispatch 6: scan_block ----------------
__global__ __launch_bounds__(256) void scan_block_kernel(const int* __restrict__ counts,
                                                         int* __restrict__ offsets,
                                                         int* __restrict__ blocksum, int N) {
    int t = threadIdx.x;
    int i = blockIdx.x * 256 + t;
    int v = (i < N) ? counts[i] + 1 : 0;
    int lane = t & 63, w = t >> 6;
    int xv = v;
#pragma unroll
    for (int d = 1; d < 64; d <<= 1) {
        int y = __shfl_up(xv, d);
        if (lane >= d) xv += y;
    }
    __shared__ int wsum[4];
    if (lane == 63) wsum[w] = xv;
    __syncthreads();
    int base = 0;
    for (int k = 0; k < w; k++) base += wsum[k];
    int incl = xv + base;
    if (i < N) offsets[i + 1] = incl;
    if (t == 255) blocksum[blockIdx.x] = incl;
}

// ---------------- dispatch 7: scan_add ----------------
__global__ void scan_add_kernel(const int* __restrict__ blocksum, int* __restrict__ offsets, int N,
                                int nb) {
    int t = threadIdx.x;
    int v = (t < nb) ? blocksum[t] : 0;
    int lane = t & 63, w = t >> 6;
    int x = v;
#pragma unroll
    for (int d = 1; d < 64; d <<= 1) {
        int y = __shfl_up(x, d);
        if (lane >= d) x += y;
    }
    __shared__ int wsum[4];
    __shared__ int excl[256];
    if (lane == 63) wsum[w] = x;
    __syncthreads();
    int base = 0;
    for (int k = 0; k < w; k++) base += wsum[k];
    excl[t] = x + base - v;
    __syncthreads();
    int myb = excl[blockIdx.x];
    int i = blockIdx.x * 256 + t;
    if (i < N) offsets[i + 1] += myb;
    if (i == 0) offsets[0] = 0;
}

// ---------------- MFMA f16 GEMM body, column range [CT0,CT1) ----------------
// Tile NT (== Nc/16) is the fused-att tile (present only when CT1 == NT+1).
template <int Nc, int K, int CT0, int CT1>
__device__ __forceinline__ void gemm_att_body(int blk, const _Float16* __restrict__ A,
                                              const _Float16* __restrict__ Btx,
                                              _Float16* __restrict__ C_, float* __restrict__ as_,
                                              float* __restrict__ ad_, int M) {
    constexpr int NT = Nc / 16;
    constexpr int NC = CT1 - CT0;
    constexpr int KT = K / 32;
    int w = threadIdx.x >> 6;
    int l = threadIdx.x & 63;
    int quad = l >> 4, lan = l & 15;
    int row = blk * 64 + w * 16 + lan;
    int arow = min(row, M - 1);
    f4v acc[NC] = {};
    const _Float16* Aptr = A + (long)arow * K + quad * 8;
#pragma unroll
    for (int k0 = 0; k0 < KT; k0++) {
        h8v af = *(const h8v*)(Aptr + k0 * 32);
#pragma unroll
        for (int ci = 0; ci < NC; ci++) {
            int ct = CT0 + ci;
            const _Float16* Bptr = Btx + (long)(ct * 16 + lan) * K + k0 * 32 + quad * 8;
            h8v bf = *(const h8v*)Bptr;
            acc[ci] = __builtin_amdgcn_mfma_f32_16x16x32_f16(af, bf, acc[ci], 0, 0, 0);
        }
    }
    int orow = blk * 64 + w * 16 + quad * 4;
#pragma unroll
    for (int r = 0; r < 4; r++) {
        int gr = orow + r;
        if (gr < M) {
            _Float16* out = C_ + (long)gr * Nc + lan;
#pragma unroll
            for (int ci = 0; ci < NC; ci++) {
                int ct = CT0 + ci;
                if (ct < NT) out[ct * 16] = (_Float16)acc[ci][r];
            }
            if (CT1 == NT + 1) {
                float av = acc[NC - 1][r];
                if (lan < 4)
                    as_[gr * 4 + lan] = av;
                else if (lan < 8)
                    ad_[gr * 4 + lan - 4] = av;
            }
        }
    }
}

// ---------------- att1 mini-GEMM: as1/ad1 = xs @ (W1·att) (8 cols) ----------------
__device__ __forceinline__ void att1_body(int blk, const _Float16* __restrict__ A,
                                          const _Float16* __restrict__ Batt,
                                          float* __restrict__ as_, float* __restrict__ ad_,
                                          int M) {
    int w = threadIdx.x >> 6;
    int l = threadIdx.x & 63;
    int quad = l >> 4, lan = l & 15;
    int row = blk * 64 + w * 16 + lan;
    int arow = min(row, M - 1);
    f4v acc = {0.f, 0.f, 0.f, 0.f};
    const _Float16* Aptr = A + (long)arow * F_IN + quad * 8;
#pragma unroll
    for (int k0 = 0; k0 < F_IN / 32; k0++) {
        h8v af = *(const h8v*)(Aptr + k0 * 32);
        h8v bf = *(const h8v*)(Batt + (long)lan * F_IN + k0 * 32 + quad * 8);
        acc = __builtin_amdgcn_mfma_f32_16x16x32_f16(af, bf, acc, 0, 0, 0);
    }
    int orow = blk * 64 + w * 16 + quad * 4;
#pragma unroll
    for (int r = 0; r < 4; r++) {
        int gr = orow + r;
        if (gr < M) {
            float av = acc[r];
            if (lan < 4)
                as_[gr * 4 + lan] = av;
            else if (lan < 8)
                ad_[gr * 4 + lan - 4] = av;
        }
    }
}

// ---------------- dispatch 8 (fused): csr-scatter | att1 ----------------
__global__ __launch_bounds__(256) void fused_csr_att1_kernel(
    const int* __restrict__ bucketEdges, const int* __restrict__ bucketTotal,
    const int* __restrict__ offsets, int* __restrict__ csr, int N, int nbuck,
    const _Float16* __restrict__ xs, const _Float16* __restrict__ B1x,
    float* __restrict__ as_, float* __restrict__ ad_) {
    int b = blockIdx.x;
    if (b < nbuck) {
        __shared__ int cur[NPB];
        int t = threadIdx.x;
        int node = b * NPB + t;
        if (t < NPB && node < N) {
            int off = offsets[node];
            csr[off] = node;  // self loop at slot 0
            cur[t] = off + 1;
        }
        __syncthreads();
        int cnt = bucketTotal[b];
        const int* be = bucketEdges + (size_t)b * BCAP;
        for (int i = t; i < cnt; i += 256) {
            int v = be[i];
            int pos = atomicAdd(&cur[(v >> 16) & (NPB - 1)], 1);  // LDS returning atomic
            csr[pos] = v & 0xFFFF;
        }
    } else {
        att1_body(b - nbuck, xs, B1x + (size_t)HC1 * F_IN, as_, ad_, N);
    }
}

// ---------------- dispatch 9: per-head layer-1 aggregate in xs-space ----------------
// (256,4): allow up to 128 VGPR so the 4-deep gather unroll stays in flight.
__global__ __launch_bounds__(256, 4) void aggregate_x4_kernel(
    const _Float16* __restrict__ xs, const float* __restrict__ a_src,
    const float* __restrict__ a_dst, const int* __restrict__ offsets,
    const int* __restrict__ csr_src, _Float16* __restrict__ aggx_lo,
    _Float16* __restrict__ aggx_hi, int Ntot) {
    int w = threadIdx.x >> 6, l = threadIdx.x & 63;
    int node = blockIdx.x * 4 + w;
    if (node >= Ntot) return;  // wave-uniform exit

    __shared__ __align__(16) int sidx_sh[4][64];     // byte offsets into xs (row = 256B)
    __shared__ __align__(16) float ew_sh[4][64][4];  // per-edge per-head exp weights

    int start = offsets[node], deg = offsets[node + 1] - start;
    float4 adv = ((const float4*)a_dst)[node];
    const char* hbl = (const char*)xs + 4 * l;  // this lane's 2-channel slice

    float ds0 = 0.f, ds1 = 0.f, ds2 = 0.f, ds3 = 0.f;
    float a00 = 0.f, a01 = 0.f, a10 = 0.f, a11 = 0.f;
    float a20 = 0.f, a21 = 0.f, a30 = 0.f, a31 = 0.f;

    for (int base = 0; base < deg; base += 64) {
        int cnt = min(64, deg - base);
        if (l < cnt) {
            int s = csr_src[start + base + l];
            sidx_sh[w][l] = s * (F_IN * 2);
            float4 av = ((const float4*)a_src)[s];
            float e0 = av.x + adv.x, e1 = av.y + adv.y, e2 = av.z + adv.z, e3 = av.w + adv.w;
            e0 = fmaxf(e0, NEG_SLOPE * e0);
            e1 = fmaxf(e1, NEG_SLOPE * e1);
            e2 = fmaxf(e2, NEG_SLOPE * e2);
            e3 = fmaxf(e3, NEG_SLOPE * e3);
            float w0 = __expf(e0), w1 = __expf(e1), w2 = __expf(e2), w3 = __expf(e3);
            *(float4*)ew_sh[w][l] = make_float4(w0, w1, w2, w3);
            ds0 += w0;
            ds1 += w1;
            ds2 += w2;
            ds3 += w3;
        }
        int j = 0;
        for (; j + 3 < cnt; j += 4) {
            int4 o4 = *(const int4*)&sidx_sh[w][j];
            float4 wa = *(const float4*)ew_sh[w][j + 0];
            float4 wb = *(const float4*)ew_sh[w][j + 1];
            float4 wc = *(const float4*)ew_sh[w][j + 2];
            float4 wd = *(const float4*)ew_sh[w][j + 3];
            int p0 = *(const int*)(hbl + o4.x);
            int p1 = *(const int*)(hbl + o4.y);
            int p2 = *(const int*)(hbl + o4.z);
            int p3 = *(const int*)(hbl + o4.w);
            FMIX_LO(a00, p0, wa.x); FMIX_HI(a01, p0, wa.x);
            FMIX_LO(a10, p0, wa.y); FMIX_HI(a11, p0, wa.y);
            FMIX_LO(a20, p0, wa.z); FMIX_HI(a21, p0, wa.z);
            FMIX_LO(a30, p0, wa.w); FMIX_HI(a31, p0, wa.w);
            FMIX_LO(a00, p1, wb.x); FMIX_HI(a01, p1, wb.x);
            FMIX_LO(a10, p1, wb.y); FMIX_HI(a11, p1, wb.y);
            FMIX_LO(a20, p1, wb.z); FMIX_HI(a21, p1, wb.z);
            FMIX_LO(a30, p1, wb.w); FMIX_HI(a31, p1, wb.w);
            FMIX_LO(a00, p2, wc.x); FMIX_HI(a01, p2, wc.x);
            FMIX_LO(a10, p2, wc.y); FMIX_HI(a11, p2, wc.y);
            FMIX_LO(a20, p2, wc.z); FMIX_HI(a21, p2, wc.z);
            FMIX_LO(a30, p2, wc.w); FMIX_HI(a31, p2, wc.w);
            FMIX_LO(a00, p3, wd.x); FMIX_HI(a01, p3, wd.x);
            FMIX_LO(a10, p3, wd.y); FMIX_HI(a11, p3, wd.y);
            FMIX_LO(a20, p3, wd.z); FMIX_HI(a21, p3, wd.z);
            FMIX_LO(a30, p3, wd.w); FMIX_HI(a31, p3, wd.w);
        }
        for (; j < cnt; j++) {
            int off = sidx_sh[w][j];
            float4 wa = *(const float4*)ew_sh[w][j];
            int p0 = *(const int*)(hbl + off);
            FMIX_LO(a00, p0, wa.x); FMIX_HI(a01, p0, wa.x);
            FMIX_LO(a10, p0, wa.y); FMIX_HI(a11, p0, wa.y);
            FMIX_LO(a20, p0, wa.z); FMIX_HI(a21, p0, wa.z);
            FMIX_LO(a30, p0, wa.w); FMIX_HI(a31, p0, wa.w);
        }
    }

#pragma unroll
    for (int off = 1; off < 64; off <<= 1) {
        ds0 += __shfl_xor(ds0, off);
        ds1 += __shfl_xor(ds1, off);
        ds2 += __shfl_xor(ds2, off);
        ds3 += __shfl_xor(ds3, off);
    }

    float i0 = 1.0f / ds0, i1 = 1.0f / ds1, i2 = 1.0f / ds2, i3 = 1.0f / ds3;
    h2v hv;
    hv[0] = (_Float16)(a00 * i0);
    hv[1] = (_Float16)(a01 * i0);
    *(h2v*)(aggx_lo + (size_t)node * F_IN + 2 * l) = hv;
    hv[0] = (_Float16)(a10 * i1);
    hv[1] = (_Float16)(a11 * i1);
    *(h2v*)(aggx_lo + ((size_t)Ntot + node) * F_IN + 2 * l) = hv;
    hv[0] = (_Float16)(a20 * i2);
    hv[1] = (_Float16)(a21 * i2);
    *(h2v*)(aggx_hi + (size_t)node * F_IN + 2 * l) = hv;
    hv[0] = (_Float16)(a30 * i3);
    hv[1] = (_Float16)(a31 * i3);
    *(h2v*)(aggx_hi + ((size_t)Ntot + node) * F_IN + 2 * l) = hv;
}

// ---------------- dispatch 10: gemm1b = relu(aggx[h] @ W1[:,h] + b1), col-split x2 ----------------
template <int CT0, int CT1>
__device__ __forceinline__ void gemm1b_body(const _Float16* __restrict__ Alo,
                                            const _Float16* __restrict__ Ahi,
                                            const _Float16* __restrict__ Btx,
                                            const float* __restrict__ bias,
                                            _Float16* __restrict__ C_, int M, int blk) {
    constexpr int NC = CT1 - CT0;
    constexpr int KT = F_IN / 32;  // 4
    int w = threadIdx.x >> 6;
    int l = threadIdx.x & 63;
    int quad = l >> 4, lan = l & 15;
    int row = blk * 64 + w * 16 + lan;
    int arow = min(row, M - 1);
    f4v acc[NC] = {};
    const _Float16* Ah0 = Alo + (size_t)arow * F_IN + quad * 8;
    const _Float16* Ah1 = Alo + ((size_t)M + arow) * F_IN + quad * 8;
    const _Float16* Ah2 = Ahi + (size_t)arow * F_IN + quad * 8;
    const _Float16* Ah3 = Ahi + ((size_t)M + arow) * F_IN + quad * 8;
#pragma unroll
    for (int k0 = 0; k0 < KT; k0++) {
        h8v af0 = *(const h8v*)(Ah0 + k0 * 32);
        h8v af1 = *(const h8v*)(Ah1 + k0 * 32);
        h8v af2 = *(const h8v*)(Ah2 + k0 * 32);
        h8v af3 = *(const h8v*)(Ah3 + k0 * 32);
#pragma unroll
        for (int ci = 0; ci < NC; ci++) {
            int ct = CT0 + ci;
            const _Float16* Bptr = Btx + (long)(ct * 16 + lan) * F_IN + k0 * 32 + quad * 8;
            h8v bf = *(const h8v*)Bptr;
            h8v af = (ct < 4) ? af0 : (ct < 8) ? af1 : (ct < 12) ? af2 : af3;
            acc[ci] = __builtin_amdgcn_mfma_f32_16x16x32_f16(af, bf, acc[ci], 0, 0, 0);
        }
    }
    int orow = blk * 64 + w * 16 + quad * 4;
#pragma unroll
    for (int r = 0; r < 4; r++) {
        int gr = orow + r;
        if (gr < M) {
            _Float16* out = C_ + (long)gr * HC1 + lan;
#pragma unroll
            for (int ci = 0; ci < NC; ci++) {
                int ct = CT0 + ci;
                float v = acc[ci][r] + bias[ct * 16 + lan];
                out[ct * 16] = (_Float16)fmaxf(v, 0.f);
            }
        }
    }
}

__global__ __launch_bounds__(256, 2) void gemm1b_kernel(const _Float16* __restrict__ Alo,
                                                        const _Float16* __restrict__ Ahi,
                                                        const _Float16* __restrict__ Btx,
                                                        const float* __restrict__ bias,
                                                        _Float16* __restrict__ C_, int M) {
    int blk = blockIdx.x >> 1;
    if (blockIdx.x & 1)
        gemm1b_body<8, 16>(Alo, Ahi, Btx, bias, C_, M, blk);
    else
        gemm1b_body<0, 8>(Alo, Ahi, Btx, bias, C_, M, blk);
}

// ---------------- dispatch 11: gemm2(+att2), col-split x2 ----------------
__global__ __launch_bounds__(256, 2) void gemm2_kernel(const _Float16* __restrict__ A,
                                                       const _Float16* __restrict__ B2x,
                                                       _Float16* __restrict__ C_,
                                                       float* __restrict__ as_,
                                                       float* __restrict__ ad_, int M) {
    int blk = blockIdx.x >> 1;
    if (blockIdx.x & 1)
        gemm_att_body<HC2, HC1, 5, 11>(blk, A, B2x, C_, as_, ad_, M);  // tiles 5-9 + att
    else
        gemm_att_body<HC2, HC1, 0, 5>(blk, A, B2x, C_, as_, ad_, M);   // tiles 0-4
}

// ---------------- layer-2 aggregate (R1 row-major structure, x8 unroll) ----------------
template <int HC, bool RELU, typename OutT>
__global__ __launch_bounds__(256, 4) void aggregate_kernel(
    const _Float16* __restrict__ hb, const float* __restrict__ a_src,
    const float* __restrict__ a_dst, const int* __restrict__ offsets,
    const int* __restrict__ csr_src, const float* __restrict__ bias, OutT* __restrict__ out,
    int Ntot) {
    constexpr int ACT = HC / 4;       // active gather lanes (64 or 40)
    constexpr int CHPH = HC / NHEAD;  // channels per head
    constexpr bool FULL = (ACT == 64);
    int w = threadIdx.x >> 6, l = threadIdx.x & 63;
    int node = blockIdx.x * 4 + w;
    if (node >= Ntot) return;  // wave-uniform exit

    __shared__ __align__(16) int sidx_sh[4][64];     // byte offsets into hb
    __shared__ __align__(16) float ew_sh[4][64][4];  // per-edge per-head exp weights

    int start = offsets[node], end = offsets[node + 1];
    int deg = end - start;
    float4 adv = ((const float4*)a_dst)[node];
    const int hd = min((4 * l) / CHPH, 3);
    const char* hbl = (const char*)hb + 8 * l;  // this lane's 4-channel slice

    float ds0 = 0.f, ds1 = 0.f, ds2 = 0.f, ds3 = 0.f;
    float a0 = 0.f, a1 = 0.f, a2 = 0.f, a3 = 0.f;

    for (int base = 0; base < deg; base += 64) {
        int cnt = min(64, deg - base);
        if (l < cnt) {
            int s = csr_src[start + base + l];
            sidx_sh[w][l] = s * (HC * 2);
            float4 av = ((const float4*)a_src)[s];
            float e0 = av.x + adv.x, e1 = av.y + adv.y, e2 = av.z + adv.z, e3 = av.w + adv.w;
            e0 = fmaxf(e0, NEG_SLOPE * e0);
            e1 = fmaxf(e1, NEG_SLOPE * e1);
            e2 = fmaxf(e2, NEG_SLOPE * e2);
            e3 = fmaxf(e3, NEG_SLOPE * e3);
            float w0 = __expf(e0), w1 = __expf(e1), w2 = __expf(e2), w3 = __expf(e3);
            *(float4*)ew_sh[w][l] = make_float4(w0, w1, w2, w3);
            ds0 += w0;
            ds1 += w1;
            ds2 += w2;
            ds3 += w3;
        }
        int j = 0;
        for (; j + 7 < cnt; j += 8) {
            int4 oa = *(const int4*)&sidx_sh[w][j];
            int4 ob = *(const int4*)&sidx_sh[w][j + 4];
            float w0 = ew_sh[w][j + 0][hd], w1 = ew_sh[w][j + 1][hd];
            float w2 = ew_sh[w][j + 2][hd], w3 = ew_sh[w][j + 3][hd];
            float w4 = ew_sh[w][j + 4][hd], w5 = ew_sh[w][j + 5][hd];
            float w6 = ew_sh[w][j + 6][hd], w7 = ew_sh[w][j + 7][hd];
            if (FULL || l < ACT) {
                int2 p0 = *(const int2*)(hbl + oa.x);
                int2 p1 = *(const int2*)(hbl + oa.y);
                int2 p2 = *(const int2*)(hbl + oa.z);
                int2 p3 = *(const int2*)(hbl + oa.w);
                int2 p4 = *(const int2*)(hbl + ob.x);
                int2 p5 = *(const int2*)(hbl + ob.y);
                int2 p6 = *(const int2*)(hbl + ob.z);
                int2 p7 = *(const int2*)(hbl + ob.w);
                FMIX_LO(a0, p0.x, w0); FMIX_HI(a1, p0.x, w0);
                FMIX_LO(a2, p0.y, w0); FMIX_HI(a3, p0.y, w0);
                FMIX_LO(a0, p1.x, w1); FMIX_HI(a1, p1.x, w1);
                FMIX_LO(a2, p1.y, w1); FMIX_HI(a3, p1.y, w1);
                FMIX_LO(a0, p2.x, w2); FMIX_HI(a1, p2.x, w2);
                FMIX_LO(a2, p2.y, w2); FMIX_HI(a3, p2.y, w2);
                FMIX_LO(a0, p3.x, w3); FMIX_HI(a1, p3.x, w3);
                FMIX_LO(a2, p3.y, w3); FMIX_HI(a3, p3.y, w3);
                FMIX_LO(a0, p4.x, w4); FMIX_HI(a1, p4.x, w4);
                FMIX_LO(a2, p4.y, w4); FMIX_HI(a3, p4.y, w4);
                FMIX_LO(a0, p5.x, w5); FMIX_HI(a1, p5.x, w5);
                FMIX_LO(a2, p5.y, w5); FMIX_HI(a3, p5.y, w5);
                FMIX_LO(a0, p6.x, w6); FMIX_HI(a1, p6.x, w6);
                FMIX_LO(a2, p6.y, w6); FMIX_HI(a3, p6.y, w6);
                FMIX_LO(a0, p7.x, w7); FMIX_HI(a1, p7.x, w7);
                FMIX_LO(a2, p7.y, w7); FMIX_HI(a3, p7.y, w7);
            }
        }
        for (; j + 3 < cnt; j += 4) {
            int4 o4 = *(const int4*)&sidx_sh[w][j];
            float w0 = ew_sh[w][j + 0][hd], w1 = ew_sh[w][j + 1][hd];
            float w2 = ew_sh[w][j + 2][hd], w3 = ew_sh[w][j + 3][hd];
            if (FULL || l < ACT) {
                int2 p0 = *(const int2*)(hbl + o4.x);
                int2 p1 = *(const int2*)(hbl + o4.y);
                int2 p2 = *(const int2*)(hbl + o4.z);
                int2 p3 = *(const int2*)(hbl + o4.w);
                FMIX_LO(a0, p0.x, w0); FMIX_HI(a1, p0.x, w0);
                FMIX_LO(a2, p0.y, w0); FMIX_HI(a3, p0.y, w0);
                FMIX_LO(a0, p1.x, w1); FMIX_HI(a1, p1.x, w1);
                FMIX_LO(a2, p1.y, w1); FMIX_HI(a3, p1.y, w1);
                FMIX_LO(a0, p2.x, w2); FMIX_HI(a1, p2.x, w2);
                FMIX_LO(a2, p2.y, w2); FMIX_HI(a3, p2.y, w2);
                FMIX_LO(a0, p3.x, w3); FMIX_HI(a1, p3.x, w3);
                FMIX_LO(a2, p3.y, w3); FMIX_HI(a3, p3.y, w3);
            }
        }
        for (; j < cnt; j++) {
            int off = sidx_sh[w][j];
            float w0 = ew_sh[w][j][hd];
            if (FULL || l < ACT) {
                int2 p0 = *(const int2*)(hbl + off);
                FMIX_LO(a0, p0.x, w0); FMIX_HI(a1, p0.x, w0);
                FMIX_LO(a2, p0.y, w0); FMIX_HI(a3, p0.y, w0);
            }
        }
    }

#pragma unroll
    for (int off = 1; off < 64; off <<= 1) {
        ds0 += __shfl_xor(ds0, off);
        ds1 += __shfl_xor(ds1, off);
        ds2 += __shfl_xor(ds2, off);
        ds3 += __shfl_xor(ds3, off);
    }

    if (FULL || l < ACT) {
        float dsel = hd == 0 ? ds0 : hd == 1 ? ds1 : hd == 2 ? ds2 : ds3;
        float inv = 1.0f / dsel;
        float4 bv = ((const float4*)bias)[l];
        float r0 = a0 * inv + bv.x;
        float r1 = a1 * inv + bv.y;
        float r2 = a2 * inv + bv.z;
        float r3 = a3 * inv + bv.w;
        if (RELU) {
            r0 = fmaxf(r0, 0.f);
            r1 = fmaxf(r1, 0.f);
            r2 = fmaxf(r2, 0.f);
            r3 = fmaxf(r3, 0.f);
        }
        OutT* op = out + (long)node * HC + 4 * l;
        if (sizeof(OutT) == 2) {
            h4v hv;
            hv[0] = (_Float16)r0;
            hv[1] = (_Float16)r1;
            hv[2] = (_Float16)r2;
            hv[3] = (_Float16)r3;
            *(h4v*)op = hv;
        } else {
            *(float4*)op = make_float4(r0, r1, r2, r3);
        }
    }
}

// ---------------- launch ----------------
extern "C" void kernel_launch(void* const* d_in, const int* in_sizes, int n_in, void* d_out,
                              int out_size, void* d_ws, size_t ws_size, hipStream_t stream) {
    const float* x = (const float*)d_in[0];
    const void* ei = d_in[1];
    const float* W1 = (const float*)d_in[2];
    const float* attS1 = (const float*)d_in[3];
    const float* attD1 = (const float*)d_in[4];
    const float* b1 = (const float*)d_in[5];
    const float* W2 = (const float*)d_in[6];
    const float* attS2 = (const float*)d_in[7];
    const float* attD2 = (const float*)d_in[8];
    const float* b2 = (const float*)d_in[9];
    float* out = (float*)d_out;

    int N = in_sizes[0] / F_IN;  // 50000
    int E = in_sizes[1] / 2;     // 800000
    int nb = (N + 255) / 256;    // 196
    int nw = (N + 3) / 4;        // wave-per-node aggregate grid
    int nblk1 = (E + EB - 1) / EB;   // 391 level-1 edge blocks
    int nbuck = (N + NPB - 1) / NPB; // 391 node buckets

    _Float16* xs_h = (_Float16*)d_ws;             // N*128
    _Float16* o1h = xs_h + (size_t)N * F_IN;      // N*256 (CSR-build scratch overlays early)
    _Float16* hb2 = o1h + (size_t)N * HC1;        // N*160
    _Float16* aggx_hi = hb2 + (size_t)N * HC2;    // N*256 (heads 2,3 of aggx)
    _Float16* B1x = aggx_hi + (size_t)N * HC1;    // 272*128
    _Float16* B2x = B1x + (HC1 + 16) * F_IN;      // 176*256
    float* as1 = (float*)(B2x + (HC2 + 16) * HC1);
    float* ad1 = as1 + (size_t)N * NHEAD;
    float* as2 = ad1 + (size_t)N * NHEAD;
    float* ad2 = as2 + (size_t)N * NHEAD;
    float* stats = ad2 + (size_t)N * NHEAD;       // 256 (zeroed in detect_kernel)
    int* offsets = (int*)(stats + 256);           // N+1 (pad 4)
    int* csr = offsets + (N + 4);                 // E+N
    int* blocksum = csr + (E + N);                // 256
    int* mode = blocksum + 256;                   // 1
    // CSR-build scratch in o1h slot (dead before gemm1b writes o1h): ~7.9MB < 25.6MB
    int* counts = (int*)o1h;                              // N
    int* bucketEdges = counts + N;                        // nbuck*BCAP
    int* hist = bucketEdges + (size_t)nbuck * BCAP;       // nbuck*nblk1 (bucket-major)
    int* colBaseT = hist + (size_t)nbuck * nblk1;         // nblk1*nbuck (block-major)
    int* bucketTotal = colBaseT + (size_t)nblk1 * nbuck;  // nbuck
    _Float16* aggx_lo = (_Float16*)d_out;  // heads 0,1 (25.6MB <= out buffer;
                                           // fully overwritten by final aggregate)

    constexpr int TCV = (HC1 + 16) * F_IN + (HC2 + 16) * HC1;
    int nbConv = (TCV + 255) / 256;                      // 143
    int total4 = N * F_IN / 4;
    int nbStd = (total4 + 255) / 256;                    // 6250
    int nbG1 = (N + 63) / 64;                            // 782

    // 1. detect edge dtype + zero stats
    detect_kernel<<<1, 256, 0, stream>>>((const unsigned int*)ei, mode, stats);
    // 2. fused: bucket-hist | colstats | convert_w  (no far atomics)
    fused_pre_kernel<<<nblk1 + nb + nbConv, 256, 0, stream>>>(
        ei, mode, E, nbuck, nblk1, hist, x, stats, N, W1, attS1, attD1, B1x, W2, attS2, attD2,
        B2x, nb);
    // 3. fused: standardize | bucket col-scan
    fused_mid_kernel<<<nbStd + nbuck, 256, 0, stream>>>(x, stats, xs_h, total4,
                                                        1.0f / (float)N, 1.0f / (float)(N - 1),
                                                        hist, colBaseT, bucketTotal, nbuck,
                                                        nblk1, nbStd);
    // 4. level-1 scatter into bucket regions
    scatter1_kernel<<<nblk1, 256, 0, stream>>>(ei, mode, E, nbuck, colBaseT, bucketEdges);
    // 5. per-bucket node counts
    bucket_count_kernel<<<nbuck, 256, 0, stream>>>(bucketEdges, bucketTotal, counts, N);
    // 6. scan offsets
    scan_block_kernel<<<nb, 256, 0, stream>>>(counts, offsets, blocksum, N);
    // 7. scan_add
    scan_add_kernel<<<nb, 256, 0, stream>>>(blocksum, offsets, N, nb);
    // 8. fused: csr scatter | att1
    fused_csr_att1_kernel<<<nbuck + nbG1, 256, 0, stream>>>(bucketEdges, bucketTotal, offsets,
                                                            csr, N, nbuck, xs_h, B1x, as1, ad1);
    // 9. per-head aggregate in xs-space
    aggregate_x4_kernel<<<nw, 256, 0, stream>>>(xs_h, as1, ad1, offsets, csr, aggx_lo, aggx_hi,
                                                N);
    // 10. gemm1b: o1[:, h*64:+64] = relu(aggx[h] @ W1[:, h*64:+64] + b1)  (col-split x2)
    gemm1b_kernel<<<nbG1 * 2, 256, 0, stream>>>(aggx_lo, aggx_hi, B1x, b1, o1h, N);
    // 11. gemm2(+att2)  (col-split x2)
    gemm2_kernel<<<nbG1 * 2, 256, 0, stream>>>(o1h, B2x, hb2, as2, ad2, N);
    // 12. aggregate layer 2
    aggregate_kernel<HC2, false, float>
        <<<nw, 256, 0, stream>>>(hb2, as2, ad2, offsets, csr, b2, out, N);
}

// Round 7
// 336.154 us; speedup vs baseline: 1.6697x; 1.0132x over previous
//
#include <hip/hip_runtime.h>
#include <math.h>

#define NEG_SLOPE 0.2f

constexpr int F_IN  = 128;
constexpr int HC1   = 256;  // H*HID
constexpr int HC2   = 160;  // H*CLS
constexpr int NHEAD = 4;
constexpr int EB    = 2048; // edges per level-1 block
constexpr int NPB   = 128;  // nodes per bucket
constexpr int BCAP  = 4096; // bucket capacity (avg 2046 @ E=800k; Poisson tail safe)

typedef _Float16 h8v __attribute__((ext_vector_type(8)));
typedef _Float16 h4v __attribute__((ext_vector_type(4)));
typedef _Float16 h2v __attribute__((ext_vector_type(2)));
typedef float f4v __attribute__((ext_vector_type(4)));

// f32 += f16(lo/hi of packed) * f32 — single VOP3P instruction
#define FMIX_LO(acc, pk, wt) \
    asm("v_fma_mix_f32 %0, %1, %2, %0 op_sel:[0,0,0] op_sel_hi:[1,0,0]" \
        : "+v"(acc) : "v"(pk), "v"(wt))
#define FMIX_HI(acc, pk, wt) \
    asm("v_fma_mix_f32 %0, %1, %2, %0 op_sel:[1,0,0] op_sel_hi:[1,0,0]" \
        : "+v"(acc) : "v"(pk), "v"(wt))

__device__ __forceinline__ int edge_val(const void* p, int m64, long long i) {
    if (m64) return (int)((const long long*)p)[i];
    return ((const int*)p)[i];
}

// ---------------- dispatch 1: edge dtype detect (+ zero stats) ----------------
__global__ void detect_kernel(const unsigned int* __restrict__ ei_words, int* __restrict__ mode,
                              float* __restrict__ stats) {
    stats[threadIdx.x] = 0.f;  // 256 threads zero 256 floats (sum|sumsq)
    __shared__ unsigned int red[256];
    unsigned int v = 0;
    for (int i = 1 + 2 * (int)threadIdx.x; i < 4096; i += 512) v |= ei_words[i];
    red[threadIdx.x] = v;
    __syncthreads();
    for (int off = 128; off > 0; off >>= 1) {
        if (threadIdx.x < off) red[threadIdx.x] |= red[threadIdx.x + off];
        __syncthreads();
    }
    if (threadIdx.x == 0) *mode = (red[0] == 0u) ? 1 : 0;
}

// ---------------- dispatch 2 (fused): bucket-hist | colstats | convert_w ----------------
__global__ __launch_bounds__(256) void fused_pre_kernel(
    const void* __restrict__ ei, const int* __restrict__ mode, int E, int nbuck, int nblk1,
    int* __restrict__ hist, const float* __restrict__ x, float* __restrict__ stats, int N,
    const float* __restrict__ W1, const float* __restrict__ aS1, const float* __restrict__ aD1,
    _Float16* __restrict__ B1x, const float* __restrict__ W2, const float* __restrict__ aS2,
    const float* __restrict__ aD2, _Float16* __restrict__ B2x, int nbStats) {
    int b = blockIdx.x;
    if (b < nblk1) {
        // ---- level-1 histogram ----
        __shared__ int lh[512];
        for (int i = threadIdx.x; i < nbuck; i += 256) lh[i] = 0;
        __syncthreads();
        int m = *mode;
        long long e0 = (long long)b * EB;
#pragma unroll
        for (int k = 0; k < EB / 256; k++) {
            long long e = e0 + (int)threadIdx.x + k * 256;
            if (e < E) {
                int d = edge_val(ei, m, (long long)E + e);
                atomicAdd(&lh[d >> 7], 1);
            }
        }
        __syncthreads();
        for (int i = threadIdx.x; i < nbuck; i += 256) hist[(size_t)i * nblk1 + b] = lh[i];
    } else if (b < nblk1 + nbStats) {
        // ---- colstats: float4 loads, 32 iters/thread, LDS-reduce 8 row groups ----
        int t = (int)threadIdx.x;
        int c = t & 31;   // handles cols 4c..4c+3
        int g = t >> 5;   // row subgroup 0..7
        int r0 = (b - nblk1) * 256;
        int rend = min(r0 + 256, N);
        f4v s = {0.f, 0.f, 0.f, 0.f}, q = {0.f, 0.f, 0.f, 0.f};
        for (int r = r0 + g; r < rend; r += 8) {
            f4v v = *(const f4v*)&x[(long)r * F_IN + 4 * c];
            s += v;
            q += v * v;
        }
        __shared__ f4v sh4[256];
        sh4[t] = s;
        __syncthreads();
        if (t < 32) {
            f4v a = sh4[t];
            for (int g2 = 1; g2 < 8; g2++) a += sh4[g2 * 32 + t];
            atomicAdd(&stats[4 * t + 0], a[0]);
            atomicAdd(&stats[4 * t + 1], a[1]);
            atomicAdd(&stats[4 * t + 2], a[2]);
            atomicAdd(&stats[4 * t + 3], a[3]);
        }
        __syncthreads();
        sh4[t] = q;
        __syncthreads();
        if (t < 32) {
            f4v a = sh4[t];
            for (int g2 = 1; g2 < 8; g2++) a += sh4[g2 * 32 + t];
            atomicAdd(&stats[128 + 4 * t + 0], a[0]);
            atomicAdd(&stats[128 + 4 * t + 1], a[1]);
            atomicAdd(&stats[128 + 4 * t + 2], a[2]);
            atomicAdd(&stats[128 + 4 * t + 3], a[3]);
        }
    } else {
        // ---- convert weights -> fp16 transposed + att columns ----
        constexpr int T1 = (HC1 + 16) * F_IN;
        constexpr int T2 = (HC2 + 16) * HC1;
        int idx = (b - nblk1 - nbStats) * 256 + (int)threadIdx.x;
        if (idx < T1) {
            int n = idx / F_IN, k = idx - n * F_IN;
            float v = 0.f;
            if (n < HC1) {
                v = W1[k * HC1 + n];
            } else {
                int n2 = n - HC1;
                if (n2 < 8) {
                    int hd = n2 & 3;
                    const float* a = (n2 < 4) ? aS1 : aD1;
                    for (int c = 0; c < 64; c++) v += W1[k * HC1 + hd * 64 + c] * a[hd * 64 + c];
                }
            }
            B1x[n * F_IN + k] = (_Float16)v;
        } else if (idx < T1 + T2) {
            int i2 = idx - T1;
            int n = i2 / HC1, k = i2 - n * HC1;
            float v = 0.f;
            if (n < HC2) {
                v = W2[k * HC2 + n];
            } else {
                int n2 = n - HC2;
                if (n2 < 8) {
                    int hd = n2 & 3;
                    const float* a = (n2 < 4) ? aS2 : aD2;
                    for (int c = 0; c < 40; c++) v += W2[k * HC2 + hd * 40 + c] * a[hd * 40 + c];
                }
            }
            B2x[n * HC1 + k] = (_Float16)v;
        }
    }
}

// ---------------- dispatch 3 (fused): standardize | bucket col-scan ----------------
__global__ __launch_bounds__(256) void fused_mid_kernel(
    const float* __restrict__ x, const float* __restrict__ stats, _Float16* __restrict__ xs,
    int total4, float invN, float invN1, const int* __restrict__ hist,
    int* __restrict__ colBaseT, int* __restrict__ bucketTotal, int nbuck, int nblk1,
    int nbStd) {
    int b = blockIdx.x;
    if (b < nbStd) {
        int i = b * 256 + (int)threadIdx.x;
        if (i >= total4) return;
        int c = (i * 4) & (F_IN - 1);
        float4 s4 = *(const float4*)&stats[c];
        float4 q4 = *(const float4*)&stats[128 + c];
        float4 v = ((const float4*)x)[i];
        h4v o;
        o[0] = (_Float16)((v.x - s4.x * invN) / sqrtf((q4.x - s4.x * s4.x * invN) * invN1));
        o[1] = (_Float16)((v.y - s4.y * invN) / sqrtf((q4.y - s4.y * s4.y * invN) * invN1));
        o[2] = (_Float16)((v.z - s4.z * invN) / sqrtf((q4.z - s4.z * s4.z * invN) * invN1));
        o[3] = (_Float16)((v.w - s4.w * invN) / sqrtf((q4.w - s4.w * s4.w * invN) * invN1));
        ((h4v*)xs)[i] = o;
    } else {
        // col-scan: exclusive prefix over blocks of hist[bb][*]; write transposed
        int bb = b - nbStd;
        int t = (int)threadIdx.x;
        __shared__ int sh[512];
        __shared__ int wsum[4];
        for (int i = t; i < nblk1; i += 256) sh[i] = hist[(size_t)bb * nblk1 + i];
        __syncthreads();
        int carry = 0;
        for (int base = 0; base < nblk1; base += 256) {
            int idx = base + t;
            int v = (idx < nblk1) ? sh[idx] : 0;
            int lane = t & 63, w = t >> 6;
            int xv = v;
#pragma unroll
            for (int d = 1; d < 64; d <<= 1) {
                int y = __shfl_up(xv, d);
                if (lane >= d) xv += y;
            }
            if (lane == 63) wsum[w] = xv;
            __syncthreads();
            int wb = 0;
            for (int k = 0; k < w; k++) wb += wsum[k];
            int excl = xv - v + wb + carry;
            if (idx < nblk1) colBaseT[(size_t)idx * nbuck + bb] = excl;
            carry += wsum[0] + wsum[1] + wsum[2] + wsum[3];
            __syncthreads();
        }
        if (t == 0) bucketTotal[bb] = carry;
    }
}

// ---------------- dispatch 4: level-1 scatter into bucket regions ----------------
__global__ __launch_bounds__(256) void scatter1_kernel(const void* __restrict__ ei,
                                                       const int* __restrict__ mode, int E,
                                                       int nbuck,
                                                       const int* __restrict__ colBaseT,
                                                       int* __restrict__ bucketEdges) {
    __shared__ int cur[512];
    int b = blockIdx.x;
    for (int i = threadIdx.x; i < nbuck; i += 256)
        cur[i] = colBaseT[(size_t)b * nbuck + i];
    __syncthreads();
    int m = *mode;
    long long e0 = (long long)b * EB;
#pragma unroll
    for (int k = 0; k < EB / 256; k++) {
        long long e = e0 + (int)threadIdx.x + k * 256;
        if (e < E) {
            int s = edge_val(ei, m, e);
            int d = edge_val(ei, m, (long long)E + e);
            int bk = d >> 7;
            int r = atomicAdd(&cur[bk], 1);  // LDS returning atomic (fast)
            bucketEdges[(size_t)bk * BCAP + r] = s | ((d & (NPB - 1)) << 16);
        }
    }
}

// ---------------- dispatch 5: per-bucket node counts ----------------
__global__ __launch_bounds__(256) void bucket_count_kernel(const int* __restrict__ bucketEdges,
                                                           const int* __restrict__ bucketTotal,
                                                           int* __restrict__ counts, int N) {
    __shared__ int c[NPB];
    int b = blockIdx.x, t = threadIdx.x;
    if (t < NPB) c[t] = 0;
    __syncthreads();
    int cnt = bucketTotal[b];
    const int* be = bucketEdges + (size_t)b * BCAP;
    for (int i = t; i < cnt; i += 256) atomicAdd(&c[(be[i] >> 16) & (NPB - 1)], 1);
    __syncthreads();
    int node = b * NPB + t;
    if (t < NPB && node < N) counts[node] = c[t];  // non-atomic: bucket owns these nodes
}

// ---------------- dispatch 6: scan_block ----------------
__global__ __launch_bounds__(256) void scan_block_kernel(const int* __restrict__ counts,
                                                         int* __restrict__ offsets,
                                                         int* __restrict__ blocksum, int N) {
    int t = threadIdx.x;
    int i = blockIdx.x * 256 + t;
    int v = (i < N) ? counts[i] + 1 : 0;
    int lane = t & 63, w = t >> 6;
    int xv = v;
#pragma unroll
    for (int d = 1; d < 64; d <<= 1) {
        int y = __shfl_up(xv, d);
        if (lane >= d) xv += y;
    }
    __shared__ int wsum[4];
    if (lane == 63) wsum[w] = xv;
    __syncthreads();
    int base = 0;
    for (int k = 0; k < w; k++) base += wsum[k];
    int incl = xv + base;
    if (i < N) offsets[i + 1] = incl;
    if (t == 255) blocksum[blockIdx.x] = incl;
}

// ---------------- dispatch 7: scan_add ----------------
__global__ void scan_add_kernel(const int* __restrict__ blocksum, int* __restrict__ offsets, int N,
                                int nb) {
    int t = threadIdx.x;
    int v = (t < nb) ? blocksum[t] : 0;
    int lane = t & 63, w = t >> 6;
    int x = v;
#pragma unroll
    for (int d = 1; d < 64; d <<= 1) {
        int y = __shfl_up(x, d);
        if (lane >= d) x += y;
    }
    __shared__ int wsum[4];
    __shared__ int excl[256];
    if (lane == 63) wsum[w] = x;
    __syncthreads();
    int base = 0;
    for (int k = 0; k < w; k++) base += wsum[k];
    excl[t] = x + base - v;
    __syncthreads();
    int myb = excl[blockIdx.x];
    int i = blockIdx.x * 256 + t;
    if (i < N) offsets[i + 1] += myb;
    if (i == 0) offsets[0] = 0;
}

// ---------------- MFMA f16 GEMM body, column range [CT0,CT1), batched-load version ----
// ALL A and B fragments are issued into register arrays before the MFMA loop so the
// ~56 16B loads are in flight simultaneously (one latency wait, not 56 serial ones).
// Tile NT (== Nc/16) is the fused-att tile (present only when CT1 == NT+1).
template <int Nc, int K, int CT0, int CT1>
__device__ __forceinline__ void gemm_att_body(int blk, const _Float16* __restrict__ A,
                                              const _Float16* __restrict__ Btx,
                                              _Float16* __restrict__ C_, float* __restrict__ as_,
                                              float* __restrict__ ad_, int M) {
    constexpr int NT = Nc / 16;
    constexpr int NC = CT1 - CT0;
    constexpr int KT = K / 32;
    int w = threadIdx.x >> 6;
    int l = threadIdx.x & 63;
    int quad = l >> 4, lan = l & 15;
    int row = blk * 64 + w * 16 + lan;
    int arow = min(row, M - 1);
    const _Float16* Aptr = A + (long)arow * K + quad * 8;
    h8v afr[KT];
#pragma unroll
    for (int k0 = 0; k0 < KT; k0++) afr[k0] = *(const h8v*)(Aptr + k0 * 32);
    h8v bfr[KT][NC];
#pragma unroll
    for (int k0 = 0; k0 < KT; k0++)
#pragma unroll
        for (int ci = 0; ci < NC; ci++)
            bfr[k0][ci] =
                *(const h8v*)(Btx + (long)((CT0 + ci) * 16 + lan) * K + k0 * 32 + quad * 8);
    f4v acc[NC] = {};
#pragma unroll
    for (int k0 = 0; k0 < KT; k0++)
#pragma unroll
        for (int ci = 0; ci < NC; ci++)
            acc[ci] = __builtin_amdgcn_mfma_f32_16x16x32_f16(afr[k0], bfr[k0][ci], acc[ci],
                                                             0, 0, 0);
    int orow = blk * 64 + w * 16 + quad * 4;
#pragma unroll
    for (int r = 0; r < 4; r++) {
        int gr = orow + r;
        if (gr < M) {
            _Float16* out = C_ + (long)gr * Nc + lan;
#pragma unroll
            for (int ci = 0; ci < NC; ci++) {
                int ct = CT0 + ci;
                if (ct < NT) out[ct * 16] = (_Float16)acc[ci][r];
            }
            if (CT1 == NT + 1) {
                float av = acc[NC - 1][r];
                if (lan < 4)
                    as_[gr * 4 + lan] = av;
                else if (lan < 8)
                    ad_[gr * 4 + lan - 4] = av;
            }
        }
    }
}

// ---------------- att1 mini-GEMM: as1/ad1 = xs @ (W1·att) (8 cols), batched loads ----
__device__ __forceinline__ void att1_body(int blk, const _Float16* __restrict__ A,
                                          const _Float16* __restrict__ Batt,
                                          float* __restrict__ as_, float* __restrict__ ad_,
                                          int M) {
    constexpr int KT = F_IN / 32;  // 4
    int w = threadIdx.x >> 6;
    int l = threadIdx.x & 63;
    int quad = l >> 4, lan = l & 15;
    int row = blk * 64 + w * 16 + lan;
    int arow = min(row, M - 1);
    const _Float16* Aptr = A + (long)arow * F_IN + quad * 8;
    h8v afr[KT], bfr[KT];
#pragma unroll
    for (int k0 = 0; k0 < KT; k0++) afr[k0] = *(const h8v*)(Aptr + k0 * 32);
#pragma unroll
    for (int k0 = 0; k0 < KT; k0++)
        bfr[k0] = *(const h8v*)(Batt + (long)lan * F_IN + k0 * 32 + quad * 8);
    f4v acc = {0.f, 0.f, 0.f, 0.f};
#pragma unroll
    for (int k0 = 0; k0 < KT; k0++)
        acc = __builtin_amdgcn_mfma_f32_16x16x32_f16(afr[k0], bfr[k0], acc, 0, 0, 0);
    int orow = blk * 64 + w * 16 + quad * 4;
#pragma unroll
    for (int r = 0; r < 4; r++) {
        int gr = orow + r;
        if (gr < M) {
            float av = acc[r];
            if (lan < 4)
                as_[gr * 4 + lan] = av;
            else if (lan < 8)
                ad_[gr * 4 + lan - 4] = av;
        }
    }
}

// ---------------- dispatch 8 (fused): csr-scatter | att1 ----------------
__global__ __launch_bounds__(256) void fused_csr_att1_kernel(
    const int* __restrict__ bucketEdges, const int* __restrict__ bucketTotal,
    const int* __restrict__ offsets, int* __restrict__ csr, int N, int nbuck,
    const _Float16* __restrict__ xs, const _Float16* __restrict__ B1x,
    float* __restrict__ as_, float* __restrict__ ad_) {
    int b = blockIdx.x;
    if (b < nbuck) {
        __shared__ int cur[NPB];
        int t = threadIdx.x;
        int node = b * NPB + t;
        if (t < NPB && node < N) {
            int off = offsets[node];
            csr[off] = node;  // self loop at slot 0
            cur[t] = off + 1;
        }
        __syncthreads();
        int cnt = bucketTotal[b];
        const int* be = bucketEdges + (size_t)b * BCAP;
        for (int i = t; i < cnt; i += 256) {
            int v = be[i];
            int pos = atomicAdd(&cur[(v >> 16) & (NPB - 1)], 1);  // LDS returning atomic
            csr[pos] = v & 0xFFFF;
        }
    } else {
        att1_body(b - nbuck, xs, B1x + (size_t)HC1 * F_IN, as_, ad_, N);
    }
}

// ---------------- dispatch 9: per-head layer-1 aggregate in xs-space ----------------
// (256,4): allow up to 128 VGPR so the 4-deep gather unroll stays in flight.
__global__ __launch_bounds__(256, 4) void aggregate_x4_kernel(
    const _Float16* __restrict__ xs, const float* __restrict__ a_src,
    const float* __restrict__ a_dst, const int* __restrict__ offsets,
    const int* __restrict__ csr_src, _Float16* __restrict__ aggx_lo,
    _Float16* __restrict__ aggx_hi, int Ntot) {
    int w = threadIdx.x >> 6, l = threadIdx.x & 63;
    int node = blockIdx.x * 4 + w;
    if (node >= Ntot) return;  // wave-uniform exit

    __shared__ __align__(16) int sidx_sh[4][64];     // byte offsets into xs (row = 256B)
    __shared__ __align__(16) float ew_sh[4][64][4];  // per-edge per-head exp weights

    int start = offsets[node], deg = offsets[node + 1] - start;
    float4 adv = ((const float4*)a_dst)[node];
    const char* hbl = (const char*)xs + 4 * l;  // this lane's 2-channel slice

    float ds0 = 0.f, ds1 = 0.f, ds2 = 0.f, ds3 = 0.f;
    float a00 = 0.f, a01 = 0.f, a10 = 0.f, a11 = 0.f;
    float a20 = 0.f, a21 = 0.f, a30 = 0.f, a31 = 0.f;

    for (int base = 0; base < deg; base += 64) {
        int cnt = min(64, deg - base);
        if (l < cnt) {
            int s = csr_src[start + base + l];
            sidx_sh[w][l] = s * (F_IN * 2);
            float4 av = ((const float4*)a_src)[s];
            float e0 = av.x + adv.x, e1 = av.y + adv.y, e2 = av.z + adv.z, e3 = av.w + adv.w;
            e0 = fmaxf(e0, NEG_SLOPE * e0);
            e1 = fmaxf(e1, NEG_SLOPE * e1);
            e2 = fmaxf(e2, NEG_SLOPE * e2);
            e3 = fmaxf(e3, NEG_SLOPE * e3);
            float w0 = __expf(e0), w1 = __expf(e1), w2 = __expf(e2), w3 = __expf(e3);
            *(float4*)ew_sh[w][l] = make_float4(w0, w1, w2, w3);
            ds0 += w0;
            ds1 += w1;
            ds2 += w2;
            ds3 += w3;
        }
        int j = 0;
        for (; j + 3 < cnt; j += 4) {
            int4 o4 = *(const int4*)&sidx_sh[w][j];
            float4 wa = *(const float4*)ew_sh[w][j + 0];
            float4 wb = *(const float4*)ew_sh[w][j + 1];
            float4 wc = *(const float4*)ew_sh[w][j + 2];
            float4 wd = *(const float4*)ew_sh[w][j + 3];
            int p0 = *(const int*)(hbl + o4.x);
            int p1 = *(const int*)(hbl + o4.y);
            int p2 = *(const int*)(hbl + o4.z);
            int p3 = *(const int*)(hbl + o4.w);
            FMIX_LO(a00, p0, wa.x); FMIX_HI(a01, p0, wa.x);
            FMIX_LO(a10, p0, wa.y); FMIX_HI(a11, p0, wa.y);
            FMIX_LO(a20, p0, wa.z); FMIX_HI(a21, p0, wa.z);
            FMIX_LO(a30, p0, wa.w); FMIX_HI(a31, p0, wa.w);
            FMIX_LO(a00, p1, wb.x); FMIX_HI(a01, p1, wb.x);
            FMIX_LO(a10, p1, wb.y); FMIX_HI(a11, p1, wb.y);
            FMIX_LO(a20, p1, wb.z); FMIX_HI(a21, p1, wb.z);
            FMIX_LO(a30, p1, wb.w); FMIX_HI(a31, p1, wb.w);
            FMIX_LO(a00, p2, wc.x); FMIX_HI(a01, p2, wc.x);
            FMIX_LO(a10, p2, wc.y); FMIX_HI(a11, p2, wc.y);
            FMIX_LO(a20, p2, wc.z); FMIX_HI(a21, p2, wc.z);
            FMIX_LO(a30, p2, wc.w); FMIX_HI(a31, p2, wc.w);
            FMIX_LO(a00, p3, wd.x); FMIX_HI(a01, p3, wd.x);
            FMIX_LO(a10, p3, wd.y); FMIX_HI(a11, p3, wd.y);
            FMIX_LO(a20, p3, wd.z); FMIX_HI(a21, p3, wd.z);
            FMIX_LO(a30, p3, wd.w); FMIX_HI(a31, p3, wd.w);
        }
        for (; j < cnt; j++) {
            int off = sidx_sh[w][j];
            float4 wa = *(const float4*)ew_sh[w][j];
            int p0 = *(const int*)(hbl + off);
            FMIX_LO(a00, p0, wa.x); FMIX_HI(a01, p0, wa.x);
            FMIX_LO(a10, p0, wa.y); FMIX_HI(a11, p0, wa.y);
            FMIX_LO(a20, p0, wa.z); FMIX_HI(a21, p0, wa.z);
            FMIX_LO(a30, p0, wa.w); FMIX_HI(a31, p0, wa.w);
        }
    }

#pragma unroll
    for (int off = 1; off < 64; off <<= 1) {
        ds0 += __shfl_xor(ds0, off);
        ds1 += __shfl_xor(ds1, off);
        ds2 += __shfl_xor(ds2, off);
        ds3 += __shfl_xor(ds3, off);
    }

    float i0 = 1.0f / ds0, i1 = 1.0f / ds1, i2 = 1.0f / ds2, i3 = 1.0f / ds3;
    h2v hv;
    hv[0] = (_Float16)(a00 * i0);
    hv[1] = (_Float16)(a01 * i0);
    *(h2v*)(aggx_lo + (size_t)node * F_IN + 2 * l) = hv;
    hv[0] = (_Float16)(a10 * i1);
    hv[1] = (_Float16)(a11 * i1);
    *(h2v*)(aggx_lo + ((size_t)Ntot + node) * F_IN + 2 * l) = hv;
    hv[0] = (_Float16)(a20 * i2);
    hv[1] = (_Float16)(a21 * i2);
    *(h2v*)(aggx_hi + (size_t)node * F_IN + 2 * l) = hv;
    hv[0] = (_Float16)(a30 * i3);
    hv[1] = (_Float16)(a31 * i3);
    *(h2v*)(aggx_hi + ((size_t)Ntot + node) * F_IN + 2 * l) = hv;
}

// ---------------- dispatch 10: gemm1b = relu(aggx[h] @ W1[:,h] + b1), col-split x2 ----
// Batched-load version: all 8 A-frags (2 heads) + 32 B-frags issued before MFMA loop.
template <int CT0, int CT1>
__device__ __forceinline__ void gemm1b_body(const _Float16* __restrict__ Ah,
                                            const _Float16* __restrict__ Btx,
                                            const float* __restrict__ bias,
                                            _Float16* __restrict__ C_, int M, int blk) {
    constexpr int NC = CT1 - CT0;  // 8
    constexpr int KT = F_IN / 32;  // 4
    int w = threadIdx.x >> 6;
    int l = threadIdx.x & 63;
    int quad = l >> 4, lan = l & 15;
    int row = blk * 64 + w * 16 + lan;
    int arow = min(row, M - 1);
    const _Float16* A0 = Ah + (size_t)arow * F_IN + quad * 8;          // head CT0/4
    const _Float16* A1 = Ah + ((size_t)M + arow) * F_IN + quad * 8;    // head CT0/4+1
    h8v af0[KT], af1[KT];
#pragma unroll
    for (int k0 = 0; k0 < KT; k0++) af0[k0] = *(const h8v*)(A0 + k0 * 32);
#pragma unroll
    for (int k0 = 0; k0 < KT; k0++) af1[k0] = *(const h8v*)(A1 + k0 * 32);
    h8v bfr[KT][NC];
#pragma unroll
    for (int k0 = 0; k0 < KT; k0++)
#pragma unroll
        for (int ci = 0; ci < NC; ci++)
            bfr[k0][ci] =
                *(const h8v*)(Btx + (long)((CT0 + ci) * 16 + lan) * F_IN + k0 * 32 + quad * 8);
    f4v acc[NC] = {};
#pragma unroll
    for (int k0 = 0; k0 < KT; k0++)
#pragma unroll
        for (int ci = 0; ci < NC; ci++) {
            h8v af = (ci < 4) ? af0[k0] : af1[k0];
            acc[ci] = __builtin_amdgcn_mfma_f32_16x16x32_f16(af, bfr[k0][ci], acc[ci], 0, 0, 0);
        }
    int orow = blk * 64 + w * 16 + quad * 4;
#pragma unroll
    for (int r = 0; r < 4; r++) {
        int gr = orow + r;
        if (gr < M) {
            _Float16* out = C_ + (long)gr * HC1 + lan;
#pragma unroll
            for (int ci = 0; ci < NC; ci++) {
                int ct = CT0 + ci;
                float v = acc[ci][r] + bias[ct * 16 + lan];
                out[ct * 16] = (_Float16)fmaxf(v, 0.f);
            }
        }
    }
}

__global__ __launch_bounds__(256, 2) void gemm1b_kernel(const _Float16* __restrict__ Alo,
                                                        const _Float16* __restrict__ Ahi,
                                                        const _Float16* __restrict__ Btx,
                                                        const float* __restrict__ bias,
                                                        _Float16* __restrict__ C_, int M) {
    int blk = blockIdx.x >> 1;
    if (blockIdx.x & 1)
        gemm1b_body<8, 16>(Ahi, Btx, bias, C_, M, blk);  // heads 2,3
    else
        gemm1b_body<0, 8>(Alo, Btx, bias, C_, M, blk);   // heads 0,1
}

// ---------------- dispatch 11: gemm2(+att2), col-split x2, batched loads ----------------
// (256,1): VGPR cap 512 — odd half needs ~250 regs for 48 B-frags + 8 A-frags + acc.
__global__ __launch_bounds__(256, 1) void gemm2_kernel(const _Float16* __restrict__ A,
                                                       const _Float16* __restrict__ B2x,
                                                       _Float16* __restrict__ C_,
                                                       float* __restrict__ as_,
                                                       float* __restrict__ ad_, int M) {
    int blk = blockIdx.x >> 1;
    if (blockIdx.x & 1)
        gemm_att_body<HC2, HC1, 5, 11>(blk, A, B2x, C_, as_, ad_, M);  // tiles 5-9 + att
    else
        gemm_att_body<HC2, HC1, 0, 5>(blk, A, B2x, C_, as_, ad_, M);   // tiles 0-4
}

// ---------------- layer-2 aggregate (R1 row-major structure, x8 unroll) ----------------
template <int HC, bool RELU, typename OutT>
__global__ __launch_bounds__(256, 4) void aggregate_kernel(
    const _Float16* __restrict__ hb, const float* __restrict__ a_src,
    const float* __restrict__ a_dst, const int* __restrict__ offsets,
    const int* __restrict__ csr_src, const float* __restrict__ bias, OutT* __restrict__ out,
    int Ntot) {
    constexpr int ACT = HC / 4;       // active gather lanes (64 or 40)
    constexpr int CHPH = HC / NHEAD;  // channels per head
    constexpr bool FULL = (ACT == 64);
    int w = threadIdx.x >> 6, l = threadIdx.x & 63;
    int node = blockIdx.x * 4 + w;
    if (node >= Ntot) return;  // wave-uniform exit

    __shared__ __align__(16) int sidx_sh[4][64];     // byte offsets into hb
    __shared__ __align__(16) float ew_sh[4][64][4];  // per-edge per-head exp weights

    int start = offsets[node], end = offsets[node + 1];
    int deg = end - start;
    float4 adv = ((const float4*)a_dst)[node];
    const int hd = min((4 * l) / CHPH, 3);
    const char* hbl = (const char*)hb + 8 * l;  // this lane's 4-channel slice

    float ds0 = 0.f, ds1 = 0.f, ds2 = 0.f, ds3 = 0.f;
    float a0 = 0.f, a1 = 0.f, a2 = 0.f, a3 = 0.f;

    for (int base = 0; base < deg; base += 64) {
        int cnt = min(64, deg - base);
        if (l < cnt) {
            int s = csr_src[start + base + l];
            sidx_sh[w][l] = s * (HC * 2);
            float4 av = ((const float4*)a_src)[s];
            float e0 = av.x + adv.x, e1 = av.y + adv.y, e2 = av.z + adv.z, e3 = av.w + adv.w;
            e0 = fmaxf(e0, NEG_SLOPE * e0);
            e1 = fmaxf(e1, NEG_SLOPE * e1);
            e2 = fmaxf(e2, NEG_SLOPE * e2);
            e3 = fmaxf(e3, NEG_SLOPE * e3);
            float w0 = __expf(e0), w1 = __expf(e1), w2 = __expf(e2), w3 = __expf(e3);
            *(float4*)ew_sh[w][l] = make_float4(w0, w1, w2, w3);
            ds0 += w0;
            ds1 += w1;
            ds2 += w2;
            ds3 += w3;
        }
        int j = 0;
        for (; j + 7 < cnt; j += 8) {
            int4 oa = *(const int4*)&sidx_sh[w][j];
            int4 ob = *(const int4*)&sidx_sh[w][j + 4];
            float w0 = ew_sh[w][j + 0][hd], w1 = ew_sh[w][j + 1][hd];
            float w2 = ew_sh[w][j + 2][hd], w3 = ew_sh[w][j + 3][hd];
            float w4 = ew_sh[w][j + 4][hd], w5 = ew_sh[w][j + 5][hd];
            float w6 = ew_sh[w][j + 6][hd], w7 = ew_sh[w][j + 7][hd];
            if (FULL || l < ACT) {
                int2 p0 = *(const int2*)(hbl + oa.x);
                int2 p1 = *(const int2*)(hbl + oa.y);
                int2 p2 = *(const int2*)(hbl + oa.z);
                int2 p3 = *(const int2*)(hbl + oa.w);
                int2 p4 = *(const int2*)(hbl + ob.x);
                int2 p5 = *(const int2*)(hbl + ob.y);
                int2 p6 = *(const int2*)(hbl + ob.z);
                int2 p7 = *(const int2*)(hbl + ob.w);
                FMIX_LO(a0, p0.x, w0); FMIX_HI(a1, p0.x, w0);
                FMIX_LO(a2, p0.y, w0); FMIX_HI(a3, p0.y, w0);
                FMIX_LO(a0, p1.x, w1); FMIX_HI(a1, p1.x, w1);
                FMIX_LO(a2, p1.y, w1); FMIX_HI(a3, p1.y, w1);
                FMIX_LO(a0, p2.x, w2); FMIX_HI(a1, p2.x, w2);
                FMIX_LO(a2, p2.y, w2); FMIX_HI(a3, p2.y, w2);
                FMIX_LO(a0, p3.x, w3); FMIX_HI(a1, p3.x, w3);
                FMIX_LO(a2, p3.y, w3); FMIX_HI(a3, p3.y, w3);
                FMIX_LO(a0, p4.x, w4); FMIX_HI(a1, p4.x, w4);
                FMIX_LO(a2, p4.y, w4); FMIX_HI(a3, p4.y, w4);
                FMIX_LO(a0, p5.x, w5); FMIX_HI(a1, p5.x, w5);
                FMIX_LO(a2, p5.y, w5); FMIX_HI(a3, p5.y, w5);
                FMIX_LO(a0, p6.x, w6); FMIX_HI(a1, p6.x, w6);
                FMIX_LO(a2, p6.y, w6); FMIX_HI(a3, p6.y, w6);
                FMIX_LO(a0, p7.x, w7); FMIX_HI(a1, p7.x, w7);
                FMIX_LO(a2, p7.y, w7); FMIX_HI(a3, p7.y, w7);
            }
        }
        for (; j + 3 < cnt; j += 4) {
            int4 o4 = *(const int4*)&sidx_sh[w][j];
            float w0 = ew_sh[w][j + 0][hd], w1 = ew_sh[w][j + 1][hd];
            float w2 = ew_sh[w][j + 2][hd], w3 = ew_sh[w][j + 3][hd];
            if (FULL || l < ACT) {
                int2 p0 = *(const int2*)(hbl + o4.x);
                int2 p1 = *(const int2*)(hbl + o4.y);
                int2 p2 = *(const int2*)(hbl + o4.z);
                int2 p3 = *(const int2*)(hbl + o4.w);
                FMIX_LO(a0, p0.x, w0); FMIX_HI(a1, p0.x, w0);
                FMIX_LO(a2, p0.y, w0); FMIX_HI(a3, p0.y, w0);
                FMIX_LO(a0, p1.x, w1); FMIX_HI(a1, p1.x, w1);
                FMIX_LO(a2, p1.y, w1); FMIX_HI(a3, p1.y, w1);
                FMIX_LO(a0, p2.x, w2); FMIX_HI(a1, p2.x, w2);
                FMIX_LO(a2, p2.y, w2); FMIX_HI(a3, p2.y, w2);
                FMIX_LO(a0, p3.x, w3); FMIX_HI(a1, p3.x, w3);
                FMIX_LO(a2, p3.y, w3); FMIX_HI(a3, p3.y, w3);
            }
        }
        for (; j < cnt; j++) {
            int off = sidx_sh[w][j];
            float w0 = ew_sh[w][j][hd];
            if (FULL || l < ACT) {
                int2 p0 = *(const int2*)(hbl + off);
                FMIX_LO(a0, p0.x, w0); FMIX_HI(a1, p0.x, w0);
                FMIX_LO(a2, p0.y, w0); FMIX_HI(a3, p0.y, w0);
            }
        }
    }

#pragma unroll
    for (int off = 1; off < 64; off <<= 1) {
        ds0 += __shfl_xor(ds0, off);
        ds1 += __shfl_xor(ds1, off);
        ds2 += __shfl_xor(ds2, off);
        ds3 += __shfl_xor(ds3, off);
    }

    if (FULL || l < ACT) {
        float dsel = hd == 0 ? ds0 : hd == 1 ? ds1 : hd == 2 ? ds2 : ds3;
        float inv = 1.0f / dsel;
        float4 bv = ((const float4*)bias)[l];
        float r0 = a0 * inv + bv.x;
        float r1 = a1 * inv + bv.y;
        float r2 = a2 * inv + bv.z;
        float r3 = a3 * inv + bv.w;
        if (RELU) {
            r0 = fmaxf(r0, 0.f);
            r1 = fmaxf(r1, 0.f);
            r2 = fmaxf(r2, 0.f);
            r3 = fmaxf(r3, 0.f);
        }
        OutT* op = out + (long)node * HC + 4 * l;
        if (sizeof(OutT) == 2) {
            h4v hv;
            hv[0] = (_Float16)r0;
            hv[1] = (_Float16)r1;
            hv[2] = (_Float16)r2;
            hv[3] = (_Float16)r3;
            *(h4v*)op = hv;
        } else {
            *(float4*)op = make_float4(r0, r1, r2, r3);
        }
    }
}

// ---------------- launch ----------------
extern "C" void kernel_launch(void* const* d_in, const int* in_sizes, int n_in, void* d_out,
                              int out_size, void* d_ws, size_t ws_size, hipStream_t stream) {
    const float* x = (const float*)d_in[0];
    const void* ei = d_in[1];
    const float* W1 = (const float*)d_in[2];
    const float* attS1 = (const float*)d_in[3];
    const float* attD1 = (const float*)d_in[4];
    const float* b1 = (const float*)d_in[5];
    const float* W2 = (const float*)d_in[6];
    const float* attS2 = (const float*)d_in[7];
    const float* attD2 = (const float*)d_in[8];
    const float* b2 = (const float*)d_in[9];
    float* out = (float*)d_out;

    int N = in_sizes[0] / F_IN;  // 50000
    int E = in_sizes[1] / 2;     // 800000
    int nb = (N + 255) / 256;    // 196
    int nw = (N + 3) / 4;        // wave-per-node aggregate grid
    int nblk1 = (E + EB - 1) / EB;   // 391 level-1 edge blocks
    int nbuck = (N + NPB - 1) / NPB; // 391 node buckets

    _Float16* xs_h = (_Float16*)d_ws;             // N*128
    _Float16* o1h = xs_h + (size_t)N * F_IN;      // N*256 (CSR-build scratch overlays early)
    _Float16* hb2 = o1h + (size_t)N * HC1;        // N*160
    _Float16* aggx_hi = hb2 + (size_t)N * HC2;    // N*256 (heads 2,3 of aggx)
    _Float16* B1x = aggx_hi + (size_t)N * HC1;    // 272*128
    _Float16* B2x = B1x + (HC1 + 16) * F_IN;      // 176*256
    float* as1 = (float*)(B2x + (HC2 + 16) * HC1);
    float* ad1 = as1 + (size_t)N * NHEAD;
    float* as2 = ad1 + (size_t)N * NHEAD;
    float* ad2 = as2 + (size_t)N * NHEAD;
    float* stats = ad2 + (size_t)N * NHEAD;       // 256 (zeroed in detect_kernel)
    int* offsets = (int*)(stats + 256);           // N+1 (pad 4)
    int* csr = offsets + (N + 4);                 // E+N
    int* blocksum = csr + (E + N);                // 256
    int* mode = blocksum + 256;                   // 1
    // CSR-build scratch in o1h slot (dead before gemm1b writes o1h): ~7.9MB < 25.6MB
    int* counts = (int*)o1h;                              // N
    int* bucketEdges = counts + N;                        // nbuck*BCAP
    int* hist = bucketEdges + (size_t)nbuck * BCAP;       // nbuck*nblk1 (bucket-major)
    int* colBaseT = hist + (size_t)nbuck * nblk1;         // nblk1*nbuck (block-major)
    int* bucketTotal = colBaseT + (size_t)nblk1 * nbuck;  // nbuck
    _Float16* aggx_lo = (_Float16*)d_out;  // heads 0,1 (25.6MB <= out buffer;
                                           // fully overwritten by final aggregate)

    constexpr int TCV = (HC1 + 16) * F_IN + (HC2 + 16) * HC1;
    int nbConv = (TCV + 255) / 256;                      // 143
    int total4 = N * F_IN / 4;
    int nbStd = (total4 + 255) / 256;                    // 6250
    int nbG1 = (N + 63) / 64;                            // 782

    // 1. detect edge dtype + zero stats
    detect_kernel<<<1, 256, 0, stream>>>((const unsigned int*)ei, mode, stats);
    // 2. fused: bucket-hist | colstats | convert_w  (no far atomics)
    fused_pre_kernel<<<nblk1 + nb + nbConv, 256, 0, stream>>>(
        ei, mode, E, nbuck, nblk1, hist, x, stats, N, W1, attS1, attD1, B1x, W2, attS2, attD2,
        B2x, nb);
    // 3. fused: standardize | bucket col-scan
    fused_mid_kernel<<<nbStd + nbuck, 256, 0, stream>>>(x, stats, xs_h, total4,
                                                        1.0f / (float)N, 1.0f / (float)(N - 1),
                                                        hist, colBaseT, bucketTotal, nbuck,
                                                        nblk1, nbStd);
    // 4. level-1 scatter into bucket regions
    scatter1_kernel<<<nblk1, 256, 0, stream>>>(ei, mode, E, nbuck, colBaseT, bucketEdges);
    // 5. per-bucket node counts
    bucket_count_kernel<<<nbuck, 256, 0, stream>>>(bucketEdges, bucketTotal, counts, N);
    // 6. scan offsets
    scan_block_kernel<<<nb, 256, 0, stream>>>(counts, offsets, blocksum, N);
    // 7. scan_add
    scan_add_kernel<<<nb, 256, 0, stream>>>(blocksum, offsets, N, nb);
    // 8. fused: csr scatter | att1
    fused_csr_att1_kernel<<<nbuck + nbG1, 256, 0, stream>>>(bucketEdges, bucketTotal, offsets,
                                                            csr, N, nbuck, xs_h, B1x, as1, ad1);
    // 9. per-head aggregate in xs-space
    aggregate_x4_kernel<<<nw, 256, 0, stream>>>(xs_h, as1, ad1, offsets, csr, aggx_lo, aggx_hi,
                                                N);
    // 10. gemm1b: o1[:, h*64:+64] = relu(aggx[h] @ W1[:, h*64:+64] + b1)  (col-split x2)
    gemm1b_kernel<<<nbG1 * 2, 256, 0, stream>>>(aggx_lo, aggx_hi, B1x, b1, o1h, N);
    // 11. gemm2(+att2)  (col-split x2, batched loads)
    gemm2_kernel<<<nbG1 * 2, 256, 0, stream>>>(o1h, B2x, hb2, as2, ad2, N);
    // 12. aggregate layer 2
    aggregate_kernel<HC2, false, float>
        <<<nw, 256, 0, stream>>>(hb2, as2, ad2, offsets, csr, b2, out, N);
}

// Round 8
// 295.009 us; speedup vs baseline: 1.9026x; 1.1395x over previous
//
#include <hip/hip_runtime.h>
#include <math.h>

#define NEG_SLOPE 0.2f

constexpr int F_IN  = 128;
constexpr int HC1   = 256;  // H*HID
constexpr int HC2   = 160;  // H*CLS
constexpr int NHEAD = 4;
constexpr int EB    = 2048; // edges per level-1 block
constexpr int NPB   = 128;  // nodes per bucket
constexpr int BCAP  = 4096; // bucket capacity (avg 2046 @ E=800k; Poisson tail safe)

typedef _Float16 h8v __attribute__((ext_vector_type(8)));
typedef _Float16 h4v __attribute__((ext_vector_type(4)));
typedef _Float16 h2v __attribute__((ext_vector_type(2)));
typedef float f4v __attribute__((ext_vector_type(4)));

// f32 += f16(lo/hi of packed) * f32 — single VOP3P instruction
#define FMIX_LO(acc, pk, wt) \
    asm("v_fma_mix_f32 %0, %1, %2, %0 op_sel:[0,0,0] op_sel_hi:[1,0,0]" \
        : "+v"(acc) : "v"(pk), "v"(wt))
#define FMIX_HI(acc, pk, wt) \
    asm("v_fma_mix_f32 %0, %1, %2, %0 op_sel:[1,0,0] op_sel_hi:[1,0,0]" \
        : "+v"(acc) : "v"(pk), "v"(wt))

__device__ __forceinline__ int edge_val(const void* p, int m64, long long i) {
    if (m64) return (int)((const long long*)p)[i];
    return ((const int*)p)[i];
}

// ---------------- dispatch 1: edge dtype detect (+ zero stats) ----------------
__global__ void detect_kernel(const unsigned int* __restrict__ ei_words, int* __restrict__ mode,
                              float* __restrict__ stats) {
    stats[threadIdx.x] = 0.f;  // 256 threads zero 256 floats (sum|sumsq)
    __shared__ unsigned int red[256];
    unsigned int v = 0;
    for (int i = 1 + 2 * (int)threadIdx.x; i < 4096; i += 512) v |= ei_words[i];
    red[threadIdx.x] = v;
    __syncthreads();
    for (int off = 128; off > 0; off >>= 1) {
        if (threadIdx.x < off) red[threadIdx.x] |= red[threadIdx.x + off];
        __syncthreads();
    }
    if (threadIdx.x == 0) *mode = (red[0] == 0u) ? 1 : 0;
}

// ---------------- dispatch 2 (fused): bucket-hist | colstats | convert_w ----------------
__global__ __launch_bounds__(256) void fused_pre_kernel(
    const void* __restrict__ ei, const int* __restrict__ mode, int E, int nbuck, int nblk1,
    int* __restrict__ hist, const float* __restrict__ x, float* __restrict__ stats, int N,
    const float* __restrict__ W1, const float* __restrict__ aS1, const float* __restrict__ aD1,
    _Float16* __restrict__ B1x, const float* __restrict__ W2, const float* __restrict__ aS2,
    const float* __restrict__ aD2, _Float16* __restrict__ B2x, int nbStats) {
    int b = blockIdx.x;
    if (b < nblk1) {
        // ---- level-1 histogram ----
        __shared__ int lh[512];
        for (int i = threadIdx.x; i < nbuck; i += 256) lh[i] = 0;
        __syncthreads();
        int m = *mode;
        long long e0 = (long long)b * EB;
#pragma unroll
        for (int k = 0; k < EB / 256; k++) {
            long long e = e0 + (int)threadIdx.x + k * 256;
            if (e < E) {
                int d = edge_val(ei, m, (long long)E + e);
                atomicAdd(&lh[d >> 7], 1);
            }
        }
        __syncthreads();
        for (int i = threadIdx.x; i < nbuck; i += 256) hist[(size_t)i * nblk1 + b] = lh[i];
    } else if (b < nblk1 + nbStats) {
        // ---- colstats: float4 loads, 32 iters/thread, LDS-reduce 8 row groups ----
        int t = (int)threadIdx.x;
        int c = t & 31;   // handles cols 4c..4c+3
        int g = t >> 5;   // row subgroup 0..7
        int r0 = (b - nblk1) * 256;
        int rend = min(r0 + 256, N);
        f4v s = {0.f, 0.f, 0.f, 0.f}, q = {0.f, 0.f, 0.f, 0.f};
        for (int r = r0 + g; r < rend; r += 8) {
            f4v v = *(const f4v*)&x[(long)r * F_IN + 4 * c];
            s += v;
            q += v * v;
        }
        __shared__ f4v sh4[256];
        sh4[t] = s;
        __syncthreads();
        if (t < 32) {
            f4v a = sh4[t];
            for (int g2 = 1; g2 < 8; g2++) a += sh4[g2 * 32 + t];
            atomicAdd(&stats[4 * t + 0], a[0]);
            atomicAdd(&stats[4 * t + 1], a[1]);
            atomicAdd(&stats[4 * t + 2], a[2]);
            atomicAdd(&stats[4 * t + 3], a[3]);
        }
        __syncthreads();
        sh4[t] = q;
        __syncthreads();
        if (t < 32) {
            f4v a = sh4[t];
            for (int g2 = 1; g2 < 8; g2++) a += sh4[g2 * 32 + t];
            atomicAdd(&stats[128 + 4 * t + 0], a[0]);
            atomicAdd(&stats[128 + 4 * t + 1], a[1]);
            atomicAdd(&stats[128 + 4 * t + 2], a[2]);
            atomicAdd(&stats[128 + 4 * t + 3], a[3]);
        }
    } else {
        // ---- convert weights -> fp16 transposed + att columns ----
        constexpr int T1 = (HC1 + 16) * F_IN;
        constexpr int T2 = (HC2 + 16) * HC1;
        int idx = (b - nblk1 - nbStats) * 256 + (int)threadIdx.x;
        if (idx < T1) {
            int n = idx / F_IN, k = idx - n * F_IN;
            float v = 0.f;
            if (n < HC1) {
                v = W1[k * HC1 + n];
            } else {
                int n2 = n - HC1;
                if (n2 < 8) {
                    int hd = n2 & 3;
                    const float* a = (n2 < 4) ? aS1 : aD1;
                    for (int c = 0; c < 64; c++) v += W1[k * HC1 + hd * 64 + c] * a[hd * 64 + c];
                }
            }
            B1x[n * F_IN + k] = (_Float16)v;
        } else if (idx < T1 + T2) {
            int i2 = idx - T1;
            int n = i2 / HC1, k = i2 - n * HC1;
            float v = 0.f;
            if (n < HC2) {
                v = W2[k * HC2 + n];
            } else {
                int n2 = n - HC2;
                if (n2 < 8) {
                    int hd = n2 & 3;
                    const float* a = (n2 < 4) ? aS2 : aD2;
                    for (int c = 0; c < 40; c++) v += W2[k * HC2 + hd * 40 + c] * a[hd * 40 + c];
                }
            }
            B2x[n * HC1 + k] = (_Float16)v;
        }
    }
}

// ---------------- dispatch 3 (fused): standardize | bucket col-scan ----------------
__global__ __launch_bounds__(256) void fused_mid_kernel(
    const float* __restrict__ x, const float* __restrict__ stats, _Float16* __restrict__ xs,
    int total4, float invN, float invN1, const int* __restrict__ hist,
    int* __restrict__ colBaseT, int* __restrict__ bucketTotal, int nbuck, int nblk1,
    int nbStd) {
    int b = blockIdx.x;
    if (b < nbStd) {
        int i = b * 256 + (int)threadIdx.x;
        if (i >= total4) return;
        int c = (i * 4) & (F_IN - 1);
        float4 s4 = *(const float4*)&stats[c];
        float4 q4 = *(const float4*)&stats[128 + c];
        float4 v = ((const float4*)x)[i];
        h4v o;
        o[0] = (_Float16)((v.x - s4.x * invN) / sqrtf((q4.x - s4.x * s4.x * invN) * invN1));
        o[1] = (_Float16)((v.y - s4.y * invN) / sqrtf((q4.y - s4.y * s4.y * invN) * invN1));
        o[2] = (_Float16)((v.z - s4.z * invN) / sqrtf((q4.z - s4.z * s4.z * invN) * invN1));
        o[3] = (_Float16)((v.w - s4.w * invN) / sqrtf((q4.w - s4.w * s4.w * invN) * invN1));
        ((h4v*)xs)[i] = o;
    } else {
        // col-scan: exclusive prefix over blocks of hist[bb][*]; write transposed
        int bb = b - nbStd;
        int t = (int)threadIdx.x;
        __shared__ int sh[512];
        __shared__ int wsum[4];
        for (int i = t; i < nblk1; i += 256) sh[i] = hist[(size_t)bb * nblk1 + i];
        __syncthreads();
        int carry = 0;
        for (int base = 0; base < nblk1; base += 256) {
            int idx = base + t;
            int v = (idx < nblk1) ? sh[idx] : 0;
            int lane = t & 63, w = t >> 6;
            int xv = v;
#pragma unroll
            for (int d = 1; d < 64; d <<= 1) {
                int y = __shfl_up(xv, d);
                if (lane >= d) xv += y;
            }
            if (lane == 63) wsum[w] = xv;
            __syncthreads();
            int wb = 0;
            for (int k = 0; k < w; k++) wb += wsum[k];
            int excl = xv - v + wb + carry;
            if (idx < nblk1) colBaseT[(size_t)idx * nbuck + bb] = excl;
            carry += wsum[0] + wsum[1] + wsum[2] + wsum[3];
            __syncthreads();
        }
        if (t == 0) bucketTotal[bb] = carry;
    }
}

// ---------------- dispatch 4: level-1 scatter into bucket regions ----------------
__global__ __launch_bounds__(256) void scatter1_kernel(const void* __restrict__ ei,
                                                       const int* __restrict__ mode, int E,
                                                       int nbuck,
                                                       const int* __restrict__ colBaseT,
                                                       int* __restrict__ bucketEdges) {
    __shared__ int cur[512];
    int b = blockIdx.x;
    for (int i = threadIdx.x; i < nbuck; i += 256)
        cur[i] = colBaseT[(size_t)b * nbuck + i];
    __syncthreads();
    int m = *mode;
    long long e0 = (long long)b * EB;
#pragma unroll
    for (int k = 0; k < EB / 256; k++) {
        long long e = e0 + (int)threadIdx.x + k * 256;
        if (e < E) {
            int s = edge_val(ei, m, e);
            int d = edge_val(ei, m, (long long)E + e);
            int bk = d >> 7;
            int r = atomicAdd(&cur[bk], 1);  // LDS returning atomic (fast)
            bucketEdges[(size_t)bk * BCAP + r] = s | ((d & (NPB - 1)) << 16);
        }
    }
}

// ---------------- dispatch 5: per-bucket node counts ----------------
__global__ __launch_bounds__(256) void bucket_count_kernel(const int* __restrict__ bucketEdges,
                                                           const int* __restrict__ bucketTotal,
                                                           int* __restrict__ counts, int N) {
    __shared__ int c[NPB];
    int b = blockIdx.x, t = threadIdx.x;
    if (t < NPB) c[t] = 0;
    __syncthreads();
    int cnt = bucketTotal[b];
    const int* be = bucketEdges + (size_t)b * BCAP;
    for (int i = t; i < cnt; i += 256) atomicAdd(&c[(be[i] >> 16) & (NPB - 1)], 1);
    __syncthreads();
    int node = b * NPB + t;
    if (t < NPB && node < N) counts[node] = c[t];  // non-atomic: bucket owns these nodes
}

// ---------------- dispatch 6: scan_block ----------------
__global__ __launch_bounds__(256) void scan_block_kernel(const int* __restrict__ counts,
                                                         int* __restrict__ offsets,
                                                         int* __restrict__ blocksum, int N) {
    int t = threadIdx.x;
    int i = blockIdx.x * 256 + t;
    int v = (i < N) ? counts[i] + 1 : 0;
    int lane = t & 63, w = t >> 6;
    int xv = v;
#pragma unroll
    for (int d = 1; d < 64; d <<= 1) {
        int y = __shfl_up(xv, d);
        if (lane >= d) xv += y;
    }
    __shared__ int wsum[4];
    if (lane == 63) wsum[w] = xv;
    __syncthreads();
    int base = 0;
    for (int k = 0; k < w; k++) base += wsum[k];
    int incl = xv + base;
    if (i < N) offsets[i + 1] = incl;
    if (t == 255) blocksum[blockIdx.x] = incl;
}

// ---------------- dispatch 7: scan_add ----------------
__global__ void scan_add_kernel(const int* __restrict__ blocksum, int* __restrict__ offsets, int N,
                                int nb) {
    int t = threadIdx.x;
    int v = (t < nb) ? blocksum[t] : 0;
    int lane = t & 63, w = t >> 6;
    int x = v;
#pragma unroll
    for (int d = 1; d < 64; d <<= 1) {
        int y = __shfl_up(x, d);
        if (lane >= d) x += y;
    }
    __shared__ int wsum[4];
    __shared__ int excl[256];
    if (lane == 63) wsum[w] = x;
    __syncthreads();
    int base = 0;
    for (int k = 0; k < w; k++) base += wsum[k];
    excl[t] = x + base - v;
    __syncthreads();
    int myb = excl[blockIdx.x];
    int i = blockIdx.x * 256 + t;
    if (i < N) offsets[i + 1] += myb;
    if (i == 0) offsets[0] = 0;
}

// ---------------- att1 mini-GEMM: as1/ad1 = xs @ (W1·att) (8 cols) ----------------
__device__ __forceinline__ void att1_body(int blk, const _Float16* __restrict__ A,
                                          const _Float16* __restrict__ Batt,
                                          float* __restrict__ as_, float* __restrict__ ad_,
                                          int M) {
    constexpr int KT = F_IN / 32;  // 4
    int w = threadIdx.x >> 6;
    int l = threadIdx.x & 63;
    int quad = l >> 4, lan = l & 15;
    int row = blk * 64 + w * 16 + lan;
    int arow = min(row, M - 1);
    const _Float16* Aptr = A + (long)arow * F_IN + quad * 8;
    h8v afr[KT], bfr[KT];
#pragma unroll
    for (int k0 = 0; k0 < KT; k0++) afr[k0] = *(const h8v*)(Aptr + k0 * 32);
#pragma unroll
    for (int k0 = 0; k0 < KT; k0++)
        bfr[k0] = *(const h8v*)(Batt + (long)lan * F_IN + k0 * 32 + quad * 8);
    f4v acc = {0.f, 0.f, 0.f, 0.f};
#pragma unroll
    for (int k0 = 0; k0 < KT; k0++)
        acc = __builtin_amdgcn_mfma_f32_16x16x32_f16(afr[k0], bfr[k0], acc, 0, 0, 0);
    int orow = blk * 64 + w * 16 + quad * 4;
#pragma unroll
    for (int r = 0; r < 4; r++) {
        int gr = orow + r;
        if (gr < M) {
            float av = acc[r];
            if (lan < 4)
                as_[gr * 4 + lan] = av;
            else if (lan < 8)
                ad_[gr * 4 + lan - 4] = av;
        }
    }
}

// ---------------- dispatch 8 (fused): csr-scatter | att1 ----------------
__global__ __launch_bounds__(256) void fused_csr_att1_kernel(
    const int* __restrict__ bucketEdges, const int* __restrict__ bucketTotal,
    const int* __restrict__ offsets, int* __restrict__ csr, int N, int nbuck,
    const _Float16* __restrict__ xs, const _Float16* __restrict__ B1x,
    float* __restrict__ as_, float* __restrict__ ad_) {
    int b = blockIdx.x;
    if (b < nbuck) {
        __shared__ int cur[NPB];
        int t = threadIdx.x;
        int node = b * NPB + t;
        if (t < NPB && node < N) {
            int off = offsets[node];
            csr[off] = node;  // self loop at slot 0
            cur[t] = off + 1;
        }
        __syncthreads();
        int cnt = bucketTotal[b];
        const int* be = bucketEdges + (size_t)b * BCAP;
        for (int i = t; i < cnt; i += 256) {
            int v = be[i];
            int pos = atomicAdd(&cur[(v >> 16) & (NPB - 1)], 1);  // LDS returning atomic
            csr[pos] = v & 0xFFFF;
        }
    } else {
        att1_body(b - nbuck, xs, B1x + (size_t)HC1 * F_IN, as_, ad_, N);
    }
}

// ---------------- dispatch 9: per-head layer-1 aggregate in xs-space ----------------
// (256,4): allow up to 128 VGPR so the 4-deep gather unroll stays in flight.
__global__ __launch_bounds__(256, 4) void aggregate_x4_kernel(
    const _Float16* __restrict__ xs, const float* __restrict__ a_src,
    const float* __restrict__ a_dst, const int* __restrict__ offsets,
    const int* __restrict__ csr_src, _Float16* __restrict__ aggx_lo,
    _Float16* __restrict__ aggx_hi, int Ntot) {
    int w = threadIdx.x >> 6, l = threadIdx.x & 63;
    int node = blockIdx.x * 4 + w;
    if (node >= Ntot) return;  // wave-uniform exit

    __shared__ __align__(16) int sidx_sh[4][64];     // byte offsets into xs (row = 256B)
    __shared__ __align__(16) float ew_sh[4][64][4];  // per-edge per-head exp weights

    int start = offsets[node], deg = offsets[node + 1] - start;
    float4 adv = ((const float4*)a_dst)[node];
    const char* hbl = (const char*)xs + 4 * l;  // this lane's 2-channel slice

    float ds0 = 0.f, ds1 = 0.f, ds2 = 0.f, ds3 = 0.f;
    float a00 = 0.f, a01 = 0.f, a10 = 0.f, a11 = 0.f;
    float a20 = 0.f, a21 = 0.f, a30 = 0.f, a31 = 0.f;

    for (int base = 0; base < deg; base += 64) {
        int cnt = min(64, deg - base);
        if (l < cnt) {
            int s = csr_src[start + base + l];
            sidx_sh[w][l] = s * (F_IN * 2);
            float4 av = ((const float4*)a_src)[s];
            float e0 = av.x + adv.x, e1 = av.y + adv.y, e2 = av.z + adv.z, e3 = av.w + adv.w;
            e0 = fmaxf(e0, NEG_SLOPE * e0);
            e1 = fmaxf(e1, NEG_SLOPE * e1);
            e2 = fmaxf(e2, NEG_SLOPE * e2);
            e3 = fmaxf(e3, NEG_SLOPE * e3);
            float w0 = __expf(e0), w1 = __expf(e1), w2 = __expf(e2), w3 = __expf(e3);
            *(float4*)ew_sh[w][l] = make_float4(w0, w1, w2, w3);
            ds0 += w0;
            ds1 += w1;
            ds2 += w2;
            ds3 += w3;
        }
        int j = 0;
        for (; j + 3 < cnt; j += 4) {
            int4 o4 = *(const int4*)&sidx_sh[w][j];
            float4 wa = *(const float4*)ew_sh[w][j + 0];
            float4 wb = *(const float4*)ew_sh[w][j + 1];
            float4 wc = *(const float4*)ew_sh[w][j + 2];
            float4 wd = *(const float4*)ew_sh[w][j + 3];
            int p0 = *(const int*)(hbl + o4.x);
            int p1 = *(const int*)(hbl + o4.y);
            int p2 = *(const int*)(hbl + o4.z);
            int p3 = *(const int*)(hbl + o4.w);
            FMIX_LO(a00, p0, wa.x); FMIX_HI(a01, p0, wa.x);
            FMIX_LO(a10, p0, wa.y); FMIX_HI(a11, p0, wa.y);
            FMIX_LO(a20, p0, wa.z); FMIX_HI(a21, p0, wa.z);
            FMIX_LO(a30, p0, wa.w); FMIX_HI(a31, p0, wa.w);
            FMIX_LO(a00, p1, wb.x); FMIX_HI(a01, p1, wb.x);
            FMIX_LO(a10, p1, wb.y); FMIX_HI(a11, p1, wb.y);
            FMIX_LO(a20, p1, wb.z); FMIX_HI(a21, p1, wb.z);
            FMIX_LO(a30, p1, wb.w); FMIX_HI(a31, p1, wb.w);
            FMIX_LO(a00, p2, wc.x); FMIX_HI(a01, p2, wc.x);
            FMIX_LO(a10, p2, wc.y); FMIX_HI(a11, p2, wc.y);
            FMIX_LO(a20, p2, wc.z); FMIX_HI(a21, p2, wc.z);
            FMIX_LO(a30, p2, wc.w); FMIX_HI(a31, p2, wc.w);
            FMIX_LO(a00, p3, wd.x); FMIX_HI(a01, p3, wd.x);
            FMIX_LO(a10, p3, wd.y); FMIX_HI(a11, p3, wd.y);
            FMIX_LO(a20, p3, wd.z); FMIX_HI(a21, p3, wd.z);
            FMIX_LO(a30, p3, wd.w); FMIX_HI(a31, p3, wd.w);
        }
        for (; j < cnt; j++) {
            int off = sidx_sh[w][j];
            float4 wa = *(const float4*)ew_sh[w][j];
            int p0 = *(const int*)(hbl + off);
            FMIX_LO(a00, p0, wa.x); FMIX_HI(a01, p0, wa.x);
            FMIX_LO(a10, p0, wa.y); FMIX_HI(a11, p0, wa.y);
            FMIX_LO(a20, p0, wa.z); FMIX_HI(a21, p0, wa.z);
            FMIX_LO(a30, p0, wa.w); FMIX_HI(a31, p0, wa.w);
        }
    }

#pragma unroll
    for (int off = 1; off < 64; off <<= 1) {
        ds0 += __shfl_xor(ds0, off);
        ds1 += __shfl_xor(ds1, off);
        ds2 += __shfl_xor(ds2, off);
        ds3 += __shfl_xor(ds3, off);
    }

    float i0 = 1.0f / ds0, i1 = 1.0f / ds1, i2 = 1.0f / ds2, i3 = 1.0f / ds3;
    h2v hv;
    hv[0] = (_Float16)(a00 * i0);
    hv[1] = (_Float16)(a01 * i0);
    *(h2v*)(aggx_lo + (size_t)node * F_IN + 2 * l) = hv;
    hv[0] = (_Float16)(a10 * i1);
    hv[1] = (_Float16)(a11 * i1);
    *(h2v*)(aggx_lo + ((size_t)Ntot + node) * F_IN + 2 * l) = hv;
    hv[0] = (_Float16)(a20 * i2);
    hv[1] = (_Float16)(a21 * i2);
    *(h2v*)(aggx_hi + (size_t)node * F_IN + 2 * l) = hv;
    hv[0] = (_Float16)(a30 * i3);
    hv[1] = (_Float16)(a31 * i3);
    *(h2v*)(aggx_hi + ((size_t)Ntot + node) * F_IN + 2 * l) = hv;
}

// ---------------- dispatch 10: gemm1b with fragment-linear LDS-staged B ----------------
// B staged once per block into LDS in MFMA-fragment order: chunk j=(ci*KT+k0)*64+l holds
// B row (CT0+ci)*16+(l&15), cols k0*32+(l>>4)*8 .. +8. MFMA-loop B read = Bs + (..+l)*8
// -> contiguous per lane, conflict-free. A-loads issued first so latency hides under staging.
template <int CT0, int CT1>
__device__ __forceinline__ void gemm1b_lds_body(int blk, const _Float16* __restrict__ Ah,
                                                const _Float16* __restrict__ Btx,
                                                _Float16* Bs, const float* __restrict__ bias,
                                                _Float16* __restrict__ C_, int M) {
    constexpr int NC = CT1 - CT0;  // 8
    constexpr int KT = F_IN / 32;  // 4
    int t = threadIdx.x;
    int w = t >> 6, l = t & 63;
    int quad = l >> 4, lan = l & 15;
    int row = blk * 64 + w * 16 + lan;
    int arow = min(row, M - 1);
    const _Float16* A0 = Ah + (size_t)arow * F_IN + quad * 8;        // head CT0/4
    const _Float16* A1 = Ah + ((size_t)M + arow) * F_IN + quad * 8;  // head CT0/4+1
    h8v af0[KT], af1[KT];
#pragma unroll
    for (int k0 = 0; k0 < KT; k0++) af0[k0] = *(const h8v*)(A0 + k0 * 32);
#pragma unroll
    for (int k0 = 0; k0 < KT; k0++) af1[k0] = *(const h8v*)(A1 + k0 * 32);
#pragma unroll
    for (int jj = 0; jj < NC * KT * 64 / 256; jj++) {  // 8 iters
        int j = jj * 256 + t;
        int cik = j >> 6;
        int k0_ = cik % KT, ci_ = cik / KT;
        int jl = j & 63;
        const _Float16* src =
            Btx + (long)((CT0 + ci_) * 16 + (jl & 15)) * F_IN + k0_ * 32 + (jl >> 4) * 8;
        *(h8v*)(Bs + (size_t)j * 8) = *(const h8v*)src;
    }
    __syncthreads();
    f4v acc[NC] = {};
#pragma unroll
    for (int k0 = 0; k0 < KT; k0++)
#pragma unroll
        for (int ci = 0; ci < NC; ci++) {
            h8v bf = *(const h8v*)(Bs + ((size_t)(ci * KT + k0) * 64 + l) * 8);
            h8v af = (ci < 4) ? af0[k0] : af1[k0];
            acc[ci] = __builtin_amdgcn_mfma_f32_16x16x32_f16(af, bf, acc[ci], 0, 0, 0);
        }
    int orow = blk * 64 + w * 16 + quad * 4;
#pragma unroll
    for (int r = 0; r < 4; r++) {
        int gr = orow + r;
        if (gr < M) {
            _Float16* out = C_ + (long)gr * HC1 + lan;
#pragma unroll
            for (int ci = 0; ci < NC; ci++) {
                int ct = CT0 + ci;
                float v = acc[ci][r] + bias[ct * 16 + lan];
                out[ct * 16] = (_Float16)fmaxf(v, 0.f);
            }
        }
    }
}

__global__ __launch_bounds__(256, 3) void gemm1b_kernel(const _Float16* __restrict__ Alo,
                                                        const _Float16* __restrict__ Ahi,
                                                        const _Float16* __restrict__ Btx,
                                                        const float* __restrict__ bias,
                                                        _Float16* __restrict__ C_, int M) {
    __shared__ __align__(16) _Float16 Bs[8 * 4 * 64 * 8];  // 32KB
    int blk = blockIdx.x >> 1;
    if (blockIdx.x & 1)
        gemm1b_lds_body<8, 16>(blk, Ahi, Btx, Bs, bias, C_, M);  // heads 2,3
    else
        gemm1b_lds_body<0, 8>(blk, Alo, Btx, Bs, bias, C_, M);   // heads 0,1
}

// ---------------- dispatch 11: gemm2(+att2) with fragment-linear LDS-staged B ----------
template <int CT0, int CT1>
__device__ __forceinline__ void gemm2_lds_body(int blk, const _Float16* __restrict__ A,
                                               const _Float16* __restrict__ Btx,
                                               _Float16* Bs, _Float16* __restrict__ C_,
                                               float* __restrict__ as_, float* __restrict__ ad_,
                                               int M) {
    constexpr int NT = HC2 / 16;   // 10
    constexpr int NC = CT1 - CT0;  // 5 or 6
    constexpr int KT = HC1 / 32;   // 8
    int t = threadIdx.x;
    int w = t >> 6, l = t & 63;
    int quad = l >> 4, lan = l & 15;
    int row = blk * 64 + w * 16 + lan;
    int arow = min(row, M - 1);
    const _Float16* Aptr = A + (long)arow * HC1 + quad * 8;
    h8v afr[KT];
#pragma unroll
    for (int k0 = 0; k0 < KT; k0++) afr[k0] = *(const h8v*)(Aptr + k0 * 32);
#pragma unroll
    for (int jj = 0; jj < NC * KT * 64 / 256; jj++) {  // 10 or 12 iters
        int j = jj * 256 + t;
        int cik = j >> 6;
        int k0_ = cik % KT, ci_ = cik / KT;
        int jl = j & 63;
        const _Float16* src =
            Btx + (long)((CT0 + ci_) * 16 + (jl & 15)) * HC1 + k0_ * 32 + (jl >> 4) * 8;
        *(h8v*)(Bs + (size_t)j * 8) = *(const h8v*)src;
    }
    __syncthreads();
    f4v acc[NC] = {};
#pragma unroll
    for (int k0 = 0; k0 < KT; k0++)
#pragma unroll
        for (int ci = 0; ci < NC; ci++) {
            h8v bf = *(const h8v*)(Bs + ((size_t)(ci * KT + k0) * 64 + l) * 8);
            acc[ci] = __builtin_amdgcn_mfma_f32_16x16x32_f16(afr[k0], bf, acc[ci], 0, 0, 0);
        }
    int orow = blk * 64 + w * 16 + quad * 4;
#pragma unroll
    for (int r = 0; r < 4; r++) {
        int gr = orow + r;
        if (gr < M) {
            _Float16* out = C_ + (long)gr * HC2 + lan;
#pragma unroll
            for (int ci = 0; ci < NC; ci++) {
                int ct = CT0 + ci;
                if (ct < NT) out[ct * 16] = (_Float16)acc[ci][r];
            }
            if (CT1 == NT + 1) {
                float av = acc[NC - 1][r];
                if (lan < 4)
                    as_[gr * 4 + lan] = av;
                else if (lan < 8)
                    ad_[gr * 4 + lan - 4] = av;
            }
        }
    }
}

__global__ __launch_bounds__(256, 3) void gemm2_kernel(const _Float16* __restrict__ A,
                                                       const _Float16* __restrict__ B2x,
                                                       _Float16* __restrict__ C_,
                                                       float* __restrict__ as_,
                                                       float* __restrict__ ad_, int M) {
    __shared__ __align__(16) _Float16 Bs[6 * 8 * 64 * 8];  // 48KB (odd half size)
    int blk = blockIdx.x >> 1;
    if (blockIdx.x & 1)
        gemm2_lds_body<5, 11>(blk, A, B2x, Bs, C_, as_, ad_, M);  // tiles 5-9 + att
    else
        gemm2_lds_body<0, 5>(blk, A, B2x, Bs, C_, as_, ad_, M);   // tiles 0-4
}

// ---------------- layer-2 aggregate (R1 row-major structure, x8 unroll) ----------------
template <int HC, bool RELU, typename OutT>
__global__ __launch_bounds__(256, 4) void aggregate_kernel(
    const _Float16* __restrict__ hb, const float* __restrict__ a_src,
    const float* __restrict__ a_dst, const int* __restrict__ offsets,
    const int* __restrict__ csr_src, const float* __restrict__ bias, OutT* __restrict__ out,
    int Ntot) {
    constexpr int ACT = HC / 4;       // active gather lanes (64 or 40)
    constexpr int CHPH = HC / NHEAD;  // channels per head
    constexpr bool FULL = (ACT == 64);
    int w = threadIdx.x >> 6, l = threadIdx.x & 63;
    int node = blockIdx.x * 4 + w;
    if (node >= Ntot) return;  // wave-uniform exit

    __shared__ __align__(16) int sidx_sh[4][64];     // byte offsets into hb
    __shared__ __align__(16) float ew_sh[4][64][4];  // per-edge per-head exp weights

    int start = offsets[node], end = offsets[node + 1];
    int deg = end - start;
    float4 adv = ((const float4*)a_dst)[node];
    const int hd = min((4 * l) / CHPH, 3);
    const char* hbl = (const char*)hb + 8 * l;  // this lane's 4-channel slice

    float ds0 = 0.f, ds1 = 0.f, ds2 = 0.f, ds3 = 0.f;
    float a0 = 0.f, a1 = 0.f, a2 = 0.f, a3 = 0.f;

    for (int base = 0; base < deg; base += 64) {
        int cnt = min(64, deg - base);
        if (l < cnt) {
            int s = csr_src[start + base + l];
            sidx_sh[w][l] = s * (HC * 2);
            float4 av = ((const float4*)a_src)[s];
            float e0 = av.x + adv.x, e1 = av.y + adv.y, e2 = av.z + adv.z, e3 = av.w + adv.w;
            e0 = fmaxf(e0, NEG_SLOPE * e0);
            e1 = fmaxf(e1, NEG_SLOPE * e1);
            e2 = fmaxf(e2, NEG_SLOPE * e2);
            e3 = fmaxf(e3, NEG_SLOPE * e3);
            float w0 = __expf(e0), w1 = __expf(e1), w2 = __expf(e2), w3 = __expf(e3);
            *(float4*)ew_sh[w][l] = make_float4(w0, w1, w2, w3);
            ds0 += w0;
            ds1 += w1;
            ds2 += w2;
            ds3 += w3;
        }
        int j = 0;
        for (; j + 7 < cnt; j += 8) {
            int4 oa = *(const int4*)&sidx_sh[w][j];
            int4 ob = *(const int4*)&sidx_sh[w][j + 4];
            float w0 = ew_sh[w][j + 0][hd], w1 = ew_sh[w][j + 1][hd];
            float w2 = ew_sh[w][j + 2][hd], w3 = ew_sh[w][j + 3][hd];
            float w4 = ew_sh[w][j + 4][hd], w5 = ew_sh[w][j + 5][hd];
            float w6 = ew_sh[w][j + 6][hd], w7 = ew_sh[w][j + 7][hd];
            if (FULL || l < ACT) {
                int2 p0 = *(const int2*)(hbl + oa.x);
                int2 p1 = *(const int2*)(hbl + oa.y);
                int2 p2 = *(const int2*)(hbl + oa.z);
                int2 p3 = *(const int2*)(hbl + oa.w);
                int2 p4 = *(const int2*)(hbl + ob.x);
                int2 p5 = *(const int2*)(hbl + ob.y);
                int2 p6 = *(const int2*)(hbl + ob.z);
                int2 p7 = *(const int2*)(hbl + ob.w);
                FMIX_LO(a0, p0.x, w0); FMIX_HI(a1, p0.x, w0);
                FMIX_LO(a2, p0.y, w0); FMIX_HI(a3, p0.y, w0);
                FMIX_LO(a0, p1.x, w1); FMIX_HI(a1, p1.x, w1);
                FMIX_LO(a2, p1.y, w1); FMIX_HI(a3, p1.y, w1);
                FMIX_LO(a0, p2.x, w2); FMIX_HI(a1, p2.x, w2);
                FMIX_LO(a2, p2.y, w2); FMIX_HI(a3, p2.y, w2);
                FMIX_LO(a0, p3.x, w3); FMIX_HI(a1, p3.x, w3);
                FMIX_LO(a2, p3.y, w3); FMIX_HI(a3, p3.y, w3);
                FMIX_LO(a0, p4.x, w4); FMIX_HI(a1, p4.x, w4);
                FMIX_LO(a2, p4.y, w4); FMIX_HI(a3, p4.y, w4);
                FMIX_LO(a0, p5.x, w5); FMIX_HI(a1, p5.x, w5);
                FMIX_LO(a2, p5.y, w5); FMIX_HI(a3, p5.y, w5);
                FMIX_LO(a0, p6.x, w6); FMIX_HI(a1, p6.x, w6);
                FMIX_LO(a2, p6.y, w6); FMIX_HI(a3, p6.y, w6);
                FMIX_LO(a0, p7.x, w7); FMIX_HI(a1, p7.x, w7);
                FMIX_LO(a2, p7.y, w7); FMIX_HI(a3, p7.y, w7);
            }
        }
        for (; j + 3 < cnt; j += 4) {
            int4 o4 = *(const int4*)&sidx_sh[w][j];
            float w0 = ew_sh[w][j + 0][hd], w1 = ew_sh[w][j + 1][hd];
            float w2 = ew_sh[w][j + 2][hd], w3 = ew_sh[w][j + 3][hd];
            if (FULL || l < ACT) {
                int2 p0 = *(const int2*)(hbl + o4.x);
                int2 p1 = *(const int2*)(hbl + o4.y);
                int2 p2 = *(const int2*)(hbl + o4.z);
                int2 p3 = *(const int2*)(hbl + o4.w);
                FMIX_LO(a0, p0.x, w0); FMIX_HI(a1, p0.x, w0);
                FMIX_LO(a2, p0.y, w0); FMIX_HI(a3, p0.y, w0);
                FMIX_LO(a0, p1.x, w1); FMIX_HI(a1, p1.x, w1);
                FMIX_LO(a2, p1.y, w1); FMIX_HI(a3, p1.y, w1);
                FMIX_LO(a0, p2.x, w2); FMIX_HI(a1, p2.x, w2);
                FMIX_LO(a2, p2.y, w2); FMIX_HI(a3, p2.y, w2);
                FMIX_LO(a0, p3.x, w3); FMIX_HI(a1, p3.x, w3);
                FMIX_LO(a2, p3.y, w3); FMIX_HI(a3, p3.y, w3);
            }
        }
        for (; j < cnt; j++) {
            int off = sidx_sh[w][j];
            float w0 = ew_sh[w][j][hd];
            if (FULL || l < ACT) {
                int2 p0 = *(const int2*)(hbl + off);
                FMIX_LO(a0, p0.x, w0); FMIX_HI(a1, p0.x, w0);
                FMIX_LO(a2, p0.y, w0); FMIX_HI(a3, p0.y, w0);
            }
        }
    }

#pragma unroll
    for (int off = 1; off < 64; off <<= 1) {
        ds0 += __shfl_xor(ds0, off);
        ds1 += __shfl_xor(ds1, off);
        ds2 += __shfl_xor(ds2, off);
        ds3 += __shfl_xor(ds3, off);
    }

    if (FULL || l < ACT) {
        float dsel = hd == 0 ? ds0 : hd == 1 ? ds1 : hd == 2 ? ds2 : ds3;
        float inv = 1.0f / dsel;
        float4 bv = ((const float4*)bias)[l];
        float r0 = a0 * inv + bv.x;
        float r1 = a1 * inv + bv.y;
        float r2 = a2 * inv + bv.z;
        float r3 = a3 * inv + bv.w;
        if (RELU) {
            r0 = fmaxf(r0, 0.f);
            r1 = fmaxf(r1, 0.f);
            r2 = fmaxf(r2, 0.f);
            r3 = fmaxf(r3, 0.f);
        }
        OutT* op = out + (long)node * HC + 4 * l;
        if (sizeof(OutT) == 2) {
            h4v hv;
            hv[0] = (_Float16)r0;
            hv[1] = (_Float16)r1;
            hv[2] = (_Float16)r2;
            hv[3] = (_Float16)r3;
            *(h4v*)op = hv;
        } else {
            *(float4*)op = make_float4(r0, r1, r2, r3);
        }
    }
}

// ---------------- launch ----------------
extern "C" void kernel_launch(void* const* d_in, const int* in_sizes, int n_in, void* d_out,
                              int out_size, void* d_ws, size_t ws_size, hipStream_t stream) {
    const float* x = (const float*)d_in[0];
    const void* ei = d_in[1];
    const float* W1 = (const float*)d_in[2];
    const float* attS1 = (const float*)d_in[3];
    const float* attD1 = (const float*)d_in[4];
    const float* b1 = (const float*)d_in[5];
    const float* W2 = (const float*)d_in[6];
    const float* attS2 = (const float*)d_in[7];
    const float* attD2 = (const float*)d_in[8];
    const float* b2 = (const float*)d_in[9];
    float* out = (float*)d_out;

    int N = in_sizes[0] / F_IN;  // 50000
    int E = in_sizes[1] / 2;     // 800000
    int nb = (N + 255) / 256;    // 196
    int nw = (N + 3) / 4;        // wave-per-node aggregate grid
    int nblk1 = (E + EB - 1) / EB;   // 391 level-1 edge blocks
    int nbuck = (N + NPB - 1) / NPB; // 391 node buckets

    _Float16* xs_h = (_Float16*)d_ws;             // N*128
    _Float16* o1h = xs_h + (size_t)N * F_IN;      // N*256 (CSR-build scratch overlays early)
    _Float16* hb2 = o1h + (size_t)N * HC1;        // N*160
    _Float16* aggx_hi = hb2 + (size_t)N * HC2;    // N*256 (heads 2,3 of aggx)
    _Float16* B1x = aggx_hi + (size_t)N * HC1;    // 272*128
    _Float16* B2x = B1x + (HC1 + 16) * F_IN;      // 176*256
    float* as1 = (float*)(B2x + (HC2 + 16) * HC1);
    float* ad1 = as1 + (size_t)N * NHEAD;
    float* as2 = ad1 + (size_t)N * NHEAD;
    float* ad2 = as2 + (size_t)N * NHEAD;
    float* stats = ad2 + (size_t)N * NHEAD;       // 256 (zeroed in detect_kernel)
    int* offsets = (int*)(stats + 256);           // N+1 (pad 4)
    int* csr = offsets + (N + 4);                 // E+N
    int* blocksum = csr + (E + N);                // 256
    int* mode = blocksum + 256;                   // 1
    // CSR-build scratch in o1h slot (dead before gemm1b writes o1h): ~7.9MB < 25.6MB
    int* counts = (int*)o1h;                              // N
    int* bucketEdges = counts + N;                        // nbuck*BCAP
    int* hist = bucketEdges + (size_t)nbuck * BCAP;       // nbuck*nblk1 (bucket-major)
    int* colBaseT = hist + (size_t)nbuck * nblk1;         // nblk1*nbuck (block-major)
    int* bucketTotal = colBaseT + (size_t)nblk1 * nbuck;  // nbuck
    _Float16* aggx_lo = (_Float16*)d_out;  // heads 0,1 (25.6MB <= out buffer;
                                           // fully overwritten by final aggregate)

    constexpr int TCV = (HC1 + 16) * F_IN + (HC2 + 16) * HC1;
    int nbConv = (TCV + 255) / 256;                      // 143
    int total4 = N * F_IN / 4;
    int nbStd = (total4 + 255) / 256;                    // 6250
    int nbG1 = (N + 63) / 64;                            // 782

    // 1. detect edge dtype + zero stats
    detect_kernel<<<1, 256, 0, stream>>>((const unsigned int*)ei, mode, stats);
    // 2. fused: bucket-hist | colstats | convert_w  (no far atomics)
    fused_pre_kernel<<<nblk1 + nb + nbConv, 256, 0, stream>>>(
        ei, mode, E, nbuck, nblk1, hist, x, stats, N, W1, attS1, attD1, B1x, W2, attS2, attD2,
        B2x, nb);
    // 3. fused: standardize | bucket col-scan
    fused_mid_kernel<<<nbStd + nbuck, 256, 0, stream>>>(x, stats, xs_h, total4,
                                                        1.0f / (float)N, 1.0f / (float)(N - 1),
                                                        hist, colBaseT, bucketTotal, nbuck,
                                                        nblk1, nbStd);
    // 4. level-1 scatter into bucket regions
    scatter1_kernel<<<nblk1, 256, 0, stream>>>(ei, mode, E, nbuck, colBaseT, bucketEdges);
    // 5. per-bucket node counts
    bucket_count_kernel<<<nbuck, 256, 0, stream>>>(bucketEdges, bucketTotal, counts, N);
    // 6. scan offsets
    scan_block_kernel<<<nb, 256, 0, stream>>>(counts, offsets, blocksum, N);
    // 7. scan_add
    scan_add_kernel<<<nb, 256, 0, stream>>>(blocksum, offsets, N, nb);
    // 8. fused: csr scatter | att1
    fused_csr_att1_kernel<<<nbuck + nbG1, 256, 0, stream>>>(bucketEdges, bucketTotal, offsets,
                                                            csr, N, nbuck, xs_h, B1x, as1, ad1);
    // 9. per-head aggregate in xs-space
    aggregate_x4_kernel<<<nw, 256, 0, stream>>>(xs_h, as1, ad1, offsets, csr, aggx_lo, aggx_hi,
                                                N);
    // 10. gemm1b: o1[:, h*64:+64] = relu(aggx[h] @ W1[:, h*64:+64] + b1)  (LDS-staged B)
    gemm1b_kernel<<<nbG1 * 2, 256, 0, stream>>>(aggx_lo, aggx_hi, B1x, b1, o1h, N);
    // 11. gemm2(+att2)  (LDS-staged B)
    gemm2_kernel<<<nbG1 * 2, 256, 0, stream>>>(o1h, B2x, hb2, as2, ad2, N);
    // 12. aggregate layer 2
    aggregate_kernel<HC2, false, float>
        <<<nw, 256, 0, stream>>>(hb2, as2, ad2, offsets, csr, b2, out, N);
}